// Round 1
// baseline (1607.256 us; speedup 1.0000x reference)
//
#include <hip/hip_runtime.h>
#include <hip/hip_bf16.h>

// Mamba block: B=4, L=2048, D_MODEL=1024, D_INNER=2048, D_STATE=16, DT_RANK=64
#define B_ 4
#define L_ 2048
#define DM 1024
#define DI 2048
#define DSTATE 16
#define DTR 64

typedef unsigned short ushort_t;
typedef __bf16 bf16x8 __attribute__((ext_vector_type(8)));
typedef float f32x4 __attribute__((ext_vector_type(4)));
typedef unsigned short u16x8 __attribute__((ext_vector_type(8)));

__device__ __forceinline__ ushort_t f2bf(float f) {
    unsigned u = __builtin_bit_cast(unsigned, f);
    unsigned r = (u + 0x7FFFu + ((u >> 16) & 1u)) >> 16;
    return (ushort_t)r;
}
__device__ __forceinline__ float bf2f(ushort_t h) {
    unsigned u = ((unsigned)h) << 16;
    return __builtin_bit_cast(float, u);
}

// ---------------- f32 -> bf16 convert ----------------
__global__ __launch_bounds__(256) void k_cvt(const float* __restrict__ in,
                                             ushort_t* __restrict__ out, int n) {
    int i = (blockIdx.x * 256 + threadIdx.x) * 4;
    if (i + 3 < n) {
        float4 v = *reinterpret_cast<const float4*>(in + i);
        ushort4 o;
        o.x = f2bf(v.x); o.y = f2bf(v.y); o.z = f2bf(v.z); o.w = f2bf(v.w);
        *reinterpret_cast<ushort4*>(out + i) = o;
    } else {
        for (; i < n; ++i) out[i] = f2bf(in[i]);
    }
}

// ---------------- generic bf16 MFMA GEMM: C[M,N] = A[M,K] * W[N,K]^T ----------------
// EPI: 0 = none, 1 = softplus(acc + bias[col])
template <int EPI, bool OUTBF>
__global__ __launch_bounds__(256) void k_gemm(
    const ushort_t* __restrict__ A, const ushort_t* __restrict__ Bw,
    void* __restrict__ C, const float* __restrict__ bias,
    int M, int N, int K, int lda, int ldb, int ldc) {
    __shared__ ushort_t As[128][72];  // +8 pad: 2-way bank conflict only (free)
    __shared__ ushort_t Bs[128][72];
    int tid = threadIdx.x;
    int lane = tid & 63, wid = tid >> 6;
    int wr = wid >> 1, wc = wid & 1;
    int row0 = blockIdx.x * 128, col0 = blockIdx.y * 128;

    f32x4 acc[4][4] = {};

    for (int k0 = 0; k0 < K; k0 += 64) {
        __syncthreads();
#pragma unroll
        for (int i = 0; i < 4; ++i) {
            int c = tid + i * 256;
            int r = c >> 3, cc = (c & 7) << 3;
            *reinterpret_cast<u16x8*>(&As[r][cc]) =
                *reinterpret_cast<const u16x8*>(&A[(size_t)(row0 + r) * lda + k0 + cc]);
            u16x8 bv = {};
            if (col0 + r < N)
                bv = *reinterpret_cast<const u16x8*>(&Bw[(size_t)(col0 + r) * ldb + k0 + cc]);
            *reinterpret_cast<u16x8*>(&Bs[r][cc]) = bv;
        }
        __syncthreads();
#pragma unroll
        for (int kk = 0; kk < 2; ++kk) {
            int ko = kk * 32 + (lane >> 4) * 8;
            bf16x8 af[4], bfr[4];
#pragma unroll
            for (int m = 0; m < 4; ++m)
                af[m] = *reinterpret_cast<const bf16x8*>(&As[wr * 64 + m * 16 + (lane & 15)][ko]);
#pragma unroll
            for (int n = 0; n < 4; ++n)
                bfr[n] = *reinterpret_cast<const bf16x8*>(&Bs[wc * 64 + n * 16 + (lane & 15)][ko]);
#pragma unroll
            for (int m = 0; m < 4; ++m)
#pragma unroll
                for (int n = 0; n < 4; ++n)
                    acc[m][n] = __builtin_amdgcn_mfma_f32_16x16x32_bf16(af[m], bfr[n], acc[m][n], 0, 0, 0);
        }
    }

#pragma unroll
    for (int m = 0; m < 4; ++m) {
#pragma unroll
        for (int n = 0; n < 4; ++n) {
            int col = col0 + wc * 64 + n * 16 + (lane & 15);
            if (col >= N) continue;
#pragma unroll
            for (int r = 0; r < 4; ++r) {
                int row = row0 + wr * 64 + m * 16 + (lane >> 4) * 4 + r;
                float v = acc[m][n][r];
                if (EPI == 1) {
                    v += bias[col];
                    v = (v > 20.f) ? v : log1pf(__expf(v));
                }
                if (OUTBF)
                    ((ushort_t*)C)[(size_t)row * ldc + col] = f2bf(v);
                else
                    ((float*)C)[(size_t)row * ldc + col] = v;
            }
        }
    }
}

// ---------------- depthwise causal conv (width 4) + SiLU ----------------
// reads xm half of xz (cols 0..2047 of 4096-wide rows), writes xm_conv bf16
__global__ __launch_bounds__(256) void k_conv(const ushort_t* __restrict__ xz,
                                              const float* __restrict__ w,
                                              const float* __restrict__ bias,
                                              ushort_t* __restrict__ out) {
    int d = blockIdx.x * 256 + threadIdx.x;
    int b = blockIdx.z;
    int t0 = blockIdx.y * 128;
    float w0 = w[d * 4 + 0], w1 = w[d * 4 + 1], w2 = w[d * 4 + 2], w3 = w[d * 4 + 3];
    float bi = bias[d];
    size_t base = ((size_t)b * L_) * (2 * DI) + d;
    size_t obase = ((size_t)b * L_) * DI + d;
    float x0 = (t0 >= 3) ? bf2f(xz[base + (size_t)(t0 - 3) * (2 * DI)]) : 0.f;
    float x1 = (t0 >= 2) ? bf2f(xz[base + (size_t)(t0 - 2) * (2 * DI)]) : 0.f;
    float x2 = (t0 >= 1) ? bf2f(xz[base + (size_t)(t0 - 1) * (2 * DI)]) : 0.f;
    for (int t = t0; t < t0 + 128; ++t) {
        float cur = bf2f(xz[base + (size_t)t * (2 * DI)]);
        float v = w0 * x0 + w1 * x1 + w2 * x2 + w3 * cur + bi;
        v = v / (1.f + __expf(-v));
        out[obase + (size_t)t * DI] = f2bf(v);
        x0 = x1; x1 = x2; x2 = cur;
    }
}

// ---------------- selective scan + D*x + z-gating ----------------
__global__ __launch_bounds__(256) void k_scan(
    const float* __restrict__ dt, const ushort_t* __restrict__ xm,
    const ushort_t* __restrict__ xz, const ushort_t* __restrict__ dbc,
    const float* __restrict__ A_log, const float* __restrict__ Dp,
    ushort_t* __restrict__ yg) {
    __shared__ float Bsh[64][DSTATE];
    __shared__ float Csh[64][DSTATE];
    int tid = threadIdx.x;
    int d = blockIdx.x * 256 + tid;
    int b = blockIdx.y;
    float Arow[DSTATE];
#pragma unroll
    for (int s = 0; s < DSTATE; ++s) Arow[s] = -__expf(A_log[d * DSTATE + s]);
    float Dd = Dp[d];
    float h[DSTATE] = {};
    size_t rbase = (size_t)b * L_;
    for (int tc = 0; tc < L_; tc += 64) {
        __syncthreads();
        {
            int e0 = tid * 8;
            int t = e0 >> 5, s0 = e0 & 31;
            u16x8 v = *reinterpret_cast<const u16x8*>(&dbc[(rbase + tc + t) * 96 + DTR + s0]);
#pragma unroll
            for (int j = 0; j < 8; ++j) {
                int s = s0 + j;
                float f = bf2f(v[j]);
                if (s < DSTATE) Bsh[t][s] = f;
                else Csh[t][s - DSTATE] = f;
            }
        }
        __syncthreads();
        for (int t2 = 0; t2 < 64; ++t2) {
            size_t ro = rbase + tc + t2;
            float dtv = dt[ro * DI + d];
            float xv = bf2f(xm[ro * DI + d]);
            float zv = bf2f(xz[ro * (2 * DI) + DI + d]);
            float dx = dtv * xv;
            float y = 0.f;
#pragma unroll
            for (int s = 0; s < DSTATE; ++s) {
                h[s] = __expf(dtv * Arow[s]) * h[s] + dx * Bsh[t2][s];
                y += h[s] * Csh[t2][s];
            }
            y += Dd * xv;
            y *= zv / (1.f + __expf(-zv));
            yg[ro * DI + d] = f2bf(y);
        }
    }
}

// ---------------- residual + LayerNorm ----------------
__global__ __launch_bounds__(256) void k_ln(const float* __restrict__ mo,
                                            const float* __restrict__ x,
                                            const float* __restrict__ g,
                                            const float* __restrict__ be,
                                            float* __restrict__ out) {
    __shared__ float red[8];
    size_t r = blockIdx.x;
    int tid = threadIdx.x;
    float4 hv = *reinterpret_cast<const float4*>(&mo[r * DM + tid * 4]);
    float4 xv = *reinterpret_cast<const float4*>(&x[r * DM + tid * 4]);
    float h0 = hv.x + xv.x, h1 = hv.y + xv.y, h2 = hv.z + xv.z, h3 = hv.w + xv.w;
    float s = h0 + h1 + h2 + h3;
    float q = h0 * h0 + h1 * h1 + h2 * h2 + h3 * h3;
#pragma unroll
    for (int o = 32; o > 0; o >>= 1) {
        s += __shfl_down(s, o);
        q += __shfl_down(q, o);
    }
    int lane = tid & 63, wid = tid >> 6;
    if (lane == 0) { red[wid] = s; red[4 + wid] = q; }
    __syncthreads();
    s = red[0] + red[1] + red[2] + red[3];
    q = red[4] + red[5] + red[6] + red[7];
    float mu = s * (1.f / DM);
    float var = q * (1.f / DM) - mu * mu;
    float rs = rsqrtf(var + 1e-5f);
    float4 gv = *reinterpret_cast<const float4*>(&g[tid * 4]);
    float4 bv = *reinterpret_cast<const float4*>(&be[tid * 4]);
    float4 o;
    o.x = (h0 - mu) * rs * gv.x + bv.x;
    o.y = (h1 - mu) * rs * gv.y + bv.y;
    o.z = (h2 - mu) * rs * gv.z + bv.z;
    o.w = (h3 - mu) * rs * gv.w + bv.w;
    *reinterpret_cast<float4*>(&out[r * DM + tid * 4]) = o;
}

extern "C" void kernel_launch(void* const* d_in, const int* in_sizes, int n_in,
                              void* d_out, int out_size, void* d_ws, size_t ws_size,
                              hipStream_t stream) {
    const float* x      = (const float*)d_in[0];   // (B,L,DM)
    const float* w_in   = (const float*)d_in[1];   // (2*DI, DM)
    const float* conv_w = (const float*)d_in[2];   // (DI,1,4)
    const float* conv_b = (const float*)d_in[3];   // (DI)
    const float* w_xp   = (const float*)d_in[4];   // (96, DI)
    const float* w_dt   = (const float*)d_in[5];   // (DI, 64)
    const float* dt_b   = (const float*)d_in[6];   // (DI)
    const float* A_log  = (const float*)d_in[7];   // (DI,16)
    const float* Dp     = (const float*)d_in[8];   // (DI)
    const float* w_out  = (const float*)d_in[9];   // (DM, DI)
    const float* ln_g   = (const float*)d_in[10];
    const float* ln_b   = (const float*)d_in[11];
    float* out = (float*)d_out;

    char* ws = (char*)d_ws;
    size_t off = 0;
    auto alloc = [&](size_t bytes) -> void* {
        void* p = ws + off;
        off += (bytes + 255) & ~(size_t)255;
        return p;
    };
    const int M = B_ * L_;  // 8192
    ushort_t* w_in_b  = (ushort_t*)alloc((size_t)2 * DI * DM * 2);
    ushort_t* w_xp_b  = (ushort_t*)alloc((size_t)96 * DI * 2);
    ushort_t* w_dt_b  = (ushort_t*)alloc((size_t)DI * DTR * 2);
    ushort_t* w_out_b = (ushort_t*)alloc((size_t)DM * DI * 2);
    ushort_t* x_b     = (ushort_t*)alloc((size_t)M * DM * 2);
    ushort_t* xz      = (ushort_t*)alloc((size_t)M * 2 * DI * 2);
    ushort_t* xm      = (ushort_t*)alloc((size_t)M * DI * 2);
    ushort_t* dbc     = (ushort_t*)alloc((size_t)M * 96 * 2);
    float*    dtb     = (float*)alloc((size_t)M * DI * 4);
    ushort_t* yg      = (ushort_t*)alloc((size_t)M * DI * 2);
    float*    mo      = (float*)dtb;  // alias: dt dead after scan

    auto cvt = [&](const float* src, ushort_t* dst, int n) {
        k_cvt<<<dim3((n / 4 + 255) / 256), 256, 0, stream>>>(src, dst, n);
    };
    cvt(w_in, w_in_b, 2 * DI * DM);
    cvt(w_xp, w_xp_b, 96 * DI);
    cvt(w_dt, w_dt_b, DI * DTR);
    cvt(w_out, w_out_b, DM * DI);
    cvt(x, x_b, M * DM);

    // in_proj: xz[M, 4096] = x[M,1024] @ w_in[4096,1024]^T
    k_gemm<0, true><<<dim3(64, 32), 256, 0, stream>>>(
        x_b, w_in_b, xz, nullptr, M, 2 * DI, DM, DM, DM, 2 * DI);
    // conv + silu
    k_conv<<<dim3(DI / 256, L_ / 128, B_), 256, 0, stream>>>(xz, conv_w, conv_b, xm);
    // x_proj: dbc[M,96] = xm @ w_xp[96,2048]^T
    k_gemm<0, true><<<dim3(64, 1), 256, 0, stream>>>(
        xm, w_xp_b, dbc, nullptr, M, 96, DI, DI, DI, 96);
    // dt_proj + softplus: dt[M,2048] = softplus(dbc[:, :64] @ w_dt^T + dt_b)
    k_gemm<1, false><<<dim3(64, 16), 256, 0, stream>>>(
        dbc, w_dt_b, dtb, dt_b, M, DI, DTR, 96, DTR, DI);
    // selective scan + gating
    k_scan<<<dim3(DI / 256, B_), 256, 0, stream>>>(dtb, xm, xz, dbc, A_log, Dp, yg);
    // out_proj: mo[M,1024] = yg @ w_out[1024,2048]^T
    k_gemm<0, false><<<dim3(64, 8), 256, 0, stream>>>(
        yg, w_out_b, mo, nullptr, M, DM, DI, DI, DI, DM);
    // residual + layernorm
    k_ln<<<dim3(M), 256, 0, stream>>>(mo, x, ln_g, ln_b, out);
}

// Round 2
// 524.371 us; speedup vs baseline: 3.0651x; 3.0651x over previous
//
#include <hip/hip_runtime.h>
#include <hip/hip_bf16.h>

// Mamba block: B=4, L=2048, D_MODEL=1024, D_INNER=2048, D_STATE=16, DT_RANK=64
#define B_ 4
#define L_ 2048
#define DM 1024
#define DI 2048
#define DSTATE 16
#define DTR 64
#define LC 64            // scan chunk length
#define NC (L_ / LC)     // 32 chunks

typedef unsigned short ushort_t;
typedef __bf16 bf16x8 __attribute__((ext_vector_type(8)));
typedef float f32x4 __attribute__((ext_vector_type(4)));
typedef unsigned short u16x8 __attribute__((ext_vector_type(8)));
typedef unsigned short u16x4 __attribute__((ext_vector_type(4)));

__device__ __forceinline__ ushort_t f2bf(float f) {
    unsigned u = __builtin_bit_cast(unsigned, f);
    unsigned r = (u + 0x7FFFu + ((u >> 16) & 1u)) >> 16;
    return (ushort_t)r;
}
__device__ __forceinline__ float bf2f(ushort_t h) {
    unsigned u = ((unsigned)h) << 16;
    return __builtin_bit_cast(float, u);
}

// ---------------- f32 -> bf16 convert ----------------
__global__ __launch_bounds__(256) void k_cvt(const float* __restrict__ in,
                                             ushort_t* __restrict__ out, int n) {
    int i = (blockIdx.x * 256 + threadIdx.x) * 4;
    if (i + 3 < n) {
        float4 v = *reinterpret_cast<const float4*>(in + i);
        ushort4 o;
        o.x = f2bf(v.x); o.y = f2bf(v.y); o.z = f2bf(v.z); o.w = f2bf(v.w);
        *reinterpret_cast<ushort4*>(out + i) = o;
    } else {
        for (; i < n; ++i) out[i] = f2bf(in[i]);
    }
}

// ---------------- generic bf16 MFMA GEMM: C[M,N] = A[M,K] * W[N,K]^T ----------------
// EPI: 0 = none, 1 = softplus(acc + bias[col])
template <int EPI, bool OUTBF>
__global__ __launch_bounds__(256) void k_gemm(
    const ushort_t* __restrict__ A, const ushort_t* __restrict__ Bw,
    void* __restrict__ C, const float* __restrict__ bias,
    int M, int N, int K, int lda, int ldb, int ldc) {
    __shared__ ushort_t As[128][72];  // +8 pad: 2-way bank conflict only (free)
    __shared__ ushort_t Bs[128][72];
    int tid = threadIdx.x;
    int lane = tid & 63, wid = tid >> 6;
    int wr = wid >> 1, wc = wid & 1;
    int row0 = blockIdx.x * 128, col0 = blockIdx.y * 128;

    f32x4 acc[4][4] = {};

    for (int k0 = 0; k0 < K; k0 += 64) {
        __syncthreads();
#pragma unroll
        for (int i = 0; i < 4; ++i) {
            int c = tid + i * 256;
            int r = c >> 3, cc = (c & 7) << 3;
            *reinterpret_cast<u16x8*>(&As[r][cc]) =
                *reinterpret_cast<const u16x8*>(&A[(size_t)(row0 + r) * lda + k0 + cc]);
            u16x8 bv = {};
            if (col0 + r < N)
                bv = *reinterpret_cast<const u16x8*>(&Bw[(size_t)(col0 + r) * ldb + k0 + cc]);
            *reinterpret_cast<u16x8*>(&Bs[r][cc]) = bv;
        }
        __syncthreads();
#pragma unroll
        for (int kk = 0; kk < 2; ++kk) {
            int ko = kk * 32 + (lane >> 4) * 8;
            bf16x8 af[4], bfr[4];
#pragma unroll
            for (int m = 0; m < 4; ++m)
                af[m] = *reinterpret_cast<const bf16x8*>(&As[wr * 64 + m * 16 + (lane & 15)][ko]);
#pragma unroll
            for (int n = 0; n < 4; ++n)
                bfr[n] = *reinterpret_cast<const bf16x8*>(&Bs[wc * 64 + n * 16 + (lane & 15)][ko]);
#pragma unroll
            for (int m = 0; m < 4; ++m)
#pragma unroll
                for (int n = 0; n < 4; ++n)
                    acc[m][n] = __builtin_amdgcn_mfma_f32_16x16x32_bf16(af[m], bfr[n], acc[m][n], 0, 0, 0);
        }
    }

#pragma unroll
    for (int m = 0; m < 4; ++m) {
#pragma unroll
        for (int n = 0; n < 4; ++n) {
            int col = col0 + wc * 64 + n * 16 + (lane & 15);
            if (col >= N) continue;
#pragma unroll
            for (int r = 0; r < 4; ++r) {
                int row = row0 + wr * 64 + m * 16 + (lane >> 4) * 4 + r;
                float v = acc[m][n][r];
                if (EPI == 1) {
                    v += bias[col];
                    v = (v > 20.f) ? v : log1pf(__expf(v));
                }
                if (OUTBF)
                    ((ushort_t*)C)[(size_t)row * ldc + col] = f2bf(v);
                else
                    ((float*)C)[(size_t)row * ldc + col] = v;
            }
        }
    }
}

// ---------------- depthwise causal conv (width 4) + SiLU ----------------
__global__ __launch_bounds__(256) void k_conv(const ushort_t* __restrict__ xz,
                                              const float* __restrict__ w,
                                              const float* __restrict__ bias,
                                              ushort_t* __restrict__ out) {
    int d = blockIdx.x * 256 + threadIdx.x;
    int b = blockIdx.z;
    int t0 = blockIdx.y * 128;
    float w0 = w[d * 4 + 0], w1 = w[d * 4 + 1], w2 = w[d * 4 + 2], w3 = w[d * 4 + 3];
    float bi = bias[d];
    size_t base = ((size_t)b * L_) * (2 * DI) + d;
    size_t obase = ((size_t)b * L_) * DI + d;
    float x0 = (t0 >= 3) ? bf2f(xz[base + (size_t)(t0 - 3) * (2 * DI)]) : 0.f;
    float x1 = (t0 >= 2) ? bf2f(xz[base + (size_t)(t0 - 2) * (2 * DI)]) : 0.f;
    float x2 = (t0 >= 1) ? bf2f(xz[base + (size_t)(t0 - 1) * (2 * DI)]) : 0.f;
    for (int t = t0; t < t0 + 128; ++t) {
        float cur = bf2f(xz[base + (size_t)t * (2 * DI)]);
        float v = w0 * x0 + w1 * x1 + w2 * x2 + w3 * cur + bi;
        v = v / (1.f + __expf(-v));
        out[obase + (size_t)t * DI] = f2bf(v);
        x0 = x1; x1 = x2; x2 = cur;
    }
}

// ---------------- chunked selective scan ----------------
// Phase 1: per-chunk local scan (h starts at 0) -> chunk-final h and sum(dt)
__global__ __launch_bounds__(256) void k_scan1(
    const float* __restrict__ dt, const ushort_t* __restrict__ xm,
    const ushort_t* __restrict__ dbc, const float* __restrict__ A_log,
    float* __restrict__ hfin, float* __restrict__ dtsum) {
    __shared__ float Bsh[LC][DSTATE];
    int tid = threadIdx.x;
    int d = blockIdx.x * 256 + tid;
    int c = blockIdx.y, b = blockIdx.z;
    float Arow[DSTATE];
#pragma unroll
    for (int s = 0; s < DSTATE; ++s) Arow[s] = -__expf(A_log[d * DSTATE + s]);
    size_t rbase = (size_t)b * L_ + (size_t)c * LC;
    // stage B for the chunk: LC*16 f32, 4 per thread
    {
        int i = tid * 4;
        int t = i >> 4, s0 = i & 15;
        u16x4 v = *reinterpret_cast<const u16x4*>(&dbc[(rbase + t) * 96 + DTR + s0]);
#pragma unroll
        for (int j = 0; j < 4; ++j) Bsh[t][s0 + j] = bf2f(v[j]);
    }
    __syncthreads();
    float h[DSTATE] = {};
    float sd = 0.f;
    for (int t = 0; t < LC; ++t) {
        size_t ro = rbase + t;
        float dtv = dt[ro * DI + d];
        float xv = bf2f(xm[ro * DI + d]);
        float dx = dtv * xv;
        sd += dtv;
#pragma unroll
        for (int s = 0; s < DSTATE; ++s)
            h[s] = __expf(dtv * Arow[s]) * h[s] + dx * Bsh[t][s];
    }
    size_t hbase = (((size_t)b * NC + c) * DI + d) * DSTATE;
#pragma unroll
    for (int s = 0; s < DSTATE; s += 4)
        *reinterpret_cast<f32x4*>(&hfin[hbase + s]) = *reinterpret_cast<f32x4*>(&h[s]);
    dtsum[((size_t)b * NC + c) * DI + d] = sd;
}

// Phase 2: sequential carry over chunks, per (b,d,s) lane. In-place: hfin
// becomes the carry-IN state for each chunk.
__global__ __launch_bounds__(256) void k_scan2(
    float* __restrict__ hfin, const float* __restrict__ dtsum,
    const float* __restrict__ A_log) {
    int gid = blockIdx.x * 256 + threadIdx.x;  // s fastest, then d, then b
    int s = gid & (DSTATE - 1);
    int d = (gid >> 4) & (DI - 1);
    int b = gid >> 15;
    float Av = -__expf(A_log[d * DSTATE + s]);
    float carry = 0.f;
    for (int c = 0; c < NC; ++c) {
        size_t idx = (((size_t)b * NC + c) * DI + d) * DSTATE + s;
        float loc = hfin[idx];
        hfin[idx] = carry;
        float sd = dtsum[((size_t)b * NC + c) * DI + d];
        carry = __expf(Av * sd) * carry + loc;
    }
}

// Phase 3: local scan with correct carry-in + D*x + z-gating -> yg (bf16)
__global__ __launch_bounds__(256) void k_scan3(
    const float* __restrict__ dt, const ushort_t* __restrict__ xm,
    const ushort_t* __restrict__ xz, const ushort_t* __restrict__ dbc,
    const float* __restrict__ A_log, const float* __restrict__ Dp,
    const float* __restrict__ hinit, ushort_t* __restrict__ yg) {
    __shared__ float Bsh[LC][DSTATE];
    __shared__ float Csh[LC][DSTATE];
    int tid = threadIdx.x;
    int d = blockIdx.x * 256 + tid;
    int c = blockIdx.y, b = blockIdx.z;
    float Arow[DSTATE];
#pragma unroll
    for (int s = 0; s < DSTATE; ++s) Arow[s] = -__expf(A_log[d * DSTATE + s]);
    float Dd = Dp[d];
    size_t rbase = (size_t)b * L_ + (size_t)c * LC;
    // stage B and C: LC*32 bf16, 8 per thread
    {
        int e0 = tid * 8;
        int t = e0 >> 5, s0 = e0 & 31;
        u16x8 v = *reinterpret_cast<const u16x8*>(&dbc[(rbase + t) * 96 + DTR + s0]);
#pragma unroll
        for (int j = 0; j < 8; ++j) {
            int s = s0 + j;
            float f = bf2f(v[j]);
            if (s < DSTATE) Bsh[t][s] = f;
            else Csh[t][s - DSTATE] = f;
        }
    }
    __syncthreads();
    float h[DSTATE];
    size_t hbase = (((size_t)b * NC + c) * DI + d) * DSTATE;
#pragma unroll
    for (int s = 0; s < DSTATE; s += 4)
        *reinterpret_cast<f32x4*>(&h[s]) = *reinterpret_cast<const f32x4*>(&hinit[hbase + s]);
    for (int t = 0; t < LC; ++t) {
        size_t ro = rbase + t;
        float dtv = dt[ro * DI + d];
        float xv = bf2f(xm[ro * DI + d]);
        float zv = bf2f(xz[ro * (2 * DI) + DI + d]);
        float dx = dtv * xv;
        float y = 0.f;
#pragma unroll
        for (int s = 0; s < DSTATE; ++s) {
            h[s] = __expf(dtv * Arow[s]) * h[s] + dx * Bsh[t][s];
            y += h[s] * Csh[t][s];
        }
        y += Dd * xv;
        y *= zv / (1.f + __expf(-zv));
        yg[ro * DI + d] = f2bf(y);
    }
}

// ---------------- residual + LayerNorm ----------------
__global__ __launch_bounds__(256) void k_ln(const float* __restrict__ mo,
                                            const float* __restrict__ x,
                                            const float* __restrict__ g,
                                            const float* __restrict__ be,
                                            float* __restrict__ out) {
    __shared__ float red[8];
    size_t r = blockIdx.x;
    int tid = threadIdx.x;
    float4 hv = *reinterpret_cast<const float4*>(&mo[r * DM + tid * 4]);
    float4 xv = *reinterpret_cast<const float4*>(&x[r * DM + tid * 4]);
    float h0 = hv.x + xv.x, h1 = hv.y + xv.y, h2 = hv.z + xv.z, h3 = hv.w + xv.w;
    float s = h0 + h1 + h2 + h3;
    float q = h0 * h0 + h1 * h1 + h2 * h2 + h3 * h3;
#pragma unroll
    for (int o = 32; o > 0; o >>= 1) {
        s += __shfl_down(s, o);
        q += __shfl_down(q, o);
    }
    int lane = tid & 63, wid = tid >> 6;
    if (lane == 0) { red[wid] = s; red[4 + wid] = q; }
    __syncthreads();
    s = red[0] + red[1] + red[2] + red[3];
    q = red[4] + red[5] + red[6] + red[7];
    float mu = s * (1.f / DM);
    float var = q * (1.f / DM) - mu * mu;
    float rs = rsqrtf(var + 1e-5f);
    float4 gv = *reinterpret_cast<const float4*>(&g[tid * 4]);
    float4 bv = *reinterpret_cast<const float4*>(&be[tid * 4]);
    float4 o;
    o.x = (h0 - mu) * rs * gv.x + bv.x;
    o.y = (h1 - mu) * rs * gv.y + bv.y;
    o.z = (h2 - mu) * rs * gv.z + bv.z;
    o.w = (h3 - mu) * rs * gv.w + bv.w;
    *reinterpret_cast<float4*>(&out[r * DM + tid * 4]) = o;
}

extern "C" void kernel_launch(void* const* d_in, const int* in_sizes, int n_in,
                              void* d_out, int out_size, void* d_ws, size_t ws_size,
                              hipStream_t stream) {
    const float* x      = (const float*)d_in[0];   // (B,L,DM)
    const float* w_in   = (const float*)d_in[1];   // (2*DI, DM)
    const float* conv_w = (const float*)d_in[2];   // (DI,1,4)
    const float* conv_b = (const float*)d_in[3];   // (DI)
    const float* w_xp   = (const float*)d_in[4];   // (96, DI)
    const float* w_dt   = (const float*)d_in[5];   // (DI, 64)
    const float* dt_b   = (const float*)d_in[6];   // (DI)
    const float* A_log  = (const float*)d_in[7];   // (DI,16)
    const float* Dp     = (const float*)d_in[8];   // (DI)
    const float* w_out  = (const float*)d_in[9];   // (DM, DI)
    const float* ln_g   = (const float*)d_in[10];
    const float* ln_b   = (const float*)d_in[11];
    float* out = (float*)d_out;

    char* ws = (char*)d_ws;
    size_t off = 0;
    auto alloc = [&](size_t bytes) -> void* {
        void* p = ws + off;
        off += (bytes + 255) & ~(size_t)255;
        return p;
    };
    const int M = B_ * L_;  // 8192
    ushort_t* w_in_b  = (ushort_t*)alloc((size_t)2 * DI * DM * 2);
    ushort_t* w_xp_b  = (ushort_t*)alloc((size_t)96 * DI * 2);
    ushort_t* w_dt_b  = (ushort_t*)alloc((size_t)DI * DTR * 2);
    ushort_t* w_out_b = (ushort_t*)alloc((size_t)DM * DI * 2);
    ushort_t* x_b     = (ushort_t*)alloc((size_t)M * DM * 2);  // 16 MB
    ushort_t* xz      = (ushort_t*)alloc((size_t)M * 2 * DI * 2);
    ushort_t* xm      = (ushort_t*)alloc((size_t)M * DI * 2);
    ushort_t* dbc     = (ushort_t*)alloc((size_t)M * 96 * 2);
    float*    dtb     = (float*)alloc((size_t)M * DI * 4);
    ushort_t* yg      = (ushort_t*)alloc((size_t)M * DI * 2);
    float*    dtsum   = (float*)alloc((size_t)B_ * NC * DI * 4);  // 1 MB
    float*    mo      = (float*)dtb;   // alias: dt dead after scan
    float*    hfin    = (float*)x_b;   // alias: x_b dead after in_proj (16 MB == 16 MB)

    auto cvt = [&](const float* src, ushort_t* dst, int n) {
        k_cvt<<<dim3((n / 4 + 255) / 256), 256, 0, stream>>>(src, dst, n);
    };
    cvt(w_in, w_in_b, 2 * DI * DM);
    cvt(w_xp, w_xp_b, 96 * DI);
    cvt(w_dt, w_dt_b, DI * DTR);
    cvt(w_out, w_out_b, DM * DI);
    cvt(x, x_b, M * DM);

    // in_proj: xz[M, 4096] = x[M,1024] @ w_in[4096,1024]^T
    k_gemm<0, true><<<dim3(64, 32), 256, 0, stream>>>(
        x_b, w_in_b, xz, nullptr, M, 2 * DI, DM, DM, DM, 2 * DI);
    // conv + silu
    k_conv<<<dim3(DI / 256, L_ / 128, B_), 256, 0, stream>>>(xz, conv_w, conv_b, xm);
    // x_proj: dbc[M,96] = xm @ w_xp[96,2048]^T
    k_gemm<0, true><<<dim3(64, 1), 256, 0, stream>>>(
        xm, w_xp_b, dbc, nullptr, M, 96, DI, DI, DI, 96);
    // dt_proj + softplus: dt[M,2048] = softplus(dbc[:, :64] @ w_dt^T + dt_b)
    k_gemm<1, false><<<dim3(64, 16), 256, 0, stream>>>(
        dbc, w_dt_b, dtb, dt_b, M, DI, DTR, 96, DTR, DI);
    // chunked selective scan
    k_scan1<<<dim3(DI / 256, NC, B_), 256, 0, stream>>>(dtb, xm, dbc, A_log, hfin, dtsum);
    k_scan2<<<dim3(B_ * DI * DSTATE / 256), 256, 0, stream>>>(hfin, dtsum, A_log);
    k_scan3<<<dim3(DI / 256, NC, B_), 256, 0, stream>>>(dtb, xm, xz, dbc, A_log, Dp, hfin, yg);
    // out_proj: mo[M,1024] = yg @ w_out[1024,2048]^T
    k_gemm<0, false><<<dim3(64, 8), 256, 0, stream>>>(
        yg, w_out_b, mo, nullptr, M, DM, DI, DI, DI, DM);
    // residual + layernorm
    k_ln<<<dim3(M), 256, 0, stream>>>(mo, x, ln_g, ln_b, out);
}

// Round 3
// 423.173 us; speedup vs baseline: 3.7981x; 1.2391x over previous
//
#include <hip/hip_runtime.h>
#include <hip/hip_bf16.h>

// Mamba block: B=4, L=2048, D_MODEL=1024, D_INNER=2048, D_STATE=16, DT_RANK=64
#define B_ 4
#define L_ 2048
#define DM 1024
#define DI 2048
#define DSTATE 16
#define DTR 64
#define LC 64            // scan chunk length
#define NC (L_ / LC)     // 32 chunks

typedef unsigned short ushort_t;
typedef __bf16 bf16x8 __attribute__((ext_vector_type(8)));
typedef float f32x4 __attribute__((ext_vector_type(4)));
typedef unsigned short u16x8 __attribute__((ext_vector_type(8)));
typedef unsigned short u16x4 __attribute__((ext_vector_type(4)));

__device__ __forceinline__ ushort_t f2bf(float f) {
    unsigned u = __builtin_bit_cast(unsigned, f);
    unsigned r = (u + 0x7FFFu + ((u >> 16) & 1u)) >> 16;
    return (ushort_t)r;
}
__device__ __forceinline__ float bf2f(ushort_t h) {
    unsigned u = ((unsigned)h) << 16;
    return __builtin_bit_cast(float, u);
}

// ---------------- f32 -> bf16 convert ----------------
__global__ __launch_bounds__(256) void k_cvt(const float* __restrict__ in,
                                             ushort_t* __restrict__ out, int n) {
    int i = (blockIdx.x * 256 + threadIdx.x) * 4;
    if (i + 3 < n) {
        float4 v = *reinterpret_cast<const float4*>(in + i);
        ushort4 o;
        o.x = f2bf(v.x); o.y = f2bf(v.y); o.z = f2bf(v.z); o.w = f2bf(v.w);
        *reinterpret_cast<ushort4*>(out + i) = o;
    } else {
        for (; i < n; ++i) out[i] = f2bf(in[i]);
    }
}

// ---------------- m97-structure bf16 MFMA GEMM: C[M,N] = A[M,K] * W[N,K]^T ----
// global_load_lds 16B staging into linear LDS [128][64] with both-sides XOR
// swizzle (source pre-swizzle on stage, XOR on ds_read) -> conflict-free reads.
// EPI: 0 = none, 1 = softplus(acc + bias[col]).  OUTBF: bf16 vs f32 output.
// gridDim.z = split-K count (f32 partials at C + z*M*ldc when OUTBF=false).
template <int EPI, bool OUTBF>
__global__ __launch_bounds__(256) void k_gemm2(
    const ushort_t* __restrict__ A, const ushort_t* __restrict__ Bw,
    void* __restrict__ C, const float* __restrict__ bias,
    int M, int N, int K, int lda, int ldb, int ldc, int tilesM) {
    __shared__ ushort_t As[128 * 64];  // 16 KB, linear (global_load_lds dest)
    __shared__ ushort_t Bs[128 * 64];
    int tid = threadIdx.x;
    int lane = tid & 63, wv = tid >> 6;
    int wr = wv >> 1, wc = wv & 1;
    // XCD-aware bijective swizzle (launches guarantee gridDim.x % 8 == 0)
    int nwg = gridDim.x, bid = blockIdx.x;
    int swz = (bid & 7) * (nwg >> 3) + (bid >> 3);
    int row0 = (swz % tilesM) * 128, col0 = (swz / tilesM) * 128;
    int kchunk = K / gridDim.z;
    int kbeg = blockIdx.z * kchunk, kend = kbeg + kchunk;
    float* Cf = (float*)C + (size_t)blockIdx.z * (size_t)M * ldc;

    int sr = lane >> 3;   // sub-row within an 8-row staging slot
    int sj = lane & 7;    // 16B chunk within the 128B row
    f32x4 acc[4][4] = {};

    for (int k0 = kbeg; k0 < kend; k0 += 64) {
        __syncthreads();
#pragma unroll
        for (int i = 0; i < 4; ++i) {
            int slot = wv * 4 + i;          // 16 slots of 8 rows x 64 cols
            int r = slot * 8 + sr;
            int jA = sj ^ (r & 7);          // pre-swizzled source chunk
            __builtin_amdgcn_global_load_lds(
                (const __attribute__((address_space(1))) void*)&A[(size_t)(row0 + r) * lda + k0 + jA * 8],
                (__attribute__((address_space(3))) void*)&As[slot * 512], 16, 0, 0);
            __builtin_amdgcn_global_load_lds(
                (const __attribute__((address_space(1))) void*)&Bw[(size_t)(col0 + r) * ldb + k0 + jA * 8],
                (__attribute__((address_space(3))) void*)&Bs[slot * 512], 16, 0, 0);
        }
        __syncthreads();
#pragma unroll
        for (int kk = 0; kk < 2; ++kk) {
            int co = kk * 32 + (lane >> 4) * 8;
            int sx = (lane & 7) << 3;       // read-side swizzle (row&7)<<3
            bf16x8 af[4], bfr[4];
#pragma unroll
            for (int m = 0; m < 4; ++m) {
                int rw = wr * 64 + m * 16 + (lane & 15);
                af[m] = *reinterpret_cast<const bf16x8*>(&As[rw * 64 + (co ^ sx)]);
            }
#pragma unroll
            for (int n = 0; n < 4; ++n) {
                int rw = wc * 64 + n * 16 + (lane & 15);
                bfr[n] = *reinterpret_cast<const bf16x8*>(&Bs[rw * 64 + (co ^ sx)]);
            }
#pragma unroll
            for (int m = 0; m < 4; ++m)
#pragma unroll
                for (int n = 0; n < 4; ++n)
                    acc[m][n] = __builtin_amdgcn_mfma_f32_16x16x32_bf16(af[m], bfr[n], acc[m][n], 0, 0, 0);
        }
    }

#pragma unroll
    for (int m = 0; m < 4; ++m) {
#pragma unroll
        for (int n = 0; n < 4; ++n) {
            int col = col0 + wc * 64 + n * 16 + (lane & 15);
            if (col >= N) continue;
#pragma unroll
            for (int r = 0; r < 4; ++r) {
                int row = row0 + wr * 64 + m * 16 + (lane >> 4) * 4 + r;
                float v = acc[m][n][r];
                if (EPI == 1) {
                    v += bias[col];
                    v = (v > 20.f) ? v : log1pf(__expf(v));
                }
                if (OUTBF)
                    ((ushort_t*)C)[(size_t)row * ldc + col] = f2bf(v);
                else
                    Cf[(size_t)row * ldc + col] = v;
            }
        }
    }
}

// ---------------- split-K partial reduce (4 partials f32 -> bf16) ------------
__global__ __launch_bounds__(256) void k_red4(const float* __restrict__ p,
                                              ushort_t* __restrict__ o,
                                              int n, int stride) {
    int i = (blockIdx.x * 256 + threadIdx.x) * 4;
    if (i >= n) return;
    f32x4 a = *reinterpret_cast<const f32x4*>(&p[i]);
    f32x4 b = *reinterpret_cast<const f32x4*>(&p[i + stride]);
    f32x4 c = *reinterpret_cast<const f32x4*>(&p[i + 2 * stride]);
    f32x4 d = *reinterpret_cast<const f32x4*>(&p[i + 3 * stride]);
    ushort4 r;
    r.x = f2bf(a[0] + b[0] + c[0] + d[0]);
    r.y = f2bf(a[1] + b[1] + c[1] + d[1]);
    r.z = f2bf(a[2] + b[2] + c[2] + d[2]);
    r.w = f2bf(a[3] + b[3] + c[3] + d[3]);
    *reinterpret_cast<ushort4*>(&o[i]) = r;
}

// ---------------- depthwise causal conv (width 4) + SiLU ----------------
__global__ __launch_bounds__(256) void k_conv(const ushort_t* __restrict__ xz,
                                              const float* __restrict__ w,
                                              const float* __restrict__ bias,
                                              ushort_t* __restrict__ out) {
    int d = blockIdx.x * 256 + threadIdx.x;
    int b = blockIdx.z;
    int t0 = blockIdx.y * 128;
    float w0 = w[d * 4 + 0], w1 = w[d * 4 + 1], w2 = w[d * 4 + 2], w3 = w[d * 4 + 3];
    float bi = bias[d];
    size_t base = ((size_t)b * L_) * (2 * DI) + d;
    size_t obase = ((size_t)b * L_) * DI + d;
    float x0 = (t0 >= 3) ? bf2f(xz[base + (size_t)(t0 - 3) * (2 * DI)]) : 0.f;
    float x1 = (t0 >= 2) ? bf2f(xz[base + (size_t)(t0 - 2) * (2 * DI)]) : 0.f;
    float x2 = (t0 >= 1) ? bf2f(xz[base + (size_t)(t0 - 1) * (2 * DI)]) : 0.f;
    for (int t = t0; t < t0 + 128; ++t) {
        float cur = bf2f(xz[base + (size_t)t * (2 * DI)]);
        float v = w0 * x0 + w1 * x1 + w2 * x2 + w3 * cur + bi;
        v = v / (1.f + __expf(-v));
        out[obase + (size_t)t * DI] = f2bf(v);
        x0 = x1; x1 = x2; x2 = cur;
    }
}

// ---------------- chunked selective scan ----------------
// Phase 1: per-chunk local scan (h starts at 0) -> chunk-final h and sum(dt)
__global__ __launch_bounds__(256) void k_scan1(
    const ushort_t* __restrict__ dt, const ushort_t* __restrict__ xm,
    const ushort_t* __restrict__ dbc, const float* __restrict__ A_log,
    float* __restrict__ hfin, float* __restrict__ dtsum) {
    __shared__ float Bsh[LC][DSTATE];
    int tid = threadIdx.x;
    int d = blockIdx.x * 256 + tid;
    int c = blockIdx.y, b = blockIdx.z;
    float Arow[DSTATE];
#pragma unroll
    for (int s = 0; s < DSTATE; ++s) Arow[s] = -__expf(A_log[d * DSTATE + s]);
    size_t rbase = (size_t)b * L_ + (size_t)c * LC;
    {
        int i = tid * 4;
        int t = i >> 4, s0 = i & 15;
        u16x4 v = *reinterpret_cast<const u16x4*>(&dbc[(rbase + t) * 96 + DTR + s0]);
#pragma unroll
        for (int j = 0; j < 4; ++j) Bsh[t][s0 + j] = bf2f(v[j]);
    }
    __syncthreads();
    float h[DSTATE] = {};
    float sd = 0.f;
    for (int t = 0; t < LC; ++t) {
        size_t ro = rbase + t;
        float dtv = bf2f(dt[ro * DI + d]);
        float xv = bf2f(xm[ro * DI + d]);
        float dx = dtv * xv;
        sd += dtv;
#pragma unroll
        for (int s = 0; s < DSTATE; ++s)
            h[s] = __expf(dtv * Arow[s]) * h[s] + dx * Bsh[t][s];
    }
    size_t hbase = (((size_t)b * NC + c) * DI + d) * DSTATE;
#pragma unroll
    for (int s = 0; s < DSTATE; s += 4)
        *reinterpret_cast<f32x4*>(&hfin[hbase + s]) = *reinterpret_cast<f32x4*>(&h[s]);
    dtsum[((size_t)b * NC + c) * DI + d] = sd;
}

// Phase 2: sequential carry over chunks; hfin becomes carry-IN per chunk.
__global__ __launch_bounds__(256) void k_scan2(
    float* __restrict__ hfin, const float* __restrict__ dtsum,
    const float* __restrict__ A_log) {
    int gid = blockIdx.x * 256 + threadIdx.x;  // s fastest, then d, then b
    int s = gid & (DSTATE - 1);
    int d = (gid >> 4) & (DI - 1);
    int b = gid >> 15;
    float Av = -__expf(A_log[d * DSTATE + s]);
    float carry = 0.f;
    for (int c = 0; c < NC; ++c) {
        size_t idx = (((size_t)b * NC + c) * DI + d) * DSTATE + s;
        float loc = hfin[idx];
        hfin[idx] = carry;
        float sd = dtsum[((size_t)b * NC + c) * DI + d];
        carry = __expf(Av * sd) * carry + loc;
    }
}

// Phase 3: local scan with carry-in + D*x + z-gating -> yg (bf16)
__global__ __launch_bounds__(256) void k_scan3(
    const ushort_t* __restrict__ dt, const ushort_t* __restrict__ xm,
    const ushort_t* __restrict__ xz, const ushort_t* __restrict__ dbc,
    const float* __restrict__ A_log, const float* __restrict__ Dp,
    const float* __restrict__ hinit, ushort_t* __restrict__ yg) {
    __shared__ float Bsh[LC][DSTATE];
    __shared__ float Csh[LC][DSTATE];
    int tid = threadIdx.x;
    int d = blockIdx.x * 256 + tid;
    int c = blockIdx.y, b = blockIdx.z;
    float Arow[DSTATE];
#pragma unroll
    for (int s = 0; s < DSTATE; ++s) Arow[s] = -__expf(A_log[d * DSTATE + s]);
    float Dd = Dp[d];
    size_t rbase = (size_t)b * L_ + (size_t)c * LC;
    {
        int e0 = tid * 8;
        int t = e0 >> 5, s0 = e0 & 31;
        u16x8 v = *reinterpret_cast<const u16x8*>(&dbc[(rbase + t) * 96 + DTR + s0]);
#pragma unroll
        for (int j = 0; j < 8; ++j) {
            int s = s0 + j;
            float f = bf2f(v[j]);
            if (s < DSTATE) Bsh[t][s] = f;
            else Csh[t][s - DSTATE] = f;
        }
    }
    __syncthreads();
    float h[DSTATE];
    size_t hbase = (((size_t)b * NC + c) * DI + d) * DSTATE;
#pragma unroll
    for (int s = 0; s < DSTATE; s += 4)
        *reinterpret_cast<f32x4*>(&h[s]) = *reinterpret_cast<const f32x4*>(&hinit[hbase + s]);
    for (int t = 0; t < LC; ++t) {
        size_t ro = rbase + t;
        float dtv = bf2f(dt[ro * DI + d]);
        float xv = bf2f(xm[ro * DI + d]);
        float zv = bf2f(xz[ro * (2 * DI) + DI + d]);
        float dx = dtv * xv;
        float y = 0.f;
#pragma unroll
        for (int s = 0; s < DSTATE; ++s) {
            h[s] = __expf(dtv * Arow[s]) * h[s] + dx * Bsh[t][s];
            y += h[s] * Csh[t][s];
        }
        y += Dd * xv;
        y *= zv / (1.f + __expf(-zv));
        yg[ro * DI + d] = f2bf(y);
    }
}

// ---------------- residual + LayerNorm ----------------
__global__ __launch_bounds__(256) void k_ln(const float* __restrict__ mo,
                                            const float* __restrict__ x,
                                            const float* __restrict__ g,
                                            const float* __restrict__ be,
                                            float* __restrict__ out) {
    __shared__ float red[8];
    size_t r = blockIdx.x;
    int tid = threadIdx.x;
    float4 hv = *reinterpret_cast<const float4*>(&mo[r * DM + tid * 4]);
    float4 xv = *reinterpret_cast<const float4*>(&x[r * DM + tid * 4]);
    float h0 = hv.x + xv.x, h1 = hv.y + xv.y, h2 = hv.z + xv.z, h3 = hv.w + xv.w;
    float s = h0 + h1 + h2 + h3;
    float q = h0 * h0 + h1 * h1 + h2 * h2 + h3 * h3;
#pragma unroll
    for (int o = 32; o > 0; o >>= 1) {
        s += __shfl_down(s, o);
        q += __shfl_down(q, o);
    }
    int lane = tid & 63, wid = tid >> 6;
    if (lane == 0) { red[wid] = s; red[4 + wid] = q; }
    __syncthreads();
    s = red[0] + red[1] + red[2] + red[3];
    q = red[4] + red[5] + red[6] + red[7];
    float mu = s * (1.f / DM);
    float var = q * (1.f / DM) - mu * mu;
    float rs = rsqrtf(var + 1e-5f);
    float4 gv = *reinterpret_cast<const float4*>(&g[tid * 4]);
    float4 bv = *reinterpret_cast<const float4*>(&be[tid * 4]);
    float4 o;
    o.x = (h0 - mu) * rs * gv.x + bv.x;
    o.y = (h1 - mu) * rs * gv.y + bv.y;
    o.z = (h2 - mu) * rs * gv.z + bv.z;
    o.w = (h3 - mu) * rs * gv.w + bv.w;
    *reinterpret_cast<float4*>(&out[r * DM + tid * 4]) = o;
}

extern "C" void kernel_launch(void* const* d_in, const int* in_sizes, int n_in,
                              void* d_out, int out_size, void* d_ws, size_t ws_size,
                              hipStream_t stream) {
    const float* x      = (const float*)d_in[0];   // (B,L,DM)
    const float* w_in   = (const float*)d_in[1];   // (2*DI, DM)
    const float* conv_w = (const float*)d_in[2];   // (DI,1,4)
    const float* conv_b = (const float*)d_in[3];   // (DI)
    const float* w_xp   = (const float*)d_in[4];   // (96, DI)
    const float* w_dt   = (const float*)d_in[5];   // (DI, 64)
    const float* dt_b   = (const float*)d_in[6];   // (DI)
    const float* A_log  = (const float*)d_in[7];   // (DI,16)
    const float* Dp     = (const float*)d_in[8];   // (DI)
    const float* w_out  = (const float*)d_in[9];   // (DM, DI)
    const float* ln_g   = (const float*)d_in[10];
    const float* ln_b   = (const float*)d_in[11];
    float* out = (float*)d_out;

    char* ws = (char*)d_ws;
    size_t off = 0;
    auto alloc = [&](size_t bytes) -> void* {
        void* p = ws + off;
        off += (bytes + 255) & ~(size_t)255;
        return p;
    };
    const int M = B_ * L_;  // 8192
    ushort_t* w_in_b  = (ushort_t*)alloc((size_t)2 * DI * DM * 2);
    ushort_t* w_xp_b  = (ushort_t*)alloc((size_t)96 * DI * 2);
    ushort_t* w_dt_b  = (ushort_t*)alloc((size_t)DI * DTR * 2);
    ushort_t* w_out_b = (ushort_t*)alloc((size_t)DM * DI * 2);
    ushort_t* x_b     = (ushort_t*)alloc((size_t)M * DM * 2);   // 16.8 MB
    ushort_t* xz      = (ushort_t*)alloc((size_t)M * 2 * DI * 2);
    ushort_t* xm      = (ushort_t*)alloc((size_t)M * DI * 2);
    ushort_t* dbc     = (ushort_t*)alloc((size_t)M * 96 * 2);
    ushort_t* dtb     = (ushort_t*)alloc((size_t)M * DI * 2);   // bf16 dt (33.5 MB)
    ushort_t* yg      = (ushort_t*)alloc((size_t)M * DI * 2);
    float*    dtsum   = (float*)alloc((size_t)B_ * NC * DI * 4);
    float*    dbc_p   = (float*)alloc((size_t)4 * M * 96 * 4);  // split-K partials
    float*    mo      = (float*)dtb;   // alias: dt dead after scan3 (33.5 MB both)
    float*    hfin    = (float*)x_b;   // alias: x_b dead after in_proj (16.8 MB both)

    auto cvt = [&](const float* src, ushort_t* dst, int n) {
        k_cvt<<<dim3((n / 4 + 255) / 256), 256, 0, stream>>>(src, dst, n);
    };
    cvt(w_in, w_in_b, 2 * DI * DM);
    cvt(w_xp, w_xp_b, 96 * DI);
    cvt(w_dt, w_dt_b, DI * DTR);
    cvt(w_out, w_out_b, DM * DI);
    cvt(x, x_b, M * DM);

    // in_proj: xz[M,4096] = x[M,1024] @ w_in[4096,1024]^T  (2048 tiles)
    k_gemm2<0, true><<<dim3(64 * 32, 1, 1), 256, 0, stream>>>(
        x_b, w_in_b, xz, nullptr, M, 2 * DI, DM, DM, DM, 2 * DI, 64);
    // conv + silu
    k_conv<<<dim3(DI / 256, L_ / 128, B_), 256, 0, stream>>>(xz, conv_w, conv_b, xm);
    // x_proj (split-K=4): dbc_p[z][M,96] = xm @ w_xp[96,2048]^T (K chunk 512)
    k_gemm2<0, false><<<dim3(64, 1, 4), 256, 0, stream>>>(
        xm, w_xp_b, dbc_p, nullptr, M, 96, DI, DI, DI, 96, 64);
    k_red4<<<dim3((M * 96 / 4 + 255) / 256), 256, 0, stream>>>(dbc_p, dbc, M * 96, M * 96);
    // dt_proj + softplus -> bf16: dt[M,2048] = softplus(dbc[:,:64] @ w_dt^T + b)
    k_gemm2<1, true><<<dim3(64 * 16, 1, 1), 256, 0, stream>>>(
        dbc, w_dt_b, dtb, dt_b, M, DI, DTR, 96, DTR, DI, 64);
    // chunked selective scan
    k_scan1<<<dim3(DI / 256, NC, B_), 256, 0, stream>>>(dtb, xm, dbc, A_log, hfin, dtsum);
    k_scan2<<<dim3(B_ * DI * DSTATE / 256), 256, 0, stream>>>(hfin, dtsum, A_log);
    k_scan3<<<dim3(DI / 256, NC, B_), 256, 0, stream>>>(dtb, xm, xz, dbc, A_log, Dp, hfin, yg);
    // out_proj: mo[M,1024] = yg @ w_out[1024,2048]^T
    k_gemm2<0, false><<<dim3(64 * 8, 1, 1), 256, 0, stream>>>(
        yg, w_out_b, mo, nullptr, M, DM, DI, DI, DI, DM, 64);
    // residual + layernorm
    k_ln<<<dim3(M), 256, 0, stream>>>(mo, x, ln_g, ln_b, out);
}

// Round 4
// 408.384 us; speedup vs baseline: 3.9356x; 1.0362x over previous
//
#include <hip/hip_runtime.h>
#include <hip/hip_bf16.h>

// Mamba block: B=4, L=2048, D_MODEL=1024, D_INNER=2048, D_STATE=16, DT_RANK=64
#define B_ 4
#define L_ 2048
#define DM 1024
#define DI 2048
#define DSTATE 16
#define DTR 64
#define LC 64            // scan chunk length
#define NC (L_ / LC)     // 32 chunks

typedef unsigned short ushort_t;
typedef __bf16 bf16x8 __attribute__((ext_vector_type(8)));
typedef float f32x4 __attribute__((ext_vector_type(4)));
typedef unsigned short u16x8 __attribute__((ext_vector_type(8)));
typedef unsigned short u16x4 __attribute__((ext_vector_type(4)));

__device__ __forceinline__ ushort_t f2bf(float f) {
    unsigned u = __builtin_bit_cast(unsigned, f);
    unsigned r = (u + 0x7FFFu + ((u >> 16) & 1u)) >> 16;
    return (ushort_t)r;
}
__device__ __forceinline__ float bf2f(ushort_t h) {
    unsigned u = ((unsigned)h) << 16;
    return __builtin_bit_cast(float, u);
}

// ---------------- f32 -> bf16 convert ----------------
__global__ __launch_bounds__(256) void k_cvt(const float* __restrict__ in,
                                             ushort_t* __restrict__ out, int n) {
    int i = (blockIdx.x * 256 + threadIdx.x) * 4;
    if (i + 3 < n) {
        float4 v = *reinterpret_cast<const float4*>(in + i);
        ushort4 o;
        o.x = f2bf(v.x); o.y = f2bf(v.y); o.z = f2bf(v.z); o.w = f2bf(v.w);
        *reinterpret_cast<ushort4*>(out + i) = o;
    } else {
        for (; i < n; ++i) out[i] = f2bf(in[i]);
    }
}

// ---------------- m97-structure bf16 MFMA GEMM: C[M,N] = A[M,K] * W[N,K]^T ----
// global_load_lds 16B staging into linear LDS [128][64] with both-sides XOR
// swizzle (source pre-swizzle on stage, XOR on ds_read) -> conflict-free reads.
// Tile order: GM=8 supertile (8 M-tiles x tilesN) so the ~256 co-resident
// blocks' working set (~10 MB) fits aggregate L2 -> A/B re-reads are L2 hits.
// EPI: 0 = none, 1 = softplus(acc + bias[col]).  OUTBF: bf16 vs f32 output.
// gridDim.z = split-K count (f32 partials at C + z*M*ldc when OUTBF=false).
template <int EPI, bool OUTBF>
__global__ __launch_bounds__(256) void k_gemm2(
    const ushort_t* __restrict__ A, const ushort_t* __restrict__ Bw,
    void* __restrict__ C, const float* __restrict__ bias,
    int M, int N, int K, int lda, int ldb, int ldc, int tilesM) {
    __shared__ ushort_t As[128 * 64];  // 16 KB, linear (global_load_lds dest)
    __shared__ ushort_t Bs[128 * 64];
    int tid = threadIdx.x;
    int lane = tid & 63, wv = tid >> 6;
    int wr = wv >> 1, wc = wv & 1;
    // GM=8 supertile mapping (tilesM % 8 == 0 for all launches)
    int bid = blockIdx.x;
    int tilesN = gridDim.x / tilesM;
    int per = 8 * tilesN;
    int grp = bid / per, within = bid % per;
    int tm = grp * 8 + (within & 7);
    int tn = within >> 3;
    int row0 = tm * 128, col0 = tn * 128;
    int kchunk = K / gridDim.z;
    int kbeg = blockIdx.z * kchunk, kend = kbeg + kchunk;
    float* Cf = (float*)C + (size_t)blockIdx.z * (size_t)M * ldc;

    int sr = lane >> 3;   // sub-row within an 8-row staging slot
    int sj = lane & 7;    // 16B chunk within the 128B row
    f32x4 acc[4][4] = {};

    for (int k0 = kbeg; k0 < kend; k0 += 64) {
        __syncthreads();
#pragma unroll
        for (int i = 0; i < 4; ++i) {
            int slot = wv * 4 + i;          // 16 slots of 8 rows x 64 cols
            int r = slot * 8 + sr;
            int jA = sj ^ (r & 7);          // pre-swizzled source chunk
            __builtin_amdgcn_global_load_lds(
                (const __attribute__((address_space(1))) void*)&A[(size_t)(row0 + r) * lda + k0 + jA * 8],
                (__attribute__((address_space(3))) void*)&As[slot * 512], 16, 0, 0);
            __builtin_amdgcn_global_load_lds(
                (const __attribute__((address_space(1))) void*)&Bw[(size_t)(col0 + r) * ldb + k0 + jA * 8],
                (__attribute__((address_space(3))) void*)&Bs[slot * 512], 16, 0, 0);
        }
        __syncthreads();
#pragma unroll
        for (int kk = 0; kk < 2; ++kk) {
            int co = kk * 32 + (lane >> 4) * 8;
            int sx = (lane & 7) << 3;       // read-side swizzle (row&7)<<3
            bf16x8 af[4], bfr[4];
#pragma unroll
            for (int m = 0; m < 4; ++m) {
                int rw = wr * 64 + m * 16 + (lane & 15);
                af[m] = *reinterpret_cast<const bf16x8*>(&As[rw * 64 + (co ^ sx)]);
            }
#pragma unroll
            for (int n = 0; n < 4; ++n) {
                int rw = wc * 64 + n * 16 + (lane & 15);
                bfr[n] = *reinterpret_cast<const bf16x8*>(&Bs[rw * 64 + (co ^ sx)]);
            }
#pragma unroll
            for (int m = 0; m < 4; ++m)
#pragma unroll
                for (int n = 0; n < 4; ++n)
                    acc[m][n] = __builtin_amdgcn_mfma_f32_16x16x32_bf16(af[m], bfr[n], acc[m][n], 0, 0, 0);
        }
    }

#pragma unroll
    for (int m = 0; m < 4; ++m) {
#pragma unroll
        for (int n = 0; n < 4; ++n) {
            int col = col0 + wc * 64 + n * 16 + (lane & 15);
            if (col >= N) continue;
#pragma unroll
            for (int r = 0; r < 4; ++r) {
                int row = row0 + wr * 64 + m * 16 + (lane >> 4) * 4 + r;
                float v = acc[m][n][r];
                if (EPI == 1) {
                    v += bias[col];
                    v = (v > 20.f) ? v : log1pf(__expf(v));
                }
                if (OUTBF)
                    ((ushort_t*)C)[(size_t)row * ldc + col] = f2bf(v);
                else
                    Cf[(size_t)row * ldc + col] = v;
            }
        }
    }
}

// ---------------- split-K partial reduce (4 partials f32 -> bf16) ------------
__global__ __launch_bounds__(256) void k_red4(const float* __restrict__ p,
                                              ushort_t* __restrict__ o,
                                              int n, int stride) {
    int i = (blockIdx.x * 256 + threadIdx.x) * 4;
    if (i >= n) return;
    f32x4 a = *reinterpret_cast<const f32x4*>(&p[i]);
    f32x4 b = *reinterpret_cast<const f32x4*>(&p[i + stride]);
    f32x4 c = *reinterpret_cast<const f32x4*>(&p[i + 2 * stride]);
    f32x4 d = *reinterpret_cast<const f32x4*>(&p[i + 3 * stride]);
    ushort4 r;
    r.x = f2bf(a[0] + b[0] + c[0] + d[0]);
    r.y = f2bf(a[1] + b[1] + c[1] + d[1]);
    r.z = f2bf(a[2] + b[2] + c[2] + d[2]);
    r.w = f2bf(a[3] + b[3] + c[3] + d[3]);
    *reinterpret_cast<ushort4*>(&o[i]) = r;
}

// ---------------- depthwise causal conv (width 4) + SiLU ----------------
__global__ __launch_bounds__(256) void k_conv(const ushort_t* __restrict__ xz,
                                              const float* __restrict__ w,
                                              const float* __restrict__ bias,
                                              ushort_t* __restrict__ out) {
    int d = blockIdx.x * 256 + threadIdx.x;
    int b = blockIdx.z;
    int t0 = blockIdx.y * 128;
    float w0 = w[d * 4 + 0], w1 = w[d * 4 + 1], w2 = w[d * 4 + 2], w3 = w[d * 4 + 3];
    float bi = bias[d];
    size_t base = ((size_t)b * L_) * (2 * DI) + d;
    size_t obase = ((size_t)b * L_) * DI + d;
    float x0 = (t0 >= 3) ? bf2f(xz[base + (size_t)(t0 - 3) * (2 * DI)]) : 0.f;
    float x1 = (t0 >= 2) ? bf2f(xz[base + (size_t)(t0 - 2) * (2 * DI)]) : 0.f;
    float x2 = (t0 >= 1) ? bf2f(xz[base + (size_t)(t0 - 1) * (2 * DI)]) : 0.f;
    for (int t = t0; t < t0 + 128; ++t) {
        float cur = bf2f(xz[base + (size_t)t * (2 * DI)]);
        float v = w0 * x0 + w1 * x1 + w2 * x2 + w3 * cur + bi;
        v = v / (1.f + __expf(-v));
        out[obase + (size_t)t * DI] = f2bf(v);
        x0 = x1; x1 = x2; x2 = cur;
    }
}

// ---------------- chunked selective scan ----------------
// Phase 1: per-chunk local scan (h starts at 0) -> chunk-final h and sum(dt)
__global__ __launch_bounds__(256) void k_scan1(
    const ushort_t* __restrict__ dt, const ushort_t* __restrict__ xm,
    const ushort_t* __restrict__ dbc, const float* __restrict__ A_log,
    float* __restrict__ hfin, float* __restrict__ dtsum) {
    __shared__ float Bsh[LC][DSTATE];
    int tid = threadIdx.x;
    int d = blockIdx.x * 256 + tid;
    int c = blockIdx.y, b = blockIdx.z;
    float Arow[DSTATE];
#pragma unroll
    for (int s = 0; s < DSTATE; ++s) Arow[s] = -__expf(A_log[d * DSTATE + s]);
    size_t rbase = (size_t)b * L_ + (size_t)c * LC;
    {
        int i = tid * 4;
        int t = i >> 4, s0 = i & 15;
        u16x4 v = *reinterpret_cast<const u16x4*>(&dbc[(rbase + t) * 96 + DTR + s0]);
#pragma unroll
        for (int j = 0; j < 4; ++j) Bsh[t][s0 + j] = bf2f(v[j]);
    }
    __syncthreads();
    float h[DSTATE] = {};
    float sd = 0.f;
    for (int t = 0; t < LC; ++t) {
        size_t ro = rbase + t;
        float dtv = bf2f(dt[ro * DI + d]);
        float xv = bf2f(xm[ro * DI + d]);
        float dx = dtv * xv;
        sd += dtv;
#pragma unroll
        for (int s = 0; s < DSTATE; ++s)
            h[s] = __expf(dtv * Arow[s]) * h[s] + dx * Bsh[t][s];
    }
    size_t hbase = (((size_t)b * NC + c) * DI + d) * DSTATE;
#pragma unroll
    for (int s = 0; s < DSTATE; s += 4)
        *reinterpret_cast<f32x4*>(&hfin[hbase + s]) = *reinterpret_cast<f32x4*>(&h[s]);
    dtsum[((size_t)b * NC + c) * DI + d] = sd;
}

// Phase 2: sequential carry over chunks; hfin becomes carry-IN per chunk.
__global__ __launch_bounds__(256) void k_scan2(
    float* __restrict__ hfin, const float* __restrict__ dtsum,
    const float* __restrict__ A_log) {
    int gid = blockIdx.x * 256 + threadIdx.x;  // s fastest, then d, then b
    int s = gid & (DSTATE - 1);
    int d = (gid >> 4) & (DI - 1);
    int b = gid >> 15;
    float Av = -__expf(A_log[d * DSTATE + s]);
    float carry = 0.f;
    for (int c = 0; c < NC; ++c) {
        size_t idx = (((size_t)b * NC + c) * DI + d) * DSTATE + s;
        float loc = hfin[idx];
        hfin[idx] = carry;
        float sd = dtsum[((size_t)b * NC + c) * DI + d];
        carry = __expf(Av * sd) * carry + loc;
    }
}

// Phase 3: local scan with carry-in + D*x + z-gating -> yg (bf16)
__global__ __launch_bounds__(256) void k_scan3(
    const ushort_t* __restrict__ dt, const ushort_t* __restrict__ xm,
    const ushort_t* __restrict__ xz, const ushort_t* __restrict__ dbc,
    const float* __restrict__ A_log, const float* __restrict__ Dp,
    const float* __restrict__ hinit, ushort_t* __restrict__ yg) {
    __shared__ float Bsh[LC][DSTATE];
    __shared__ float Csh[LC][DSTATE];
    int tid = threadIdx.x;
    int d = blockIdx.x * 256 + tid;
    int c = blockIdx.y, b = blockIdx.z;
    float Arow[DSTATE];
#pragma unroll
    for (int s = 0; s < DSTATE; ++s) Arow[s] = -__expf(A_log[d * DSTATE + s]);
    float Dd = Dp[d];
    size_t rbase = (size_t)b * L_ + (size_t)c * LC;
    {
        int e0 = tid * 8;
        int t = e0 >> 5, s0 = e0 & 31;
        u16x8 v = *reinterpret_cast<const u16x8*>(&dbc[(rbase + t) * 96 + DTR + s0]);
#pragma unroll
        for (int j = 0; j < 8; ++j) {
            int s = s0 + j;
            float f = bf2f(v[j]);
            if (s < DSTATE) Bsh[t][s] = f;
            else Csh[t][s - DSTATE] = f;
        }
    }
    __syncthreads();
    float h[DSTATE];
    size_t hbase = (((size_t)b * NC + c) * DI + d) * DSTATE;
#pragma unroll
    for (int s = 0; s < DSTATE; s += 4)
        *reinterpret_cast<f32x4*>(&h[s]) = *reinterpret_cast<const f32x4*>(&hinit[hbase + s]);
    for (int t = 0; t < LC; ++t) {
        size_t ro = rbase + t;
        float dtv = bf2f(dt[ro * DI + d]);
        float xv = bf2f(xm[ro * DI + d]);
        float zv = bf2f(xz[ro * (2 * DI) + DI + d]);
        float dx = dtv * xv;
        float y = 0.f;
#pragma unroll
        for (int s = 0; s < DSTATE; ++s) {
            h[s] = __expf(dtv * Arow[s]) * h[s] + dx * Bsh[t][s];
            y += h[s] * Csh[t][s];
        }
        y += Dd * xv;
        y *= zv / (1.f + __expf(-zv));
        yg[ro * DI + d] = f2bf(y);
    }
}

// ---------------- residual + LayerNorm ----------------
__global__ __launch_bounds__(256) void k_ln(const float* __restrict__ mo,
                                            const float* __restrict__ x,
                                            const float* __restrict__ g,
                                            const float* __restrict__ be,
                                            float* __restrict__ out) {
    __shared__ float red[8];
    size_t r = blockIdx.x;
    int tid = threadIdx.x;
    float4 hv = *reinterpret_cast<const float4*>(&mo[r * DM + tid * 4]);
    float4 xv = *reinterpret_cast<const float4*>(&x[r * DM + tid * 4]);
    float h0 = hv.x + xv.x, h1 = hv.y + xv.y, h2 = hv.z + xv.z, h3 = hv.w + xv.w;
    float s = h0 + h1 + h2 + h3;
    float q = h0 * h0 + h1 * h1 + h2 * h2 + h3 * h3;
#pragma unroll
    for (int o = 32; o > 0; o >>= 1) {
        s += __shfl_down(s, o);
        q += __shfl_down(q, o);
    }
    int lane = tid & 63, wid = tid >> 6;
    if (lane == 0) { red[wid] = s; red[4 + wid] = q; }
    __syncthreads();
    s = red[0] + red[1] + red[2] + red[3];
    q = red[4] + red[5] + red[6] + red[7];
    float mu = s * (1.f / DM);
    float var = q * (1.f / DM) - mu * mu;
    float rs = rsqrtf(var + 1e-5f);
    float4 gv = *reinterpret_cast<const float4*>(&g[tid * 4]);
    float4 bv = *reinterpret_cast<const float4*>(&be[tid * 4]);
    float4 o;
    o.x = (h0 - mu) * rs * gv.x + bv.x;
    o.y = (h1 - mu) * rs * gv.y + bv.y;
    o.z = (h2 - mu) * rs * gv.z + bv.z;
    o.w = (h3 - mu) * rs * gv.w + bv.w;
    *reinterpret_cast<float4*>(&out[r * DM + tid * 4]) = o;
}

extern "C" void kernel_launch(void* const* d_in, const int* in_sizes, int n_in,
                              void* d_out, int out_size, void* d_ws, size_t ws_size,
                              hipStream_t stream) {
    const float* x      = (const float*)d_in[0];   // (B,L,DM)
    const float* w_in   = (const float*)d_in[1];   // (2*DI, DM)
    const float* conv_w = (const float*)d_in[2];   // (DI,1,4)
    const float* conv_b = (const float*)d_in[3];   // (DI)
    const float* w_xp   = (const float*)d_in[4];   // (96, DI)
    const float* w_dt   = (const float*)d_in[5];   // (DI, 64)
    const float* dt_b   = (const float*)d_in[6];   // (DI)
    const float* A_log  = (const float*)d_in[7];   // (DI,16)
    const float* Dp     = (const float*)d_in[8];   // (DI)
    const float* w_out  = (const float*)d_in[9];   // (DM, DI)
    const float* ln_g   = (const float*)d_in[10];
    const float* ln_b   = (const float*)d_in[11];
    float* out = (float*)d_out;

    char* ws = (char*)d_ws;
    size_t off = 0;
    auto alloc = [&](size_t bytes) -> void* {
        void* p = ws + off;
        off += (bytes + 255) & ~(size_t)255;
        return p;
    };
    const int M = B_ * L_;  // 8192
    ushort_t* w_in_b  = (ushort_t*)alloc((size_t)2 * DI * DM * 2);
    ushort_t* w_xp_b  = (ushort_t*)alloc((size_t)96 * DI * 2);
    ushort_t* w_dt_b  = (ushort_t*)alloc((size_t)DI * DTR * 2);
    ushort_t* w_out_b = (ushort_t*)alloc((size_t)DM * DI * 2);
    ushort_t* x_b     = (ushort_t*)alloc((size_t)M * DM * 2);   // 16.8 MB
    ushort_t* xz      = (ushort_t*)alloc((size_t)M * 2 * DI * 2);
    ushort_t* xm      = (ushort_t*)alloc((size_t)M * DI * 2);
    ushort_t* dbc     = (ushort_t*)alloc((size_t)M * 96 * 2);
    ushort_t* dtb     = (ushort_t*)alloc((size_t)M * DI * 2);   // bf16 dt (33.5 MB)
    ushort_t* yg      = (ushort_t*)alloc((size_t)M * DI * 2);
    float*    dtsum   = (float*)alloc((size_t)B_ * NC * DI * 4);
    float*    dbc_p   = (float*)alloc((size_t)4 * M * 96 * 4);  // split-K partials
    float*    mo      = (float*)dtb;   // alias: dt dead after scan3 (33.5 MB both)
    float*    hfin    = (float*)x_b;   // alias: x_b dead after in_proj (16.8 MB both)

    auto cvt = [&](const float* src, ushort_t* dst, int n) {
        k_cvt<<<dim3((n / 4 + 255) / 256), 256, 0, stream>>>(src, dst, n);
    };
    cvt(w_in, w_in_b, 2 * DI * DM);
    cvt(w_xp, w_xp_b, 96 * DI);
    cvt(w_dt, w_dt_b, DI * DTR);
    cvt(w_out, w_out_b, DM * DI);
    cvt(x, x_b, M * DM);

    // in_proj: xz[M,4096] = x[M,1024] @ w_in[4096,1024]^T  (64x32 tiles)
    k_gemm2<0, true><<<dim3(64 * 32, 1, 1), 256, 0, stream>>>(
        x_b, w_in_b, xz, nullptr, M, 2 * DI, DM, DM, DM, 2 * DI, 64);
    // conv + silu
    k_conv<<<dim3(DI / 256, L_ / 128, B_), 256, 0, stream>>>(xz, conv_w, conv_b, xm);
    // x_proj (split-K=4): dbc_p[z][M,96] = xm @ w_xp[96,2048]^T (K chunk 512)
    k_gemm2<0, false><<<dim3(64, 1, 4), 256, 0, stream>>>(
        xm, w_xp_b, dbc_p, nullptr, M, 96, DI, DI, DI, 96, 64);
    k_red4<<<dim3((M * 96 / 4 + 255) / 256), 256, 0, stream>>>(dbc_p, dbc, M * 96, M * 96);
    // dt_proj + softplus -> bf16: dt[M,2048] = softplus(dbc[:,:64] @ w_dt^T + b)
    k_gemm2<1, true><<<dim3(64 * 16, 1, 1), 256, 0, stream>>>(
        dbc, w_dt_b, dtb, dt_b, M, DI, DTR, 96, DTR, DI, 64);
    // chunked selective scan
    k_scan1<<<dim3(DI / 256, NC, B_), 256, 0, stream>>>(dtb, xm, dbc, A_log, hfin, dtsum);
    k_scan2<<<dim3(B_ * DI * DSTATE / 256), 256, 0, stream>>>(hfin, dtsum, A_log);
    k_scan3<<<dim3(DI / 256, NC, B_), 256, 0, stream>>>(dtb, xm, xz, dbc, A_log, Dp, hfin, yg);
    // out_proj: mo[M,1024] = yg @ w_out[1024,2048]^T  (64x8 tiles)
    k_gemm2<0, false><<<dim3(64 * 8, 1, 1), 256, 0, stream>>>(
        yg, w_out_b, mo, nullptr, M, DM, DI, DI, DI, DM, 64);
    // residual + layernorm
    k_ln<<<dim3(M), 256, 0, stream>>>(mo, x, ln_g, ln_b, out);
}

// Round 5
// 394.929 us; speedup vs baseline: 4.0697x; 1.0341x over previous
//
#include <hip/hip_runtime.h>
#include <hip/hip_bf16.h>

// Mamba block: B=4, L=2048, D_MODEL=1024, D_INNER=2048, D_STATE=16, DT_RANK=64
#define B_ 4
#define L_ 2048
#define DM 1024
#define DI 2048
#define DSTATE 16
#define DTR 64
#define LC 64            // scan chunk length
#define NC (L_ / LC)     // 32 chunks

typedef unsigned short ushort_t;
typedef __bf16 bf16x8 __attribute__((ext_vector_type(8)));
typedef float f32x4 __attribute__((ext_vector_type(4)));
typedef unsigned short u16x8 __attribute__((ext_vector_type(8)));
typedef unsigned short u16x4 __attribute__((ext_vector_type(4)));

__device__ __forceinline__ ushort_t f2bf(float f) {
    unsigned u = __builtin_bit_cast(unsigned, f);
    unsigned r = (u + 0x7FFFu + ((u >> 16) & 1u)) >> 16;
    return (ushort_t)r;
}
__device__ __forceinline__ float bf2f(ushort_t h) {
    unsigned u = ((unsigned)h) << 16;
    return __builtin_bit_cast(float, u);
}

// ---------------- f32 -> bf16 convert ----------------
__global__ __launch_bounds__(256) void k_cvt(const float* __restrict__ in,
                                             ushort_t* __restrict__ out, int n) {
    int i = (blockIdx.x * 256 + threadIdx.x) * 4;
    if (i + 3 < n) {
        float4 v = *reinterpret_cast<const float4*>(in + i);
        ushort4 o;
        o.x = f2bf(v.x); o.y = f2bf(v.y); o.z = f2bf(v.z); o.w = f2bf(v.w);
        *reinterpret_cast<ushort4*>(out + i) = o;
    } else {
        for (; i < n; ++i) out[i] = f2bf(in[i]);
    }
}

// ============ 256x256 8-phase MFMA GEMM for in_proj ============
// C[8192,4096](bf16) = A[8192,1024] * W[4096,1024]^T, all bf16.
// 8 waves (512 thr): wm=wid>>2 (128-row half), wn=wid&3 (64-col quarter).
// 4 LDS ring buffers x (A 256x32 + B 256x32) = 4 x 32KB = 128KB.
// Per phase: 8 ds_read frags + 2 global_load_lds stages + 16 MFMA,
// raw s_barrier pairs, counted vmcnt(8) at even phases (never 0 mid-loop).
// Schedule (iter k, phases 1..8; Rj computed at phases 2j+1,2j+2):
//   ph1: stage R3<-tile 4k+3 (A); ph2: R3 (B), vmcnt(8)
//   ph3: R0<-4k+4 (A); ph4: R0 (B), vmcnt(8)
//   ph5: R1<-4k+5 (A); ph6: R1 (B), vmcnt(8)
//   ph7: R2<-4k+6 (A); ph8: R2 (B), vmcnt(8)
// Every buffer's 4 loads are >= 8 loads old at the vmcnt(8) covering its
// reads; each buffer's overwrite is >= 2 barriers after its last read.
#define FENCE asm volatile("" ::: "memory")
#define VM8 asm volatile("s_waitcnt vmcnt(8)" ::: "memory")
#define VM4 asm volatile("s_waitcnt vmcnt(4)" ::: "memory")
#define VM0 asm volatile("s_waitcnt vmcnt(0)" ::: "memory")

__device__ __forceinline__ void mfma16(f32x4 acc[8][4], const bf16x8 av[4],
                                       const bf16x8 bv[4], int mh) {
#pragma unroll
    for (int i = 0; i < 4; ++i)
#pragma unroll
        for (int j = 0; j < 4; ++j)
            acc[mh * 4 + i][j] =
                __builtin_amdgcn_mfma_f32_16x16x32_bf16(av[i], bv[j], acc[mh * 4 + i][j], 0, 0, 0);
}

#define PHASE(BUF, MH, STAGE_STMT, WAIT_STMT)                                     \
    {                                                                             \
        bf16x8 av[4], bv[4];                                                      \
        _Pragma("unroll") for (int i_ = 0; i_ < 4; ++i_)                          \
            av[i_] = *(const bf16x8*)&lds[(BUF) * 16384 + aoff + ((MH) * 4 + i_) * 512]; \
        _Pragma("unroll") for (int i_ = 0; i_ < 4; ++i_)                          \
            bv[i_] = *(const bf16x8*)&lds[(BUF) * 16384 + boff + i_ * 512];       \
        STAGE_STMT;                                                               \
        FENCE; __builtin_amdgcn_s_barrier(); FENCE;                               \
        asm volatile("s_waitcnt lgkmcnt(0)" ::: "memory");                        \
        __builtin_amdgcn_sched_barrier(0);                                        \
        __builtin_amdgcn_s_setprio(1);                                            \
        mfma16(acc, av, bv, (MH));                                                \
        __builtin_amdgcn_s_setprio(0);                                            \
        WAIT_STMT;                                                                \
        FENCE; __builtin_amdgcn_s_barrier(); FENCE;                               \
    }

__global__ __launch_bounds__(512, 2) void k_gemm8(const ushort_t* __restrict__ Aq,
                                                  const ushort_t* __restrict__ Bq,
                                                  ushort_t* __restrict__ C) {
    __shared__ ushort_t lds[65536];  // 128 KB: 4 buffers x (A 8192 + B 8192 elems)
    const int tid = threadIdx.x;
    const int w = tid >> 6, lane = tid & 63;
    const int l15 = lane & 15;
    const int wm = w >> 2, wn = w & 3;
    // XCD-chunked tile map: xcd = bid%8 owns tm in [4*xcd, 4*xcd+4), tn = bid/32
    const int bid = blockIdx.x;
    const int tm = (bid & 7) * 4 + ((bid >> 3) & 3);
    const int tn = bid >> 5;
    const int row0 = tm * 256, col0 = tn * 256;

    // staging geometry: one global_load_lds covers a 128x32 half (8 KB):
    // wave w writes rows w*16..w*16+15 linearly; source pre-swizzled chunk
    const int rs = w * 16 + (lane >> 2);
    const int lcs = (lane & 3) ^ ((lane >> 3) & 3);
    // read-side swizzled frag offsets (elems); frag step = 512 elems (16 rows)
    const int pcr = ((lane >> 4) ^ ((l15 >> 1) & 3)) * 8;
    const int aoff = wm * 4096 + l15 * 32 + pcr;
    const int boff = 8192 + (wn >> 1) * 4096 + (wn & 1) * 2048 + l15 * 32 + pcr;

    auto stA = [&](int buf, int t) {
        const ushort_t* s = Aq + (size_t)(row0 + rs) * 1024 + t * 32 + lcs * 8;
        __builtin_amdgcn_global_load_lds(
            (const __attribute__((address_space(1))) void*)s,
            (__attribute__((address_space(3))) void*)&lds[buf * 16384 + w * 512], 16, 0, 0);
        __builtin_amdgcn_global_load_lds(
            (const __attribute__((address_space(1))) void*)(s + 128 * 1024),
            (__attribute__((address_space(3))) void*)&lds[buf * 16384 + 4096 + w * 512], 16, 0, 0);
    };
    auto stB = [&](int buf, int t) {
        const ushort_t* s = Bq + (size_t)(col0 + rs) * 1024 + t * 32 + lcs * 8;
        __builtin_amdgcn_global_load_lds(
            (const __attribute__((address_space(1))) void*)s,
            (__attribute__((address_space(3))) void*)&lds[buf * 16384 + 8192 + w * 512], 16, 0, 0);
        __builtin_amdgcn_global_load_lds(
            (const __attribute__((address_space(1))) void*)(s + 128 * 1024),
            (__attribute__((address_space(3))) void*)&lds[buf * 16384 + 12288 + w * 512], 16, 0, 0);
    };

    f32x4 acc[8][4] = {};

    // prologue: stage R0<-tile0, R1<-tile1, R2<-tile2 (12 loads); first 4 landed
    stA(0, 0); stB(0, 0);
    stA(1, 1); stB(1, 1);
    stA(2, 2); stB(2, 2);
    VM8;
    FENCE; __builtin_amdgcn_s_barrier(); FENCE;

    // main loop: K=1024 -> 32 BK=32 tiles -> 8 iterations; peel the last
#pragma unroll 1
    for (int k = 0; k < 7; ++k) {
        const int t3 = 4 * k + 3;
        PHASE(0, 0, stA(3, t3), (void)0);
        PHASE(0, 1, stB(3, t3), VM8);
        PHASE(1, 0, stA(0, t3 + 1), (void)0);
        PHASE(1, 1, stB(0, t3 + 1), VM8);
        PHASE(2, 0, stA(1, t3 + 2), (void)0);
        PHASE(2, 1, stB(1, t3 + 2), VM8);
        PHASE(3, 0, stA(2, t3 + 3), (void)0);
        PHASE(3, 1, stB(2, t3 + 3), VM8);
    }
    // last iteration (k=7): no next-iter stages; drain progressively
    PHASE(0, 0, stA(3, 31), (void)0);
    PHASE(0, 1, stB(3, 31), VM8);
    PHASE(1, 0, (void)0, (void)0);
    PHASE(1, 1, (void)0, VM4);
    PHASE(2, 0, (void)0, (void)0);
    PHASE(2, 1, (void)0, VM0);
    PHASE(3, 0, (void)0, (void)0);
    PHASE(3, 1, (void)0, (void)0);

    // epilogue: C-write (verified C/D layout: col=lane&15, row=(lane>>4)*4+r)
#pragma unroll
    for (int mf = 0; mf < 8; ++mf)
#pragma unroll
        for (int nf = 0; nf < 4; ++nf) {
            int col = col0 + wn * 64 + nf * 16 + l15;
#pragma unroll
            for (int r = 0; r < 4; ++r) {
                int row = row0 + wm * 128 + mf * 16 + (lane >> 4) * 4 + r;
                C[(size_t)row * 4096 + col] = f2bf(acc[mf][nf][r]);
            }
        }
}

// ---------------- m97-structure bf16 MFMA GEMM: C[M,N] = A[M,K] * W[N,K]^T ----
// (kept for x_proj / dt_proj / out_proj)
template <int EPI, bool OUTBF>
__global__ __launch_bounds__(256) void k_gemm2(
    const ushort_t* __restrict__ A, const ushort_t* __restrict__ Bw,
    void* __restrict__ C, const float* __restrict__ bias,
    int M, int N, int K, int lda, int ldb, int ldc, int tilesM) {
    __shared__ ushort_t As[128 * 64];  // 16 KB, linear (global_load_lds dest)
    __shared__ ushort_t Bs[128 * 64];
    int tid = threadIdx.x;
    int lane = tid & 63, wv = tid >> 6;
    int wr = wv >> 1, wc = wv & 1;
    // GM=8 supertile mapping (tilesM % 8 == 0 for all launches)
    int bid = blockIdx.x;
    int tilesN = gridDim.x / tilesM;
    int per = 8 * tilesN;
    int grp = bid / per, within = bid % per;
    int tm = grp * 8 + (within & 7);
    int tn = within >> 3;
    int row0 = tm * 128, col0 = tn * 128;
    int kchunk = K / gridDim.z;
    int kbeg = blockIdx.z * kchunk, kend = kbeg + kchunk;
    float* Cf = (float*)C + (size_t)blockIdx.z * (size_t)M * ldc;

    int sr = lane >> 3;   // sub-row within an 8-row staging slot
    int sj = lane & 7;    // 16B chunk within the 128B row
    f32x4 acc[4][4] = {};

    for (int k0 = kbeg; k0 < kend; k0 += 64) {
        __syncthreads();
#pragma unroll
        for (int i = 0; i < 4; ++i) {
            int slot = wv * 4 + i;          // 16 slots of 8 rows x 64 cols
            int r = slot * 8 + sr;
            int jA = sj ^ (r & 7);          // pre-swizzled source chunk
            __builtin_amdgcn_global_load_lds(
                (const __attribute__((address_space(1))) void*)&A[(size_t)(row0 + r) * lda + k0 + jA * 8],
                (__attribute__((address_space(3))) void*)&As[slot * 512], 16, 0, 0);
            __builtin_amdgcn_global_load_lds(
                (const __attribute__((address_space(1))) void*)&Bw[(size_t)(col0 + r) * ldb + k0 + jA * 8],
                (__attribute__((address_space(3))) void*)&Bs[slot * 512], 16, 0, 0);
        }
        __syncthreads();
#pragma unroll
        for (int kk = 0; kk < 2; ++kk) {
            int co = kk * 32 + (lane >> 4) * 8;
            int sx = (lane & 7) << 3;       // read-side swizzle (row&7)<<3
            bf16x8 af[4], bfr[4];
#pragma unroll
            for (int m = 0; m < 4; ++m) {
                int rw = wr * 64 + m * 16 + (lane & 15);
                af[m] = *reinterpret_cast<const bf16x8*>(&As[rw * 64 + (co ^ sx)]);
            }
#pragma unroll
            for (int n = 0; n < 4; ++n) {
                int rw = wc * 64 + n * 16 + (lane & 15);
                bfr[n] = *reinterpret_cast<const bf16x8*>(&Bs[rw * 64 + (co ^ sx)]);
            }
#pragma unroll
            for (int m = 0; m < 4; ++m)
#pragma unroll
                for (int n = 0; n < 4; ++n)
                    acc[m][n] = __builtin_amdgcn_mfma_f32_16x16x32_bf16(af[m], bfr[n], acc[m][n], 0, 0, 0);
        }
    }

#pragma unroll
    for (int m = 0; m < 4; ++m) {
#pragma unroll
        for (int n = 0; n < 4; ++n) {
            int col = col0 + wc * 64 + n * 16 + (lane & 15);
            if (col >= N) continue;
#pragma unroll
            for (int r = 0; r < 4; ++r) {
                int row = row0 + wr * 64 + m * 16 + (lane >> 4) * 4 + r;
                float v = acc[m][n][r];
                if (EPI == 1) {
                    v += bias[col];
                    v = (v > 20.f) ? v : log1pf(__expf(v));
                }
                if (OUTBF)
                    ((ushort_t*)C)[(size_t)row * ldc + col] = f2bf(v);
                else
                    Cf[(size_t)row * ldc + col] = v;
            }
        }
    }
}

// ---------------- split-K partial reduce (4 partials f32 -> bf16) ------------
__global__ __launch_bounds__(256) void k_red4(const float* __restrict__ p,
                                              ushort_t* __restrict__ o,
                                              int n, int stride) {
    int i = (blockIdx.x * 256 + threadIdx.x) * 4;
    if (i >= n) return;
    f32x4 a = *reinterpret_cast<const f32x4*>(&p[i]);
    f32x4 b = *reinterpret_cast<const f32x4*>(&p[i + stride]);
    f32x4 c = *reinterpret_cast<const f32x4*>(&p[i + 2 * stride]);
    f32x4 d = *reinterpret_cast<const f32x4*>(&p[i + 3 * stride]);
    ushort4 r;
    r.x = f2bf(a[0] + b[0] + c[0] + d[0]);
    r.y = f2bf(a[1] + b[1] + c[1] + d[1]);
    r.z = f2bf(a[2] + b[2] + c[2] + d[2]);
    r.w = f2bf(a[3] + b[3] + c[3] + d[3]);
    *reinterpret_cast<ushort4*>(&o[i]) = r;
}

// ---------------- depthwise causal conv (width 4) + SiLU ----------------
__global__ __launch_bounds__(256) void k_conv(const ushort_t* __restrict__ xz,
                                              const float* __restrict__ w,
                                              const float* __restrict__ bias,
                                              ushort_t* __restrict__ out) {
    int d = blockIdx.x * 256 + threadIdx.x;
    int b = blockIdx.z;
    int t0 = blockIdx.y * 128;
    float w0 = w[d * 4 + 0], w1 = w[d * 4 + 1], w2 = w[d * 4 + 2], w3 = w[d * 4 + 3];
    float bi = bias[d];
    size_t base = ((size_t)b * L_) * (2 * DI) + d;
    size_t obase = ((size_t)b * L_) * DI + d;
    float x0 = (t0 >= 3) ? bf2f(xz[base + (size_t)(t0 - 3) * (2 * DI)]) : 0.f;
    float x1 = (t0 >= 2) ? bf2f(xz[base + (size_t)(t0 - 2) * (2 * DI)]) : 0.f;
    float x2 = (t0 >= 1) ? bf2f(xz[base + (size_t)(t0 - 1) * (2 * DI)]) : 0.f;
    for (int t = t0; t < t0 + 128; ++t) {
        float cur = bf2f(xz[base + (size_t)t * (2 * DI)]);
        float v = w0 * x0 + w1 * x1 + w2 * x2 + w3 * cur + bi;
        v = v / (1.f + __expf(-v));
        out[obase + (size_t)t * DI] = f2bf(v);
        x0 = x1; x1 = x2; x2 = cur;
    }
}

// ---------------- chunked selective scan ----------------
// Phase 1: per-chunk local scan (h starts at 0) -> chunk-final h and sum(dt)
__global__ __launch_bounds__(256) void k_scan1(
    const ushort_t* __restrict__ dt, const ushort_t* __restrict__ xm,
    const ushort_t* __restrict__ dbc, const float* __restrict__ A_log,
    float* __restrict__ hfin, float* __restrict__ dtsum) {
    __shared__ float Bsh[LC][DSTATE];
    int tid = threadIdx.x;
    int d = blockIdx.x * 256 + tid;
    int c = blockIdx.y, b = blockIdx.z;
    float Arow[DSTATE];
#pragma unroll
    for (int s = 0; s < DSTATE; ++s) Arow[s] = -__expf(A_log[d * DSTATE + s]);
    size_t rbase = (size_t)b * L_ + (size_t)c * LC;
    {
        int i = tid * 4;
        int t = i >> 4, s0 = i & 15;
        u16x4 v = *reinterpret_cast<const u16x4*>(&dbc[(rbase + t) * 96 + DTR + s0]);
#pragma unroll
        for (int j = 0; j < 4; ++j) Bsh[t][s0 + j] = bf2f(v[j]);
    }
    __syncthreads();
    float h[DSTATE] = {};
    float sd = 0.f;
    for (int t = 0; t < LC; ++t) {
        size_t ro = rbase + t;
        float dtv = bf2f(dt[ro * DI + d]);
        float xv = bf2f(xm[ro * DI + d]);
        float dx = dtv * xv;
        sd += dtv;
#pragma unroll
        for (int s = 0; s < DSTATE; ++s)
            h[s] = __expf(dtv * Arow[s]) * h[s] + dx * Bsh[t][s];
    }
    size_t hbase = (((size_t)b * NC + c) * DI + d) * DSTATE;
#pragma unroll
    for (int s = 0; s < DSTATE; s += 4)
        *reinterpret_cast<f32x4*>(&hfin[hbase + s]) = *reinterpret_cast<f32x4*>(&h[s]);
    dtsum[((size_t)b * NC + c) * DI + d] = sd;
}

// Phase 2: sequential carry over chunks; hfin becomes carry-IN per chunk.
__global__ __launch_bounds__(256) void k_scan2(
    float* __restrict__ hfin, const float* __restrict__ dtsum,
    const float* __restrict__ A_log) {
    int gid = blockIdx.x * 256 + threadIdx.x;  // s fastest, then d, then b
    int s = gid & (DSTATE - 1);
    int d = (gid >> 4) & (DI - 1);
    int b = gid >> 15;
    float Av = -__expf(A_log[d * DSTATE + s]);
    float carry = 0.f;
    for (int c = 0; c < NC; ++c) {
        size_t idx = (((size_t)b * NC + c) * DI + d) * DSTATE + s;
        float loc = hfin[idx];
        hfin[idx] = carry;
        float sd = dtsum[((size_t)b * NC + c) * DI + d];
        carry = __expf(Av * sd) * carry + loc;
    }
}

// Phase 3: local scan with carry-in + D*x + z-gating -> yg (bf16)
__global__ __launch_bounds__(256) void k_scan3(
    const ushort_t* __restrict__ dt, const ushort_t* __restrict__ xm,
    const ushort_t* __restrict__ xz, const ushort_t* __restrict__ dbc,
    const float* __restrict__ A_log, const float* __restrict__ Dp,
    const float* __restrict__ hinit, ushort_t* __restrict__ yg) {
    __shared__ float Bsh[LC][DSTATE];
    __shared__ float Csh[LC][DSTATE];
    int tid = threadIdx.x;
    int d = blockIdx.x * 256 + tid;
    int c = blockIdx.y, b = blockIdx.z;
    float Arow[DSTATE];
#pragma unroll
    for (int s = 0; s < DSTATE; ++s) Arow[s] = -__expf(A_log[d * DSTATE + s]);
    float Dd = Dp[d];
    size_t rbase = (size_t)b * L_ + (size_t)c * LC;
    {
        int e0 = tid * 8;
        int t = e0 >> 5, s0 = e0 & 31;
        u16x8 v = *reinterpret_cast<const u16x8*>(&dbc[(rbase + t) * 96 + DTR + s0]);
#pragma unroll
        for (int j = 0; j < 8; ++j) {
            int s = s0 + j;
            float f = bf2f(v[j]);
            if (s < DSTATE) Bsh[t][s] = f;
            else Csh[t][s - DSTATE] = f;
        }
    }
    __syncthreads();
    float h[DSTATE];
    size_t hbase = (((size_t)b * NC + c) * DI + d) * DSTATE;
#pragma unroll
    for (int s = 0; s < DSTATE; s += 4)
        *reinterpret_cast<f32x4*>(&h[s]) = *reinterpret_cast<const f32x4*>(&hinit[hbase + s]);
    for (int t = 0; t < LC; ++t) {
        size_t ro = rbase + t;
        float dtv = bf2f(dt[ro * DI + d]);
        float xv = bf2f(xm[ro * DI + d]);
        float zv = bf2f(xz[ro * (2 * DI) + DI + d]);
        float dx = dtv * xv;
        float y = 0.f;
#pragma unroll
        for (int s = 0; s < DSTATE; ++s) {
            h[s] = __expf(dtv * Arow[s]) * h[s] + dx * Bsh[t][s];
            y += h[s] * Csh[t][s];
        }
        y += Dd * xv;
        y *= zv / (1.f + __expf(-zv));
        yg[ro * DI + d] = f2bf(y);
    }
}

// ---------------- residual + LayerNorm ----------------
__global__ __launch_bounds__(256) void k_ln(const float* __restrict__ mo,
                                            const float* __restrict__ x,
                                            const float* __restrict__ g,
                                            const float* __restrict__ be,
                                            float* __restrict__ out) {
    __shared__ float red[8];
    size_t r = blockIdx.x;
    int tid = threadIdx.x;
    float4 hv = *reinterpret_cast<const float4*>(&mo[r * DM + tid * 4]);
    float4 xv = *reinterpret_cast<const float4*>(&x[r * DM + tid * 4]);
    float h0 = hv.x + xv.x, h1 = hv.y + xv.y, h2 = hv.z + xv.z, h3 = hv.w + xv.w;
    float s = h0 + h1 + h2 + h3;
    float q = h0 * h0 + h1 * h1 + h2 * h2 + h3 * h3;
#pragma unroll
    for (int o = 32; o > 0; o >>= 1) {
        s += __shfl_down(s, o);
        q += __shfl_down(q, o);
    }
    int lane = tid & 63, wid = tid >> 6;
    if (lane == 0) { red[wid] = s; red[4 + wid] = q; }
    __syncthreads();
    s = red[0] + red[1] + red[2] + red[3];
    q = red[4] + red[5] + red[6] + red[7];
    float mu = s * (1.f / DM);
    float var = q * (1.f / DM) - mu * mu;
    float rs = rsqrtf(var + 1e-5f);
    float4 gv = *reinterpret_cast<const float4*>(&g[tid * 4]);
    float4 bv = *reinterpret_cast<const float4*>(&be[tid * 4]);
    float4 o;
    o.x = (h0 - mu) * rs * gv.x + bv.x;
    o.y = (h1 - mu) * rs * gv.y + bv.y;
    o.z = (h2 - mu) * rs * gv.z + bv.z;
    o.w = (h3 - mu) * rs * gv.w + bv.w;
    *reinterpret_cast<float4*>(&out[r * DM + tid * 4]) = o;
}

extern "C" void kernel_launch(void* const* d_in, const int* in_sizes, int n_in,
                              void* d_out, int out_size, void* d_ws, size_t ws_size,
                              hipStream_t stream) {
    const float* x      = (const float*)d_in[0];   // (B,L,DM)
    const float* w_in   = (const float*)d_in[1];   // (2*DI, DM)
    const float* conv_w = (const float*)d_in[2];   // (DI,1,4)
    const float* conv_b = (const float*)d_in[3];   // (DI)
    const float* w_xp   = (const float*)d_in[4];   // (96, DI)
    const float* w_dt   = (const float*)d_in[5];   // (DI, 64)
    const float* dt_b   = (const float*)d_in[6];   // (DI)
    const float* A_log  = (const float*)d_in[7];   // (DI,16)
    const float* Dp     = (const float*)d_in[8];   // (DI)
    const float* w_out  = (const float*)d_in[9];   // (DM, DI)
    const float* ln_g   = (const float*)d_in[10];
    const float* ln_b   = (const float*)d_in[11];
    float* out = (float*)d_out;

    char* ws = (char*)d_ws;
    size_t off = 0;
    auto alloc = [&](size_t bytes) -> void* {
        void* p = ws + off;
        off += (bytes + 255) & ~(size_t)255;
        return p;
    };
    const int M = B_ * L_;  // 8192
    ushort_t* w_in_b  = (ushort_t*)alloc((size_t)2 * DI * DM * 2);
    ushort_t* w_xp_b  = (ushort_t*)alloc((size_t)96 * DI * 2);
    ushort_t* w_dt_b  = (ushort_t*)alloc((size_t)DI * DTR * 2);
    ushort_t* w_out_b = (ushort_t*)alloc((size_t)DM * DI * 2);
    ushort_t* x_b     = (ushort_t*)alloc((size_t)M * DM * 2);   // 16.8 MB
    ushort_t* xz      = (ushort_t*)alloc((size_t)M * 2 * DI * 2);
    ushort_t* xm      = (ushort_t*)alloc((size_t)M * DI * 2);
    ushort_t* dbc     = (ushort_t*)alloc((size_t)M * 96 * 2);
    ushort_t* dtb     = (ushort_t*)alloc((size_t)M * DI * 2);   // bf16 dt (33.5 MB)
    ushort_t* yg      = (ushort_t*)alloc((size_t)M * DI * 2);
    float*    dtsum   = (float*)alloc((size_t)B_ * NC * DI * 4);
    float*    dbc_p   = (float*)alloc((size_t)4 * M * 96 * 4);  // split-K partials
    float*    mo      = (float*)dtb;   // alias: dt dead after scan3 (33.5 MB both)
    float*    hfin    = (float*)x_b;   // alias: x_b dead after in_proj (16.8 MB both)

    auto cvt = [&](const float* src, ushort_t* dst, int n) {
        k_cvt<<<dim3((n / 4 + 255) / 256), 256, 0, stream>>>(src, dst, n);
    };
    cvt(w_in, w_in_b, 2 * DI * DM);
    cvt(w_xp, w_xp_b, 96 * DI);
    cvt(w_dt, w_dt_b, DI * DTR);
    cvt(w_out, w_out_b, DM * DI);
    cvt(x, x_b, M * DM);

    // in_proj: xz[8192,4096] = x_b @ w_in_b^T  (256^2 8-phase, 32x16 tiles)
    k_gemm8<<<dim3(512), 512, 0, stream>>>(x_b, w_in_b, xz);
    // conv + silu
    k_conv<<<dim3(DI / 256, L_ / 128, B_), 256, 0, stream>>>(xz, conv_w, conv_b, xm);
    // x_proj (split-K=4): dbc_p[z][M,96] = xm @ w_xp[96,2048]^T (K chunk 512)
    k_gemm2<0, false><<<dim3(64, 1, 4), 256, 0, stream>>>(
        xm, w_xp_b, dbc_p, nullptr, M, 96, DI, DI, DI, 96, 64);
    k_red4<<<dim3((M * 96 / 4 + 255) / 256), 256, 0, stream>>>(dbc_p, dbc, M * 96, M * 96);
    // dt_proj + softplus -> bf16: dt[M,2048] = softplus(dbc[:,:64] @ w_dt^T + b)
    k_gemm2<1, true><<<dim3(64 * 16, 1, 1), 256, 0, stream>>>(
        dbc, w_dt_b, dtb, dt_b, M, DI, DTR, 96, DTR, DI, 64);
    // chunked selective scan
    k_scan1<<<dim3(DI / 256, NC, B_), 256, 0, stream>>>(dtb, xm, dbc, A_log, hfin, dtsum);
    k_scan2<<<dim3(B_ * DI * DSTATE / 256), 256, 0, stream>>>(hfin, dtsum, A_log);
    k_scan3<<<dim3(DI / 256, NC, B_), 256, 0, stream>>>(dtb, xm, xz, dbc, A_log, Dp, hfin, yg);
    // out_proj: mo[M,1024] = yg @ w_out[1024,2048]^T  (64x8 tiles)
    k_gemm2<0, false><<<dim3(64 * 8, 1, 1), 256, 0, stream>>>(
        yg, w_out_b, mo, nullptr, M, DM, DI, DI, DI, DM, 64);
    // residual + layernorm
    k_ln<<<dim3(M), 256, 0, stream>>>(mo, x, ln_g, ln_b, out);
}

// Round 6
// 381.906 us; speedup vs baseline: 4.2085x; 1.0341x over previous
//
#include <hip/hip_runtime.h>
#include <hip/hip_bf16.h>

// Mamba block: B=4, L=2048, D_MODEL=1024, D_INNER=2048, D_STATE=16, DT_RANK=64
#define B_ 4
#define L_ 2048
#define DM 1024
#define DI 2048
#define DSTATE 16
#define DTR 64
#define LC 64            // scan chunk length
#define NC (L_ / LC)     // 32 chunks

typedef unsigned short ushort_t;
typedef __bf16 bf16x8 __attribute__((ext_vector_type(8)));
typedef float f32x4 __attribute__((ext_vector_type(4)));
typedef float f32x16 __attribute__((ext_vector_type(16)));
typedef unsigned short u16x8 __attribute__((ext_vector_type(8)));
typedef unsigned short u16x4 __attribute__((ext_vector_type(4)));

__device__ __forceinline__ ushort_t f2bf(float f) {
    unsigned u = __builtin_bit_cast(unsigned, f);
    unsigned r = (u + 0x7FFFu + ((u >> 16) & 1u)) >> 16;
    return (ushort_t)r;
}
__device__ __forceinline__ float bf2f(ushort_t h) {
    unsigned u = ((unsigned)h) << 16;
    return __builtin_bit_cast(float, u);
}

// ---------------- f32 -> bf16 convert ----------------
__global__ __launch_bounds__(256) void k_cvt(const float* __restrict__ in,
                                             ushort_t* __restrict__ out, int n) {
    int i = (blockIdx.x * 256 + threadIdx.x) * 4;
    if (i + 3 < n) {
        float4 v = *reinterpret_cast<const float4*>(in + i);
        ushort4 o;
        o.x = f2bf(v.x); o.y = f2bf(v.y); o.z = f2bf(v.z); o.w = f2bf(v.w);
        *reinterpret_cast<ushort4*>(out + i) = o;
    } else {
        for (; i < n; ++i) out[i] = f2bf(in[i]);
    }
}

// ============ 256x256 8-phase MFMA GEMM for in_proj ============
#define FENCE asm volatile("" ::: "memory")
#define VM8 asm volatile("s_waitcnt vmcnt(8)" ::: "memory")
#define VM4 asm volatile("s_waitcnt vmcnt(4)" ::: "memory")
#define VM0 asm volatile("s_waitcnt vmcnt(0)" ::: "memory")

__device__ __forceinline__ void mfma16(f32x4 acc[8][4], const bf16x8 av[4],
                                       const bf16x8 bv[4], int mh) {
#pragma unroll
    for (int i = 0; i < 4; ++i)
#pragma unroll
        for (int j = 0; j < 4; ++j)
            acc[mh * 4 + i][j] =
                __builtin_amdgcn_mfma_f32_16x16x32_bf16(av[i], bv[j], acc[mh * 4 + i][j], 0, 0, 0);
}

#define PHASE(BUF, MH, STAGE_STMT, WAIT_STMT)                                     \
    {                                                                             \
        bf16x8 av[4], bv[4];                                                      \
        _Pragma("unroll") for (int i_ = 0; i_ < 4; ++i_)                          \
            av[i_] = *(const bf16x8*)&lds[(BUF) * 16384 + aoff + ((MH) * 4 + i_) * 512]; \
        _Pragma("unroll") for (int i_ = 0; i_ < 4; ++i_)                          \
            bv[i_] = *(const bf16x8*)&lds[(BUF) * 16384 + boff + i_ * 512];       \
        STAGE_STMT;                                                               \
        FENCE; __builtin_amdgcn_s_barrier(); FENCE;                               \
        asm volatile("s_waitcnt lgkmcnt(0)" ::: "memory");                        \
        __builtin_amdgcn_sched_barrier(0);                                        \
        __builtin_amdgcn_s_setprio(1);                                            \
        mfma16(acc, av, bv, (MH));                                                \
        __builtin_amdgcn_s_setprio(0);                                            \
        WAIT_STMT;                                                                \
        FENCE; __builtin_amdgcn_s_barrier(); FENCE;                               \
    }

__global__ __launch_bounds__(512, 2) void k_gemm8(const ushort_t* __restrict__ Aq,
                                                  const ushort_t* __restrict__ Bq,
                                                  ushort_t* __restrict__ C) {
    __shared__ ushort_t lds[65536];  // 128 KB: 4 buffers x (A 8192 + B 8192 elems)
    const int tid = threadIdx.x;
    const int w = tid >> 6, lane = tid & 63;
    const int l15 = lane & 15;
    const int wm = w >> 2, wn = w & 3;
    const int bid = blockIdx.x;
    const int tm = (bid & 7) * 4 + ((bid >> 3) & 3);
    const int tn = bid >> 5;
    const int row0 = tm * 256, col0 = tn * 256;

    const int rs = w * 16 + (lane >> 2);
    const int lcs = (lane & 3) ^ ((lane >> 3) & 3);
    const int pcr = ((lane >> 4) ^ ((l15 >> 1) & 3)) * 8;
    const int aoff = wm * 4096 + l15 * 32 + pcr;
    const int boff = 8192 + (wn >> 1) * 4096 + (wn & 1) * 2048 + l15 * 32 + pcr;

    auto stA = [&](int buf, int t) {
        const ushort_t* s = Aq + (size_t)(row0 + rs) * 1024 + t * 32 + lcs * 8;
        __builtin_amdgcn_global_load_lds(
            (const __attribute__((address_space(1))) void*)s,
            (__attribute__((address_space(3))) void*)&lds[buf * 16384 + w * 512], 16, 0, 0);
        __builtin_amdgcn_global_load_lds(
            (const __attribute__((address_space(1))) void*)(s + 128 * 1024),
            (__attribute__((address_space(3))) void*)&lds[buf * 16384 + 4096 + w * 512], 16, 0, 0);
    };
    auto stB = [&](int buf, int t) {
        const ushort_t* s = Bq + (size_t)(col0 + rs) * 1024 + t * 32 + lcs * 8;
        __builtin_amdgcn_global_load_lds(
            (const __attribute__((address_space(1))) void*)s,
            (__attribute__((address_space(3))) void*)&lds[buf * 16384 + 8192 + w * 512], 16, 0, 0);
        __builtin_amdgcn_global_load_lds(
            (const __attribute__((address_space(1))) void*)(s + 128 * 1024),
            (__attribute__((address_space(3))) void*)&lds[buf * 16384 + 12288 + w * 512], 16, 0, 0);
    };

    f32x4 acc[8][4] = {};

    stA(0, 0); stB(0, 0);
    stA(1, 1); stB(1, 1);
    stA(2, 2); stB(2, 2);
    VM8;
    FENCE; __builtin_amdgcn_s_barrier(); FENCE;

#pragma unroll 1
    for (int k = 0; k < 7; ++k) {
        const int t3 = 4 * k + 3;
        PHASE(0, 0, stA(3, t3), (void)0);
        PHASE(0, 1, stB(3, t3), VM8);
        PHASE(1, 0, stA(0, t3 + 1), (void)0);
        PHASE(1, 1, stB(0, t3 + 1), VM8);
        PHASE(2, 0, stA(1, t3 + 2), (void)0);
        PHASE(2, 1, stB(1, t3 + 2), VM8);
        PHASE(3, 0, stA(2, t3 + 3), (void)0);
        PHASE(3, 1, stB(2, t3 + 3), VM8);
    }
    PHASE(0, 0, stA(3, 31), (void)0);
    PHASE(0, 1, stB(3, 31), VM8);
    PHASE(1, 0, (void)0, (void)0);
    PHASE(1, 1, (void)0, VM4);
    PHASE(2, 0, (void)0, (void)0);
    PHASE(2, 1, (void)0, VM0);
    PHASE(3, 0, (void)0, (void)0);
    PHASE(3, 1, (void)0, (void)0);

#pragma unroll
    for (int mf = 0; mf < 8; ++mf)
#pragma unroll
        for (int nf = 0; nf < 4; ++nf) {
            int col = col0 + wn * 64 + nf * 16 + l15;
#pragma unroll
            for (int r = 0; r < 4; ++r) {
                int row = row0 + wm * 128 + mf * 16 + (lane >> 4) * 4 + r;
                C[(size_t)row * 4096 + col] = f2bf(acc[mf][nf][r]);
            }
        }
}

// ---------------- m97-structure bf16 MFMA GEMM (x_proj / dt_proj / out_proj) --
template <int EPI, bool OUTBF>
__global__ __launch_bounds__(256) void k_gemm2(
    const ushort_t* __restrict__ A, const ushort_t* __restrict__ Bw,
    void* __restrict__ C, const float* __restrict__ bias,
    int M, int N, int K, int lda, int ldb, int ldc, int tilesM) {
    __shared__ ushort_t As[128 * 64];
    __shared__ ushort_t Bs[128 * 64];
    int tid = threadIdx.x;
    int lane = tid & 63, wv = tid >> 6;
    int wr = wv >> 1, wc = wv & 1;
    int bid = blockIdx.x;
    int tilesN = gridDim.x / tilesM;
    int per = 8 * tilesN;
    int grp = bid / per, within = bid % per;
    int tm = grp * 8 + (within & 7);
    int tn = within >> 3;
    int row0 = tm * 128, col0 = tn * 128;
    int kchunk = K / gridDim.z;
    int kbeg = blockIdx.z * kchunk, kend = kbeg + kchunk;
    float* Cf = (float*)C + (size_t)blockIdx.z * (size_t)M * ldc;

    int sr = lane >> 3;
    int sj = lane & 7;
    f32x4 acc[4][4] = {};

    for (int k0 = kbeg; k0 < kend; k0 += 64) {
        __syncthreads();
#pragma unroll
        for (int i = 0; i < 4; ++i) {
            int slot = wv * 4 + i;
            int r = slot * 8 + sr;
            int jA = sj ^ (r & 7);
            __builtin_amdgcn_global_load_lds(
                (const __attribute__((address_space(1))) void*)&A[(size_t)(row0 + r) * lda + k0 + jA * 8],
                (__attribute__((address_space(3))) void*)&As[slot * 512], 16, 0, 0);
            __builtin_amdgcn_global_load_lds(
                (const __attribute__((address_space(1))) void*)&Bw[(size_t)(col0 + r) * ldb + k0 + jA * 8],
                (__attribute__((address_space(3))) void*)&Bs[slot * 512], 16, 0, 0);
        }
        __syncthreads();
#pragma unroll
        for (int kk = 0; kk < 2; ++kk) {
            int co = kk * 32 + (lane >> 4) * 8;
            int sx = (lane & 7) << 3;
            bf16x8 af[4], bfr[4];
#pragma unroll
            for (int m = 0; m < 4; ++m) {
                int rw = wr * 64 + m * 16 + (lane & 15);
                af[m] = *reinterpret_cast<const bf16x8*>(&As[rw * 64 + (co ^ sx)]);
            }
#pragma unroll
            for (int n = 0; n < 4; ++n) {
                int rw = wc * 64 + n * 16 + (lane & 15);
                bfr[n] = *reinterpret_cast<const bf16x8*>(&Bs[rw * 64 + (co ^ sx)]);
            }
#pragma unroll
            for (int m = 0; m < 4; ++m)
#pragma unroll
                for (int n = 0; n < 4; ++n)
                    acc[m][n] = __builtin_amdgcn_mfma_f32_16x16x32_bf16(af[m], bfr[n], acc[m][n], 0, 0, 0);
        }
    }

#pragma unroll
    for (int m = 0; m < 4; ++m) {
#pragma unroll
        for (int n = 0; n < 4; ++n) {
            int col = col0 + wc * 64 + n * 16 + (lane & 15);
            if (col >= N) continue;
#pragma unroll
            for (int r = 0; r < 4; ++r) {
                int row = row0 + wr * 64 + m * 16 + (lane >> 4) * 4 + r;
                float v = acc[m][n][r];
                if (EPI == 1) {
                    v += bias[col];
                    v = (v > 20.f) ? v : log1pf(__expf(v));
                }
                if (OUTBF)
                    ((ushort_t*)C)[(size_t)row * ldc + col] = f2bf(v);
                else
                    Cf[(size_t)row * ldc + col] = v;
            }
        }
    }
}

// ---------------- split-K partial reduce (4 partials f32 -> bf16) ------------
__global__ __launch_bounds__(256) void k_red4(const float* __restrict__ p,
                                              ushort_t* __restrict__ o,
                                              int n, int stride) {
    int i = (blockIdx.x * 256 + threadIdx.x) * 4;
    if (i >= n) return;
    f32x4 a = *reinterpret_cast<const f32x4*>(&p[i]);
    f32x4 b = *reinterpret_cast<const f32x4*>(&p[i + stride]);
    f32x4 c = *reinterpret_cast<const f32x4*>(&p[i + 2 * stride]);
    f32x4 d = *reinterpret_cast<const f32x4*>(&p[i + 3 * stride]);
    ushort4 r;
    r.x = f2bf(a[0] + b[0] + c[0] + d[0]);
    r.y = f2bf(a[1] + b[1] + c[1] + d[1]);
    r.z = f2bf(a[2] + b[2] + c[2] + d[2]);
    r.w = f2bf(a[3] + b[3] + c[3] + d[3]);
    *reinterpret_cast<ushort4*>(&o[i]) = r;
}

// ---------------- depthwise causal conv (width 4) + SiLU ----------------
__global__ __launch_bounds__(256) void k_conv(const ushort_t* __restrict__ xz,
                                              const float* __restrict__ w,
                                              const float* __restrict__ bias,
                                              ushort_t* __restrict__ out) {
    int d = blockIdx.x * 256 + threadIdx.x;
    int b = blockIdx.z;
    int t0 = blockIdx.y * 128;
    float w0 = w[d * 4 + 0], w1 = w[d * 4 + 1], w2 = w[d * 4 + 2], w3 = w[d * 4 + 3];
    float bi = bias[d];
    size_t base = ((size_t)b * L_) * (2 * DI) + d;
    size_t obase = ((size_t)b * L_) * DI + d;
    float x0 = (t0 >= 3) ? bf2f(xz[base + (size_t)(t0 - 3) * (2 * DI)]) : 0.f;
    float x1 = (t0 >= 2) ? bf2f(xz[base + (size_t)(t0 - 2) * (2 * DI)]) : 0.f;
    float x2 = (t0 >= 1) ? bf2f(xz[base + (size_t)(t0 - 1) * (2 * DI)]) : 0.f;
    for (int t = t0; t < t0 + 128; ++t) {
        float cur = bf2f(xz[base + (size_t)t * (2 * DI)]);
        float v = w0 * x0 + w1 * x1 + w2 * x2 + w3 * cur + bi;
        v = v / (1.f + __expf(-v));
        out[obase + (size_t)t * DI] = f2bf(v);
        x0 = x1; x1 = x2; x2 = cur;
    }
}

// ---------------- chunked selective scan ----------------
// h / arow live in ext_vector registers (NEVER address-taken -> no scratch).
// arow pre-scaled by log2(e) so each decay is a single v_exp_f32 (exp2).

// Phase 1: per-chunk local scan (h=0) -> chunk-final h and sum(dt)
__global__ __launch_bounds__(256) void k_scan1(
    const ushort_t* __restrict__ dt, const ushort_t* __restrict__ xm,
    const ushort_t* __restrict__ dbc, const float* __restrict__ A_log,
    float* __restrict__ hfin, float* __restrict__ dtsum) {
    __shared__ float Bsh[LC][DSTATE];
    int tid = threadIdx.x;
    int d = blockIdx.x * 256 + tid;
    int c = blockIdx.y, b = blockIdx.z;
    f32x16 arow;
#pragma unroll
    for (int s = 0; s < DSTATE; ++s)
        arow[s] = -__expf(A_log[d * DSTATE + s]) * 1.44269504f;
    size_t rbase = (size_t)b * L_ + (size_t)c * LC;
    {
        int i = tid * 4;
        int t = i >> 4, s0 = i & 15;
        u16x4 v = *reinterpret_cast<const u16x4*>(&dbc[(rbase + t) * 96 + DTR + s0]);
#pragma unroll
        for (int j = 0; j < 4; ++j) Bsh[t][s0 + j] = bf2f(v[j]);
    }
    __syncthreads();
    f32x16 h;
#pragma unroll
    for (int s = 0; s < DSTATE; ++s) h[s] = 0.f;
    float sd = 0.f;
    for (int t = 0; t < LC; ++t) {
        size_t ro = rbase + t;
        float dtv = bf2f(dt[ro * DI + d]);
        float xv = bf2f(xm[ro * DI + d]);
        float dx = dtv * xv;
        sd += dtv;
#pragma unroll
        for (int s = 0; s < DSTATE; ++s) {
            float e = __builtin_amdgcn_exp2f(dtv * arow[s]);
            h[s] = e * h[s] + dx * Bsh[t][s];
        }
    }
    size_t hbase = (((size_t)b * NC + c) * DI + d) * DSTATE;
#pragma unroll
    for (int s = 0; s < DSTATE; s += 4) {
        float4 v;
        v.x = h[s]; v.y = h[s + 1]; v.z = h[s + 2]; v.w = h[s + 3];
        *reinterpret_cast<float4*>(&hfin[hbase + s]) = v;
    }
    dtsum[((size_t)b * NC + c) * DI + d] = sd;
}

// Phase 2: sequential carry over chunks; hfin becomes carry-IN per chunk.
__global__ __launch_bounds__(256) void k_scan2(
    float* __restrict__ hfin, const float* __restrict__ dtsum,
    const float* __restrict__ A_log) {
    int gid = blockIdx.x * 256 + threadIdx.x;  // s fastest, then d, then b
    int s = gid & (DSTATE - 1);
    int d = (gid >> 4) & (DI - 1);
    int b = gid >> 15;
    float Av = -__expf(A_log[d * DSTATE + s]) * 1.44269504f;
    float carry = 0.f;
    for (int c = 0; c < NC; ++c) {
        size_t idx = (((size_t)b * NC + c) * DI + d) * DSTATE + s;
        float loc = hfin[idx];
        hfin[idx] = carry;
        float sd = dtsum[((size_t)b * NC + c) * DI + d];
        carry = __builtin_amdgcn_exp2f(Av * sd) * carry + loc;
    }
}

// Phase 3: local scan with carry-in + D*x + z-gating -> yg (bf16)
__global__ __launch_bounds__(256) void k_scan3(
    const ushort_t* __restrict__ dt, const ushort_t* __restrict__ xm,
    const ushort_t* __restrict__ xz, const ushort_t* __restrict__ dbc,
    const float* __restrict__ A_log, const float* __restrict__ Dp,
    const float* __restrict__ hinit, ushort_t* __restrict__ yg) {
    __shared__ float Bsh[LC][DSTATE];
    __shared__ float Csh[LC][DSTATE];
    int tid = threadIdx.x;
    int d = blockIdx.x * 256 + tid;
    int c = blockIdx.y, b = blockIdx.z;
    f32x16 arow;
#pragma unroll
    for (int s = 0; s < DSTATE; ++s)
        arow[s] = -__expf(A_log[d * DSTATE + s]) * 1.44269504f;
    float Dd = Dp[d];
    size_t rbase = (size_t)b * L_ + (size_t)c * LC;
    {
        int e0 = tid * 8;
        int t = e0 >> 5, s0 = e0 & 31;
        u16x8 v = *reinterpret_cast<const u16x8*>(&dbc[(rbase + t) * 96 + DTR + s0]);
#pragma unroll
        for (int j = 0; j < 8; ++j) {
            int s = s0 + j;
            float f = bf2f(v[j]);
            if (s < DSTATE) Bsh[t][s] = f;
            else Csh[t][s - DSTATE] = f;
        }
    }
    __syncthreads();
    size_t hbase = (((size_t)b * NC + c) * DI + d) * DSTATE;
    f32x16 h;
#pragma unroll
    for (int s = 0; s < DSTATE; s += 4) {
        float4 v = *reinterpret_cast<const float4*>(&hinit[hbase + s]);
        h[s] = v.x; h[s + 1] = v.y; h[s + 2] = v.z; h[s + 3] = v.w;
    }
    for (int t = 0; t < LC; ++t) {
        size_t ro = rbase + t;
        float dtv = bf2f(dt[ro * DI + d]);
        float xv = bf2f(xm[ro * DI + d]);
        float zv = bf2f(xz[ro * (2 * DI) + DI + d]);
        float dx = dtv * xv;
        float y = 0.f;
#pragma unroll
        for (int s = 0; s < DSTATE; ++s) {
            float e = __builtin_amdgcn_exp2f(dtv * arow[s]);
            h[s] = e * h[s] + dx * Bsh[t][s];
            y += h[s] * Csh[t][s];
        }
        y += Dd * xv;
        y *= zv / (1.f + __expf(-zv));
        yg[ro * DI + d] = f2bf(y);
    }
}

// ---------------- residual + LayerNorm ----------------
__global__ __launch_bounds__(256) void k_ln(const float* __restrict__ mo,
                                            const float* __restrict__ x,
                                            const float* __restrict__ g,
                                            const float* __restrict__ be,
                                            float* __restrict__ out) {
    __shared__ float red[8];
    size_t r = blockIdx.x;
    int tid = threadIdx.x;
    float4 hv = *reinterpret_cast<const float4*>(&mo[r * DM + tid * 4]);
    float4 xv = *reinterpret_cast<const float4*>(&x[r * DM + tid * 4]);
    float h0 = hv.x + xv.x, h1 = hv.y + xv.y, h2 = hv.z + xv.z, h3 = hv.w + xv.w;
    float s = h0 + h1 + h2 + h3;
    float q = h0 * h0 + h1 * h1 + h2 * h2 + h3 * h3;
#pragma unroll
    for (int o = 32; o > 0; o >>= 1) {
        s += __shfl_down(s, o);
        q += __shfl_down(q, o);
    }
    int lane = tid & 63, wid = tid >> 6;
    if (lane == 0) { red[wid] = s; red[4 + wid] = q; }
    __syncthreads();
    s = red[0] + red[1] + red[2] + red[3];
    q = red[4] + red[5] + red[6] + red[7];
    float mu = s * (1.f / DM);
    float var = q * (1.f / DM) - mu * mu;
    float rs = rsqrtf(var + 1e-5f);
    float4 gv = *reinterpret_cast<const float4*>(&g[tid * 4]);
    float4 bv = *reinterpret_cast<const float4*>(&be[tid * 4]);
    float4 o;
    o.x = (h0 - mu) * rs * gv.x + bv.x;
    o.y = (h1 - mu) * rs * gv.y + bv.y;
    o.z = (h2 - mu) * rs * gv.z + bv.z;
    o.w = (h3 - mu) * rs * gv.w + bv.w;
    *reinterpret_cast<float4*>(&out[r * DM + tid * 4]) = o;
}

extern "C" void kernel_launch(void* const* d_in, const int* in_sizes, int n_in,
                              void* d_out, int out_size, void* d_ws, size_t ws_size,
                              hipStream_t stream) {
    const float* x      = (const float*)d_in[0];   // (B,L,DM)
    const float* w_in   = (const float*)d_in[1];   // (2*DI, DM)
    const float* conv_w = (const float*)d_in[2];   // (DI,1,4)
    const float* conv_b = (const float*)d_in[3];   // (DI)
    const float* w_xp   = (const float*)d_in[4];   // (96, DI)
    const float* w_dt   = (const float*)d_in[5];   // (DI, 64)
    const float* dt_b   = (const float*)d_in[6];   // (DI)
    const float* A_log  = (const float*)d_in[7];   // (DI,16)
    const float* Dp     = (const float*)d_in[8];   // (DI)
    const float* w_out  = (const float*)d_in[9];   // (DM, DI)
    const float* ln_g   = (const float*)d_in[10];
    const float* ln_b   = (const float*)d_in[11];
    float* out = (float*)d_out;

    char* ws = (char*)d_ws;
    size_t off = 0;
    auto alloc = [&](size_t bytes) -> void* {
        void* p = ws + off;
        off += (bytes + 255) & ~(size_t)255;
        return p;
    };
    const int M = B_ * L_;  // 8192
    ushort_t* w_in_b  = (ushort_t*)alloc((size_t)2 * DI * DM * 2);
    ushort_t* w_xp_b  = (ushort_t*)alloc((size_t)96 * DI * 2);
    ushort_t* w_dt_b  = (ushort_t*)alloc((size_t)DI * DTR * 2);
    ushort_t* w_out_b = (ushort_t*)alloc((size_t)DM * DI * 2);
    ushort_t* x_b     = (ushort_t*)alloc((size_t)M * DM * 2);   // 16.8 MB
    ushort_t* xz      = (ushort_t*)alloc((size_t)M * 2 * DI * 2);
    ushort_t* xm      = (ushort_t*)alloc((size_t)M * DI * 2);
    ushort_t* dbc     = (ushort_t*)alloc((size_t)M * 96 * 2);
    ushort_t* dtb     = (ushort_t*)alloc((size_t)M * DI * 2);   // bf16 dt (33.5 MB)
    ushort_t* yg      = (ushort_t*)alloc((size_t)M * DI * 2);
    float*    dtsum   = (float*)alloc((size_t)B_ * NC * DI * 4);
    float*    dbc_p   = (float*)alloc((size_t)4 * M * 96 * 4);  // split-K partials
    float*    mo      = (float*)dtb;   // alias: dt dead after scan3 (33.5 MB both)
    float*    hfin    = (float*)x_b;   // alias: x_b dead after in_proj (16.8 MB both)

    auto cvt = [&](const float* src, ushort_t* dst, int n) {
        k_cvt<<<dim3((n / 4 + 255) / 256), 256, 0, stream>>>(src, dst, n);
    };
    cvt(w_in, w_in_b, 2 * DI * DM);
    cvt(w_xp, w_xp_b, 96 * DI);
    cvt(w_dt, w_dt_b, DI * DTR);
    cvt(w_out, w_out_b, DM * DI);
    cvt(x, x_b, M * DM);

    // in_proj: xz[8192,4096] = x_b @ w_in_b^T  (256^2 8-phase, 32x16 tiles)
    k_gemm8<<<dim3(512), 512, 0, stream>>>(x_b, w_in_b, xz);
    // conv + silu
    k_conv<<<dim3(DI / 256, L_ / 128, B_), 256, 0, stream>>>(xz, conv_w, conv_b, xm);
    // x_proj (split-K=4): dbc_p[z][M,96] = xm @ w_xp[96,2048]^T (K chunk 512)
    k_gemm2<0, false><<<dim3(64, 1, 4), 256, 0, stream>>>(
        xm, w_xp_b, dbc_p, nullptr, M, 96, DI, DI, DI, 96, 64);
    k_red4<<<dim3((M * 96 / 4 + 255) / 256), 256, 0, stream>>>(dbc_p, dbc, M * 96, M * 96);
    // dt_proj + softplus -> bf16: dt[M,2048] = softplus(dbc[:,:64] @ w_dt^T + b)
    k_gemm2<1, true><<<dim3(64 * 16, 1, 1), 256, 0, stream>>>(
        dbc, w_dt_b, dtb, dt_b, M, DI, DTR, 96, DTR, DI, 64);
    // chunked selective scan
    k_scan1<<<dim3(DI / 256, NC, B_), 256, 0, stream>>>(dtb, xm, dbc, A_log, hfin, dtsum);
    k_scan2<<<dim3(B_ * DI * DSTATE / 256), 256, 0, stream>>>(hfin, dtsum, A_log);
    k_scan3<<<dim3(DI / 256, NC, B_), 256, 0, stream>>>(dtb, xm, xz, dbc, A_log, Dp, hfin, yg);
    // out_proj: mo[M,1024] = yg @ w_out[1024,2048]^T  (64x8 tiles)
    k_gemm2<0, false><<<dim3(64 * 8, 1, 1), 256, 0, stream>>>(
        yg, w_out_b, mo, nullptr, M, DM, DI, DI, DI, DM, 64);
    // residual + layernorm
    k_ln<<<dim3(M), 256, 0, stream>>>(mo, x, ln_g, ln_b, out);
}

// Round 8
// 334.681 us; speedup vs baseline: 4.8024x; 1.1411x over previous
//
#include <hip/hip_runtime.h>
#include <hip/hip_bf16.h>

// Mamba block: B=4, L=2048, D_MODEL=1024, D_INNER=2048, D_STATE=16, DT_RANK=64
#define B_ 4
#define L_ 2048
#define DM 1024
#define DI 2048
#define DSTATE 16
#define DTR 64
#define LC 64            // scan chunk length
#define NC (L_ / LC)     // 32 chunks
#define LOG2E 1.44269504f

typedef unsigned short ushort_t;
typedef __bf16 bf16x8 __attribute__((ext_vector_type(8)));
typedef float f32x4 __attribute__((ext_vector_type(4)));
typedef float f32x16 __attribute__((ext_vector_type(16)));
typedef unsigned short u16x8 __attribute__((ext_vector_type(8)));
typedef unsigned short u16x4 __attribute__((ext_vector_type(4)));

__device__ __forceinline__ ushort_t f2bf(float f) {
    unsigned u = __builtin_bit_cast(unsigned, f);
    unsigned r = (u + 0x7FFFu + ((u >> 16) & 1u)) >> 16;
    return (ushort_t)r;
}
__device__ __forceinline__ float bf2f(ushort_t h) {
    unsigned u = ((unsigned)h) << 16;
    return __builtin_bit_cast(float, u);
}

// ---------------- fused f32 -> bf16 convert for all 5 buffers ----------------
// Region table in float4-quads. Sizes: w_in (2*DI)*DM = 4194304 f -> 1048576 q;
// w_xp 96*DI = 196608 -> 49152; w_dt DI*64 = 131072 -> 32768;
// w_out DM*DI = 2097152 -> 524288; x M*DM = 8388608 -> 2097152.
#define CV_E0 1048576
#define CV_E1 (CV_E0 + 49152)
#define CV_E2 (CV_E1 + 32768)
#define CV_E3 (CV_E2 + 524288)
#define CV_E4 (CV_E3 + 2097152)     // total 3751936 quads = 14656 * 256
__global__ __launch_bounds__(256) void k_cvt5(
    const float* __restrict__ s0, ushort_t* __restrict__ d0,
    const float* __restrict__ s1, ushort_t* __restrict__ d1,
    const float* __restrict__ s2, ushort_t* __restrict__ d2,
    const float* __restrict__ s3, ushort_t* __restrict__ d3,
    const float* __restrict__ s4, ushort_t* __restrict__ d4) {
    int g = blockIdx.x * 256 + threadIdx.x;
    const float* s;
    ushort_t* dst;
    int i;
    if (g < CV_E0)      { s = s0; dst = d0; i = g * 4; }
    else if (g < CV_E1) { s = s1; dst = d1; i = (g - CV_E0) * 4; }
    else if (g < CV_E2) { s = s2; dst = d2; i = (g - CV_E1) * 4; }
    else if (g < CV_E3) { s = s3; dst = d3; i = (g - CV_E2) * 4; }
    else                { s = s4; dst = d4; i = (g - CV_E3) * 4; }
    float4 v = *reinterpret_cast<const float4*>(s + i);
    ushort4 o;
    o.x = f2bf(v.x); o.y = f2bf(v.y); o.z = f2bf(v.z); o.w = f2bf(v.w);
    *reinterpret_cast<ushort4*>(dst + i) = o;
}

// ============ 256x256 8-phase MFMA GEMM for in_proj ============
#define FENCE asm volatile("" ::: "memory")
#define VM8 asm volatile("s_waitcnt vmcnt(8)" ::: "memory")
#define VM4 asm volatile("s_waitcnt vmcnt(4)" ::: "memory")
#define VM0 asm volatile("s_waitcnt vmcnt(0)" ::: "memory")

__device__ __forceinline__ void mfma16(f32x4 acc[8][4], const bf16x8 av[4],
                                       const bf16x8 bv[4], int mh) {
#pragma unroll
    for (int i = 0; i < 4; ++i)
#pragma unroll
        for (int j = 0; j < 4; ++j)
            acc[mh * 4 + i][j] =
                __builtin_amdgcn_mfma_f32_16x16x32_bf16(av[i], bv[j], acc[mh * 4 + i][j], 0, 0, 0);
}

#define PHASE(BUF, MH, STAGE_STMT, WAIT_STMT)                                     \
    {                                                                             \
        bf16x8 av[4], bv[4];                                                      \
        _Pragma("unroll") for (int i_ = 0; i_ < 4; ++i_)                          \
            av[i_] = *(const bf16x8*)&lds[(BUF) * 16384 + aoff + ((MH) * 4 + i_) * 512]; \
        _Pragma("unroll") for (int i_ = 0; i_ < 4; ++i_)                          \
            bv[i_] = *(const bf16x8*)&lds[(BUF) * 16384 + boff + i_ * 512];       \
        STAGE_STMT;                                                               \
        FENCE; __builtin_amdgcn_s_barrier(); FENCE;                               \
        asm volatile("s_waitcnt lgkmcnt(0)" ::: "memory");                        \
        __builtin_amdgcn_sched_barrier(0);                                        \
        __builtin_amdgcn_s_setprio(1);                                            \
        mfma16(acc, av, bv, (MH));                                                \
        __builtin_amdgcn_s_setprio(0);                                            \
        WAIT_STMT;                                                                \
        FENCE; __builtin_amdgcn_s_barrier(); FENCE;                               \
    }

__global__ __launch_bounds__(512, 2) void k_gemm8(const ushort_t* __restrict__ Aq,
                                                  const ushort_t* __restrict__ Bq,
                                                  ushort_t* __restrict__ C) {
    __shared__ ushort_t lds[65536];  // 128 KB: 4 buffers x (A 8192 + B 8192 elems)
    const int tid = threadIdx.x;
    const int w = tid >> 6, lane = tid & 63;
    const int l15 = lane & 15;
    const int wm = w >> 2, wn = w & 3;
    const int bid = blockIdx.x;
    const int tm = (bid & 7) * 4 + ((bid >> 3) & 3);
    const int tn = bid >> 5;
    const int row0 = tm * 256, col0 = tn * 256;

    const int rs = w * 16 + (lane >> 2);
    const int lcs = (lane & 3) ^ ((lane >> 3) & 3);
    const int pcr = ((lane >> 4) ^ ((l15 >> 1) & 3)) * 8;
    const int aoff = wm * 4096 + l15 * 32 + pcr;
    const int boff = 8192 + (wn >> 1) * 4096 + (wn & 1) * 2048 + l15 * 32 + pcr;

    auto stA = [&](int buf, int t) {
        const ushort_t* s = Aq + (size_t)(row0 + rs) * 1024 + t * 32 + lcs * 8;
        __builtin_amdgcn_global_load_lds(
            (const __attribute__((address_space(1))) void*)s,
            (__attribute__((address_space(3))) void*)&lds[buf * 16384 + w * 512], 16, 0, 0);
        __builtin_amdgcn_global_load_lds(
            (const __attribute__((address_space(1))) void*)(s + 128 * 1024),
            (__attribute__((address_space(3))) void*)&lds[buf * 16384 + 4096 + w * 512], 16, 0, 0);
    };
    auto stB = [&](int buf, int t) {
        const ushort_t* s = Bq + (size_t)(col0 + rs) * 1024 + t * 32 + lcs * 8;
        __builtin_amdgcn_global_load_lds(
            (const __attribute__((address_space(1))) void*)s,
            (__attribute__((address_space(3))) void*)&lds[buf * 16384 + 8192 + w * 512], 16, 0, 0);
        __builtin_amdgcn_global_load_lds(
            (const __attribute__((address_space(1))) void*)(s + 128 * 1024),
            (__attribute__((address_space(3))) void*)&lds[buf * 16384 + 12288 + w * 512], 16, 0, 0);
    };

    f32x4 acc[8][4] = {};

    stA(0, 0); stB(0, 0);
    stA(1, 1); stB(1, 1);
    stA(2, 2); stB(2, 2);
    VM8;
    FENCE; __builtin_amdgcn_s_barrier(); FENCE;

#pragma unroll 1
    for (int k = 0; k < 7; ++k) {
        const int t3 = 4 * k + 3;
        PHASE(0, 0, stA(3, t3), (void)0);
        PHASE(0, 1, stB(3, t3), VM8);
        PHASE(1, 0, stA(0, t3 + 1), (void)0);
        PHASE(1, 1, stB(0, t3 + 1), VM8);
        PHASE(2, 0, stA(1, t3 + 2), (void)0);
        PHASE(2, 1, stB(1, t3 + 2), VM8);
        PHASE(3, 0, stA(2, t3 + 3), (void)0);
        PHASE(3, 1, stB(2, t3 + 3), VM8);
    }
    PHASE(0, 0, stA(3, 31), (void)0);
    PHASE(0, 1, stB(3, 31), VM8);
    PHASE(1, 0, (void)0, (void)0);
    PHASE(1, 1, (void)0, VM4);
    PHASE(2, 0, (void)0, (void)0);
    PHASE(2, 1, (void)0, VM0);
    PHASE(3, 0, (void)0, (void)0);
    PHASE(3, 1, (void)0, (void)0);

#pragma unroll
    for (int mf = 0; mf < 8; ++mf)
#pragma unroll
        for (int nf = 0; nf < 4; ++nf) {
            int col = col0 + wn * 64 + nf * 16 + l15;
#pragma unroll
            for (int r = 0; r < 4; ++r) {
                int row = row0 + wm * 128 + mf * 16 + (lane >> 4) * 4 + r;
                C[(size_t)row * 4096 + col] = f2bf(acc[mf][nf][r]);
            }
        }
}

// ---------------- m97-structure bf16 MFMA GEMM (x_proj / dt_proj / out_proj) --
template <int EPI, bool OUTBF>
__global__ __launch_bounds__(256) void k_gemm2(
    const ushort_t* __restrict__ A, const ushort_t* __restrict__ Bw,
    void* __restrict__ C, const float* __restrict__ bias,
    int M, int N, int K, int lda, int ldb, int ldc, int tilesM) {
    __shared__ ushort_t As[128 * 64];
    __shared__ ushort_t Bs[128 * 64];
    int tid = threadIdx.x;
    int lane = tid & 63, wv = tid >> 6;
    int wr = wv >> 1, wc = wv & 1;
    int bid = blockIdx.x;
    int tilesN = gridDim.x / tilesM;
    int per = 8 * tilesN;
    int grp = bid / per, within = bid % per;
    int tm = grp * 8 + (within & 7);
    int tn = within >> 3;
    int row0 = tm * 128, col0 = tn * 128;
    int kchunk = K / gridDim.z;
    int kbeg = blockIdx.z * kchunk, kend = kbeg + kchunk;
    float* Cf = (float*)C + (size_t)blockIdx.z * (size_t)M * ldc;

    int sr = lane >> 3;
    int sj = lane & 7;
    f32x4 acc[4][4] = {};

    for (int k0 = kbeg; k0 < kend; k0 += 64) {
        __syncthreads();
#pragma unroll
        for (int i = 0; i < 4; ++i) {
            int slot = wv * 4 + i;
            int r = slot * 8 + sr;
            int jA = sj ^ (r & 7);
            __builtin_amdgcn_global_load_lds(
                (const __attribute__((address_space(1))) void*)&A[(size_t)(row0 + r) * lda + k0 + jA * 8],
                (__attribute__((address_space(3))) void*)&As[slot * 512], 16, 0, 0);
            __builtin_amdgcn_global_load_lds(
                (const __attribute__((address_space(1))) void*)&Bw[(size_t)(col0 + r) * ldb + k0 + jA * 8],
                (__attribute__((address_space(3))) void*)&Bs[slot * 512], 16, 0, 0);
        }
        __syncthreads();
#pragma unroll
        for (int kk = 0; kk < 2; ++kk) {
            int co = kk * 32 + (lane >> 4) * 8;
            int sx = (lane & 7) << 3;
            bf16x8 af[4], bfr[4];
#pragma unroll
            for (int m = 0; m < 4; ++m) {
                int rw = wr * 64 + m * 16 + (lane & 15);
                af[m] = *reinterpret_cast<const bf16x8*>(&As[rw * 64 + (co ^ sx)]);
            }
#pragma unroll
            for (int n = 0; n < 4; ++n) {
                int rw = wc * 64 + n * 16 + (lane & 15);
                bfr[n] = *reinterpret_cast<const bf16x8*>(&Bs[rw * 64 + (co ^ sx)]);
            }
#pragma unroll
            for (int m = 0; m < 4; ++m)
#pragma unroll
                for (int n = 0; n < 4; ++n)
                    acc[m][n] = __builtin_amdgcn_mfma_f32_16x16x32_bf16(af[m], bfr[n], acc[m][n], 0, 0, 0);
        }
    }

#pragma unroll
    for (int m = 0; m < 4; ++m) {
#pragma unroll
        for (int n = 0; n < 4; ++n) {
            int col = col0 + wc * 64 + n * 16 + (lane & 15);
            if (col >= N) continue;
#pragma unroll
            for (int r = 0; r < 4; ++r) {
                int row = row0 + wr * 64 + m * 16 + (lane >> 4) * 4 + r;
                float v = acc[m][n][r];
                if (EPI == 1) {
                    v += bias[col];
                    v = (v > 20.f) ? v : log1pf(__expf(v));
                }
                if (OUTBF)
                    ((ushort_t*)C)[(size_t)row * ldc + col] = f2bf(v);
                else
                    Cf[(size_t)row * ldc + col] = v;
            }
        }
    }
}

// ---------------- split-K partial reduce (4 partials f32 -> bf16) ------------
__global__ __launch_bounds__(256) void k_red4(const float* __restrict__ p,
                                              ushort_t* __restrict__ o,
                                              int n, int stride) {
    int i = (blockIdx.x * 256 + threadIdx.x) * 4;
    if (i >= n) return;
    f32x4 a = *reinterpret_cast<const f32x4*>(&p[i]);
    f32x4 b = *reinterpret_cast<const f32x4*>(&p[i + stride]);
    f32x4 c = *reinterpret_cast<const f32x4*>(&p[i + 2 * stride]);
    f32x4 d = *reinterpret_cast<const f32x4*>(&p[i + 3 * stride]);
    ushort4 r;
    r.x = f2bf(a[0] + b[0] + c[0] + d[0]);
    r.y = f2bf(a[1] + b[1] + c[1] + d[1]);
    r.z = f2bf(a[2] + b[2] + c[2] + d[2]);
    r.w = f2bf(a[3] + b[3] + c[3] + d[3]);
    *reinterpret_cast<ushort4*>(&o[i]) = r;
}

// ---------------- depthwise causal conv (width 4) + SiLU ----------------
__global__ __launch_bounds__(256) void k_conv(const ushort_t* __restrict__ xz,
                                              const float* __restrict__ w,
                                              const float* __restrict__ bias,
                                              ushort_t* __restrict__ out) {
    int d = blockIdx.x * 256 + threadIdx.x;
    int b = blockIdx.z;
    int t0 = blockIdx.y * 128;
    float w0 = w[d * 4 + 0], w1 = w[d * 4 + 1], w2 = w[d * 4 + 2], w3 = w[d * 4 + 3];
    float bi = bias[d];
    size_t base = ((size_t)b * L_) * (2 * DI) + d;
    size_t obase = ((size_t)b * L_) * DI + d;
    float x0 = (t0 >= 3) ? bf2f(xz[base + (size_t)(t0 - 3) * (2 * DI)]) : 0.f;
    float x1 = (t0 >= 2) ? bf2f(xz[base + (size_t)(t0 - 2) * (2 * DI)]) : 0.f;
    float x2 = (t0 >= 1) ? bf2f(xz[base + (size_t)(t0 - 1) * (2 * DI)]) : 0.f;
    for (int t = t0; t < t0 + 128; ++t) {
        float cur = bf2f(xz[base + (size_t)t * (2 * DI)]);
        float v = w0 * x0 + w1 * x1 + w2 * x2 + w3 * cur + bi;
        v = v / (1.f + __expf(-v));
        out[obase + (size_t)t * DI] = f2bf(v);
        x0 = x1; x1 = x2; x2 = cur;
    }
}

// ---------------- chunked selective scan ----------------
// LDS B/C rows read as f32x4 (ds_read_b128); FAST PATH exploits
// A[d][s] = -(s+1)*a1: exp(dt*A[s]) = p^(s+1), p = exp2(dt*arow0) ->
// 1 transcendental + pk-mul power chain. Runtime-checked per thread with
// general fallback, so correctness holds for arbitrary A_log.

// Phase 1: per-chunk local scan (h=0) -> chunk-final h and sum(dt)
__global__ __launch_bounds__(256) void k_scan1(
    const ushort_t* __restrict__ dt, const ushort_t* __restrict__ xm,
    const ushort_t* __restrict__ dbc, const float* __restrict__ A_log,
    float* __restrict__ hfin, float* __restrict__ dtsum) {
    __shared__ float Bsh[LC][DSTATE];
    int tid = threadIdx.x;
    int d = blockIdx.x * 256 + tid;
    int c = blockIdx.y, b = blockIdx.z;
    f32x16 arow;
    float a1 = __expf(A_log[d * DSTATE]);
    bool ok = true;
#pragma unroll
    for (int s = 0; s < DSTATE; ++s) {
        float av = __expf(A_log[d * DSTATE + s]);
        arow[s] = -av * LOG2E;
        ok = ok && (fabsf(av - (float)(s + 1) * a1) <= 1e-4f * (float)(s + 1) * fabsf(a1) + 1e-6f);
    }
    float arow0 = -a1 * LOG2E;
    size_t rbase = (size_t)b * L_ + (size_t)c * LC;
    {
        int i = tid * 4;
        int t = i >> 4, s0 = i & 15;
        u16x4 v = *reinterpret_cast<const u16x4*>(&dbc[(rbase + t) * 96 + DTR + s0]);
#pragma unroll
        for (int j = 0; j < 4; ++j) Bsh[t][s0 + j] = bf2f(v[j]);
    }
    __syncthreads();
    f32x4 h0 = {}, h1 = {}, h2 = {}, h3 = {};
    float sd = 0.f;
    if (ok) {
        for (int t = 0; t < LC; ++t) {
            size_t ro = rbase + t;
            float dtv = bf2f(dt[ro * DI + d]);
            float xv = bf2f(xm[ro * DI + d]);
            float dx = dtv * xv;
            sd += dtv;
            float p = __builtin_amdgcn_exp2f(dtv * arow0);
            float p2 = p * p, p3 = p2 * p, p4 = p2 * p2;
            f32x4 ea = {p, p2, p3, p4};
            f32x4 eb = ea * p4, ec = eb * p4, ed = ec * p4;
            const f32x4* Bq = reinterpret_cast<const f32x4*>(&Bsh[t][0]);
            h0 = h0 * ea + Bq[0] * dx;
            h1 = h1 * eb + Bq[1] * dx;
            h2 = h2 * ec + Bq[2] * dx;
            h3 = h3 * ed + Bq[3] * dx;
        }
    } else {
        for (int t = 0; t < LC; ++t) {
            size_t ro = rbase + t;
            float dtv = bf2f(dt[ro * DI + d]);
            float xv = bf2f(xm[ro * DI + d]);
            float dx = dtv * xv;
            sd += dtv;
            const f32x4* Bq = reinterpret_cast<const f32x4*>(&Bsh[t][0]);
            f32x4 e0, e1, e2, e3;
#pragma unroll
            for (int j = 0; j < 4; ++j) {
                e0[j] = __builtin_amdgcn_exp2f(dtv * arow[j]);
                e1[j] = __builtin_amdgcn_exp2f(dtv * arow[4 + j]);
                e2[j] = __builtin_amdgcn_exp2f(dtv * arow[8 + j]);
                e3[j] = __builtin_amdgcn_exp2f(dtv * arow[12 + j]);
            }
            h0 = h0 * e0 + Bq[0] * dx;
            h1 = h1 * e1 + Bq[1] * dx;
            h2 = h2 * e2 + Bq[2] * dx;
            h3 = h3 * e3 + Bq[3] * dx;
        }
    }
    size_t hbase = (((size_t)b * NC + c) * DI + d) * DSTATE;
    *reinterpret_cast<f32x4*>(&hfin[hbase + 0]) = h0;
    *reinterpret_cast<f32x4*>(&hfin[hbase + 4]) = h1;
    *reinterpret_cast<f32x4*>(&hfin[hbase + 8]) = h2;
    *reinterpret_cast<f32x4*>(&hfin[hbase + 12]) = h3;
    dtsum[((size_t)b * NC + c) * DI + d] = sd;
}

// Phase 2: sequential carry over chunks; hfin becomes carry-IN per chunk.
__global__ __launch_bounds__(256) void k_scan2(
    float* __restrict__ hfin, const float* __restrict__ dtsum,
    const float* __restrict__ A_log) {
    int gid = blockIdx.x * 256 + threadIdx.x;  // s fastest, then d, then b
    int s = gid & (DSTATE - 1);
    int d = (gid >> 4) & (DI - 1);
    int b = gid >> 15;
    float Av = -__expf(A_log[d * DSTATE + s]) * LOG2E;
    float carry = 0.f;
    for (int c = 0; c < NC; ++c) {
        size_t idx = (((size_t)b * NC + c) * DI + d) * DSTATE + s;
        float loc = hfin[idx];
        hfin[idx] = carry;
        float sd = dtsum[((size_t)b * NC + c) * DI + d];
        carry = __builtin_amdgcn_exp2f(Av * sd) * carry + loc;
    }
}

// Phase 3: local scan with carry-in + D*x + z-gating -> yg (bf16)
__global__ __launch_bounds__(256) void k_scan3(
    const ushort_t* __restrict__ dt, const ushort_t* __restrict__ xm,
    const ushort_t* __restrict__ xz, const ushort_t* __restrict__ dbc,
    const float* __restrict__ A_log, const float* __restrict__ Dp,
    const float* __restrict__ hinit, ushort_t* __restrict__ yg) {
    __shared__ float Bsh[LC][DSTATE];
    __shared__ float Csh[LC][DSTATE];
    int tid = threadIdx.x;
    int d = blockIdx.x * 256 + tid;
    int c = blockIdx.y, b = blockIdx.z;
    f32x16 arow;
    float a1 = __expf(A_log[d * DSTATE]);
    bool ok = true;
#pragma unroll
    for (int s = 0; s < DSTATE; ++s) {
        float av = __expf(A_log[d * DSTATE + s]);
        arow[s] = -av * LOG2E;
        ok = ok && (fabsf(av - (float)(s + 1) * a1) <= 1e-4f * (float)(s + 1) * fabsf(a1) + 1e-6f);
    }
    float arow0 = -a1 * LOG2E;
    float Dd = Dp[d];
    size_t rbase = (size_t)b * L_ + (size_t)c * LC;
    {
        int e0 = tid * 8;
        int t = e0 >> 5, s0 = e0 & 31;
        u16x8 v = *reinterpret_cast<const u16x8*>(&dbc[(rbase + t) * 96 + DTR + s0]);
#pragma unroll
        for (int j = 0; j < 8; ++j) {
            int s = s0 + j;
            float f = bf2f(v[j]);
            if (s < DSTATE) Bsh[t][s] = f;
            else Csh[t][s - DSTATE] = f;
        }
    }
    __syncthreads();
    size_t hbase = (((size_t)b * NC + c) * DI + d) * DSTATE;
    f32x4 h0 = *reinterpret_cast<const f32x4*>(&hinit[hbase + 0]);
    f32x4 h1 = *reinterpret_cast<const f32x4*>(&hinit[hbase + 4]);
    f32x4 h2 = *reinterpret_cast<const f32x4*>(&hinit[hbase + 8]);
    f32x4 h3 = *reinterpret_cast<const f32x4*>(&hinit[hbase + 12]);
    if (ok) {
        for (int t = 0; t < LC; ++t) {
            size_t ro = rbase + t;
            float dtv = bf2f(dt[ro * DI + d]);
            float xv = bf2f(xm[ro * DI + d]);
            float zv = bf2f(xz[ro * (2 * DI) + DI + d]);
            float dx = dtv * xv;
            float p = __builtin_amdgcn_exp2f(dtv * arow0);
            float p2 = p * p, p3 = p2 * p, p4 = p2 * p2;
            f32x4 ea = {p, p2, p3, p4};
            f32x4 eb = ea * p4, ec = eb * p4, ed = ec * p4;
            const f32x4* Bq = reinterpret_cast<const f32x4*>(&Bsh[t][0]);
            const f32x4* Cq = reinterpret_cast<const f32x4*>(&Csh[t][0]);
            h0 = h0 * ea + Bq[0] * dx;
            h1 = h1 * eb + Bq[1] * dx;
            h2 = h2 * ec + Bq[2] * dx;
            h3 = h3 * ed + Bq[3] * dx;
            f32x4 y4 = h0 * Cq[0] + h1 * Cq[1] + h2 * Cq[2] + h3 * Cq[3];
            float y = (y4[0] + y4[1]) + (y4[2] + y4[3]) + Dd * xv;
            y *= zv / (1.f + __expf(-zv));
            yg[ro * DI + d] = f2bf(y);
        }
    } else {
        for (int t = 0; t < LC; ++t) {
            size_t ro = rbase + t;
            float dtv = bf2f(dt[ro * DI + d]);
            float xv = bf2f(xm[ro * DI + d]);
            float zv = bf2f(xz[ro * (2 * DI) + DI + d]);
            float dx = dtv * xv;
            const f32x4* Bq = reinterpret_cast<const f32x4*>(&Bsh[t][0]);
            const f32x4* Cq = reinterpret_cast<const f32x4*>(&Csh[t][0]);
            f32x4 e0, e1, e2, e3;
#pragma unroll
            for (int j = 0; j < 4; ++j) {
                e0[j] = __builtin_amdgcn_exp2f(dtv * arow[j]);
                e1[j] = __builtin_amdgcn_exp2f(dtv * arow[4 + j]);
                e2[j] = __builtin_amdgcn_exp2f(dtv * arow[8 + j]);
                e3[j] = __builtin_amdgcn_exp2f(dtv * arow[12 + j]);
            }
            h0 = h0 * e0 + Bq[0] * dx;
            h1 = h1 * e1 + Bq[1] * dx;
            h2 = h2 * e2 + Bq[2] * dx;
            h3 = h3 * e3 + Bq[3] * dx;
            f32x4 y4 = h0 * Cq[0] + h1 * Cq[1] + h2 * Cq[2] + h3 * Cq[3];
            float y = (y4[0] + y4[1]) + (y4[2] + y4[3]) + Dd * xv;
            y *= zv / (1.f + __expf(-zv));
            yg[ro * DI + d] = f2bf(y);
        }
    }
}

// ---------------- residual + LayerNorm ----------------
__global__ __launch_bounds__(256) void k_ln(const float* __restrict__ mo,
                                            const float* __restrict__ x,
                                            const float* __restrict__ g,
                                            const float* __restrict__ be,
                                            float* __restrict__ out) {
    __shared__ float red[8];
    size_t r = blockIdx.x;
    int tid = threadIdx.x;
    float4 hv = *reinterpret_cast<const float4*>(&mo[r * DM + tid * 4]);
    float4 xv = *reinterpret_cast<const float4*>(&x[r * DM + tid * 4]);
    float h0 = hv.x + xv.x, h1 = hv.y + xv.y, h2 = hv.z + xv.z, h3 = hv.w + xv.w;
    float s = h0 + h1 + h2 + h3;
    float q = h0 * h0 + h1 * h1 + h2 * h2 + h3 * h3;
#pragma unroll
    for (int o = 32; o > 0; o >>= 1) {
        s += __shfl_down(s, o);
        q += __shfl_down(q, o);
    }
    int lane = tid & 63, wid = tid >> 6;
    if (lane == 0) { red[wid] = s; red[4 + wid] = q; }
    __syncthreads();
    s = red[0] + red[1] + red[2] + red[3];
    q = red[4] + red[5] + red[6] + red[7];
    float mu = s * (1.f / DM);
    float var = q * (1.f / DM) - mu * mu;
    float rs = rsqrtf(var + 1e-5f);
    float4 gv = *reinterpret_cast<const float4*>(&g[tid * 4]);
    float4 bv = *reinterpret_cast<const float4*>(&be[tid * 4]);
    float4 o;
    o.x = (h0 - mu) * rs * gv.x + bv.x;
    o.y = (h1 - mu) * rs * gv.y + bv.y;
    o.z = (h2 - mu) * rs * gv.z + bv.z;
    o.w = (h3 - mu) * rs * gv.w + bv.w;
    *reinterpret_cast<float4*>(&out[r * DM + tid * 4]) = o;
}

extern "C" void kernel_launch(void* const* d_in, const int* in_sizes, int n_in,
                              void* d_out, int out_size, void* d_ws, size_t ws_size,
                              hipStream_t stream) {
    const float* x      = (const float*)d_in[0];   // (B,L,DM)
    const float* w_in   = (const float*)d_in[1];   // (2*DI, DM)
    const float* conv_w = (const float*)d_in[2];   // (DI,1,4)
    const float* conv_b = (const float*)d_in[3];   // (DI)
    const float* w_xp   = (const float*)d_in[4];   // (96, DI)
    const float* w_dt   = (const float*)d_in[5];   // (DI, 64)
    const float* dt_b   = (const float*)d_in[6];   // (DI)
    const float* A_log  = (const float*)d_in[7];   // (DI,16)
    const float* Dp     = (const float*)d_in[8];   // (DI)
    const float* w_out  = (const float*)d_in[9];   // (DM, DI)
    const float* ln_g   = (const float*)d_in[10];
    const float* ln_b   = (const float*)d_in[11];
    float* out = (float*)d_out;

    char* ws = (char*)d_ws;
    size_t off = 0;
    auto alloc = [&](size_t bytes) -> void* {
        void* p = ws + off;
        off += (bytes + 255) & ~(size_t)255;
        return p;
    };
    const int M = B_ * L_;  // 8192
    ushort_t* w_in_b  = (ushort_t*)alloc((size_t)2 * DI * DM * 2);
    ushort_t* w_xp_b  = (ushort_t*)alloc((size_t)96 * DI * 2);
    ushort_t* w_dt_b  = (ushort_t*)alloc((size_t)DI * DTR * 2);
    ushort_t* w_out_b = (ushort_t*)alloc((size_t)DM * DI * 2);
    ushort_t* x_b     = (ushort_t*)alloc((size_t)M * DM * 2);   // 16.8 MB
    ushort_t* xz      = (ushort_t*)alloc((size_t)M * 2 * DI * 2);
    ushort_t* xm      = (ushort_t*)alloc((size_t)M * DI * 2);
    ushort_t* dbc     = (ushort_t*)alloc((size_t)M * 96 * 2);
    ushort_t* dtb     = (ushort_t*)alloc((size_t)M * DI * 2);   // bf16 dt (33.5 MB)
    ushort_t* yg      = (ushort_t*)alloc((size_t)M * DI * 2);
    float*    dtsum   = (float*)alloc((size_t)B_ * NC * DI * 4);
    float*    dbc_p   = (float*)alloc((size_t)4 * M * 96 * 4);  // split-K partials
    float*    mo      = (float*)dtb;   // alias: dt dead after scan3 (33.5 MB both)
    float*    hfin    = (float*)x_b;   // alias: x_b dead after in_proj (16.8 MB both)

    // fused f32->bf16 conversion of all inputs (1 launch instead of 5)
    k_cvt5<<<dim3(CV_E4 / 256), 256, 0, stream>>>(
        w_in, w_in_b, w_xp, w_xp_b, w_dt, w_dt_b, w_out, w_out_b, x, x_b);

    // in_proj: xz[8192,4096] = x_b @ w_in_b^T  (256^2 8-phase, 32x16 tiles)
    k_gemm8<<<dim3(512), 512, 0, stream>>>(x_b, w_in_b, xz);
    // conv + silu
    k_conv<<<dim3(DI / 256, L_ / 128, B_), 256, 0, stream>>>(xz, conv_w, conv_b, xm);
    // x_proj (split-K=4): dbc_p[z][M,96] = xm @ w_xp[96,2048]^T (K chunk 512)
    k_gemm2<0, false><<<dim3(64, 1, 4), 256, 0, stream>>>(
        xm, w_xp_b, dbc_p, nullptr, M, 96, DI, DI, DI, 96, 64);
    k_red4<<<dim3((M * 96 / 4 + 255) / 256), 256, 0, stream>>>(dbc_p, dbc, M * 96, M * 96);
    // dt_proj + softplus -> bf16: dt[M,2048] = softplus(dbc[:,:64] @ w_dt^T + b)
    k_gemm2<1, true><<<dim3(64 * 16, 1, 1), 256, 0, stream>>>(
        dbc, w_dt_b, dtb, dt_b, M, DI, DTR, 96, DTR, DI, 64);
    // chunked selective scan
    k_scan1<<<dim3(DI / 256, NC, B_), 256, 0, stream>>>(dtb, xm, dbc, A_log, hfin, dtsum);
    k_scan2<<<dim3(B_ * DI * DSTATE / 256), 256, 0, stream>>>(hfin, dtsum, A_log);
    k_scan3<<<dim3(DI / 256, NC, B_), 256, 0, stream>>>(dtb, xm, xz, dbc, A_log, Dp, hfin, yg);
    // out_proj: mo[M,1024] = yg @ w_out[1024,2048]^T  (64x8 tiles)
    k_gemm2<0, false><<<dim3(64 * 8, 1, 1), 256, 0, stream>>>(
        yg, w_out_b, mo, nullptr, M, DM, DI, DI, DI, DM, 64);
    // residual + layernorm
    k_ln<<<dim3(M), 256, 0, stream>>>(mo, x, ln_g, ln_b, out);
}

// Round 9
// 328.982 us; speedup vs baseline: 4.8855x; 1.0173x over previous
//
#include <hip/hip_runtime.h>
#include <hip/hip_bf16.h>

// Mamba block: B=4, L=2048, D_MODEL=1024, D_INNER=2048, D_STATE=16, DT_RANK=64
#define B_ 4
#define L_ 2048
#define DM 1024
#define DI 2048
#define DSTATE 16
#define DTR 64
#define LC 64            // scan chunk length
#define NC (L_ / LC)     // 32 chunks
#define LOG2E 1.44269504f

typedef unsigned short ushort_t;
typedef __bf16 bf16x8 __attribute__((ext_vector_type(8)));
typedef float f32x4 __attribute__((ext_vector_type(4)));
typedef float f32x16 __attribute__((ext_vector_type(16)));
typedef unsigned short u16x8 __attribute__((ext_vector_type(8)));
typedef unsigned short u16x4 __attribute__((ext_vector_type(4)));

__device__ __forceinline__ ushort_t f2bf(float f) {
    unsigned u = __builtin_bit_cast(unsigned, f);
    unsigned r = (u + 0x7FFFu + ((u >> 16) & 1u)) >> 16;
    return (ushort_t)r;
}
__device__ __forceinline__ float bf2f(ushort_t h) {
    unsigned u = ((unsigned)h) << 16;
    return __builtin_bit_cast(float, u);
}

// ---------------- fused f32 -> bf16 convert for all 5 buffers ----------------
#define CV_E0 1048576
#define CV_E1 (CV_E0 + 49152)
#define CV_E2 (CV_E1 + 32768)
#define CV_E3 (CV_E2 + 524288)
#define CV_E4 (CV_E3 + 2097152)     // total 3751936 quads = 14656 * 256
__global__ __launch_bounds__(256) void k_cvt5(
    const float* __restrict__ s0, ushort_t* __restrict__ d0,
    const float* __restrict__ s1, ushort_t* __restrict__ d1,
    const float* __restrict__ s2, ushort_t* __restrict__ d2,
    const float* __restrict__ s3, ushort_t* __restrict__ d3,
    const float* __restrict__ s4, ushort_t* __restrict__ d4) {
    int g = blockIdx.x * 256 + threadIdx.x;
    const float* s;
    ushort_t* dst;
    int i;
    if (g < CV_E0)      { s = s0; dst = d0; i = g * 4; }
    else if (g < CV_E1) { s = s1; dst = d1; i = (g - CV_E0) * 4; }
    else if (g < CV_E2) { s = s2; dst = d2; i = (g - CV_E1) * 4; }
    else if (g < CV_E3) { s = s3; dst = d3; i = (g - CV_E2) * 4; }
    else                { s = s4; dst = d4; i = (g - CV_E3) * 4; }
    float4 v = *reinterpret_cast<const float4*>(s + i);
    ushort4 o;
    o.x = f2bf(v.x); o.y = f2bf(v.y); o.z = f2bf(v.z); o.w = f2bf(v.w);
    *reinterpret_cast<ushort4*>(dst + i) = o;
}

// ============ 8-phase MFMA GEMM machinery ============
#define FENCE asm volatile("" ::: "memory")
#define VM8 asm volatile("s_waitcnt vmcnt(8)" ::: "memory")
#define VM6 asm volatile("s_waitcnt vmcnt(6)" ::: "memory")
#define VM4 asm volatile("s_waitcnt vmcnt(4)" ::: "memory")
#define VM3 asm volatile("s_waitcnt vmcnt(3)" ::: "memory")
#define VM0 asm volatile("s_waitcnt vmcnt(0)" ::: "memory")

__device__ __forceinline__ void mfma16(f32x4 acc[8][4], const bf16x8 av[4],
                                       const bf16x8 bv[4], int mh) {
#pragma unroll
    for (int i = 0; i < 4; ++i)
#pragma unroll
        for (int j = 0; j < 4; ++j)
            acc[mh * 4 + i][j] =
                __builtin_amdgcn_mfma_f32_16x16x32_bf16(av[i], bv[j], acc[mh * 4 + i][j], 0, 0, 0);
}

#define PHASE(BUF, MH, STAGE_STMT, WAIT_STMT)                                     \
    {                                                                             \
        bf16x8 av[4], bv[4];                                                      \
        _Pragma("unroll") for (int i_ = 0; i_ < 4; ++i_)                          \
            av[i_] = *(const bf16x8*)&lds[(BUF) * 16384 + aoff + ((MH) * 4 + i_) * 512]; \
        _Pragma("unroll") for (int i_ = 0; i_ < 4; ++i_)                          \
            bv[i_] = *(const bf16x8*)&lds[(BUF) * 16384 + boff + i_ * 512];       \
        STAGE_STMT;                                                               \
        FENCE; __builtin_amdgcn_s_barrier(); FENCE;                               \
        asm volatile("s_waitcnt lgkmcnt(0)" ::: "memory");                        \
        __builtin_amdgcn_sched_barrier(0);                                        \
        __builtin_amdgcn_s_setprio(1);                                            \
        mfma16(acc, av, bv, (MH));                                                \
        __builtin_amdgcn_s_setprio(0);                                            \
        WAIT_STMT;                                                                \
        FENCE; __builtin_amdgcn_s_barrier(); FENCE;                               \
    }

// -------- in_proj: C[8192,4096](bf16) = A[8192,1024] * W[4096,1024]^T --------
__global__ __launch_bounds__(512, 2) void k_gemm8(const ushort_t* __restrict__ Aq,
                                                  const ushort_t* __restrict__ Bq,
                                                  ushort_t* __restrict__ C) {
    __shared__ ushort_t lds[65536];  // 128 KB: 4 buffers x (A 8192 + B 8192 elems)
    const int tid = threadIdx.x;
    const int w = tid >> 6, lane = tid & 63;
    const int l15 = lane & 15;
    const int wm = w >> 2, wn = w & 3;
    const int bid = blockIdx.x;
    const int tm = (bid & 7) * 4 + ((bid >> 3) & 3);
    const int tn = bid >> 5;
    const int row0 = tm * 256, col0 = tn * 256;

    const int rs = w * 16 + (lane >> 2);
    const int lcs = (lane & 3) ^ ((lane >> 3) & 3);
    const int pcr = ((lane >> 4) ^ ((l15 >> 1) & 3)) * 8;
    const int aoff = wm * 4096 + l15 * 32 + pcr;
    const int boff = 8192 + (wn >> 1) * 4096 + (wn & 1) * 2048 + l15 * 32 + pcr;

    auto stA = [&](int buf, int t) {
        const ushort_t* s = Aq + (size_t)(row0 + rs) * 1024 + t * 32 + lcs * 8;
        __builtin_amdgcn_global_load_lds(
            (const __attribute__((address_space(1))) void*)s,
            (__attribute__((address_space(3))) void*)&lds[buf * 16384 + w * 512], 16, 0, 0);
        __builtin_amdgcn_global_load_lds(
            (const __attribute__((address_space(1))) void*)(s + 128 * 1024),
            (__attribute__((address_space(3))) void*)&lds[buf * 16384 + 4096 + w * 512], 16, 0, 0);
    };
    auto stB = [&](int buf, int t) {
        const ushort_t* s = Bq + (size_t)(col0 + rs) * 1024 + t * 32 + lcs * 8;
        __builtin_amdgcn_global_load_lds(
            (const __attribute__((address_space(1))) void*)s,
            (__attribute__((address_space(3))) void*)&lds[buf * 16384 + 8192 + w * 512], 16, 0, 0);
        __builtin_amdgcn_global_load_lds(
            (const __attribute__((address_space(1))) void*)(s + 128 * 1024),
            (__attribute__((address_space(3))) void*)&lds[buf * 16384 + 12288 + w * 512], 16, 0, 0);
    };

    f32x4 acc[8][4] = {};

    stA(0, 0); stB(0, 0);
    stA(1, 1); stB(1, 1);
    stA(2, 2); stB(2, 2);
    VM8;
    FENCE; __builtin_amdgcn_s_barrier(); FENCE;

#pragma unroll 1
    for (int k = 0; k < 7; ++k) {
        const int t3 = 4 * k + 3;
        PHASE(0, 0, stA(3, t3), (void)0);
        PHASE(0, 1, stB(3, t3), VM8);
        PHASE(1, 0, stA(0, t3 + 1), (void)0);
        PHASE(1, 1, stB(0, t3 + 1), VM8);
        PHASE(2, 0, stA(1, t3 + 2), (void)0);
        PHASE(2, 1, stB(1, t3 + 2), VM8);
        PHASE(3, 0, stA(2, t3 + 3), (void)0);
        PHASE(3, 1, stB(2, t3 + 3), VM8);
    }
    PHASE(0, 0, stA(3, 31), (void)0);
    PHASE(0, 1, stB(3, 31), VM8);
    PHASE(1, 0, (void)0, (void)0);
    PHASE(1, 1, (void)0, VM4);
    PHASE(2, 0, (void)0, (void)0);
    PHASE(2, 1, (void)0, VM0);
    PHASE(3, 0, (void)0, (void)0);
    PHASE(3, 1, (void)0, (void)0);

#pragma unroll
    for (int mf = 0; mf < 8; ++mf)
#pragma unroll
        for (int nf = 0; nf < 4; ++nf) {
            int col = col0 + wn * 64 + nf * 16 + l15;
#pragma unroll
            for (int r = 0; r < 4; ++r) {
                int row = row0 + wm * 128 + mf * 16 + (lane >> 4) * 4 + r;
                C[(size_t)row * 4096 + col] = f2bf(acc[mf][nf][r]);
            }
        }
}

// -------- out_proj: mo[8192,1024](bf16) = yg[8192,2048] * w_out[1024,2048]^T --
// BM=256, BN=128, BK=32; grid 256 (=1 block/CU); 4 ring buffers x 24KB = 96KB.
// 3 loads/buffer -> counted VM6 per phase (2 buffers = 6 loads in flight).
__global__ __launch_bounds__(512, 2) void k_gemm8o(const ushort_t* __restrict__ Aq,
                                                   const ushort_t* __restrict__ Bq,
                                                   ushort_t* __restrict__ C) {
    __shared__ ushort_t lds[49152];  // 96 KB: 4 x (A 8192 + B 4096 elems)
    const int tid = threadIdx.x;
    const int w = tid >> 6, lane = tid & 63;
    const int l15 = lane & 15;
    const int wm = w >> 2, wn = w & 3;  // wm: 128-row half, wn: 32-col quarter
    const int bid = blockIdx.x;
    const int tm = bid & 31, tn = bid >> 5;   // 32 consecutive bids share B-panel
    const int row0 = tm * 256, col0 = tn * 128;

    const int rs = w * 16 + (lane >> 2);
    const int lcs = (lane & 3) ^ ((lane >> 3) & 3);
    const int pcr = ((lane >> 4) ^ ((l15 >> 1) & 3)) * 8;
    const int aoff = wm * 4096 + l15 * 32 + pcr;
    const int boff = 8192 + wn * 1024 + l15 * 32 + pcr;

    auto stg = [&](int buf, int t) {
        const ushort_t* sa = Aq + (size_t)(row0 + rs) * 2048 + t * 32 + lcs * 8;
        __builtin_amdgcn_global_load_lds(
            (const __attribute__((address_space(1))) void*)sa,
            (__attribute__((address_space(3))) void*)&lds[buf * 12288 + w * 512], 16, 0, 0);
        __builtin_amdgcn_global_load_lds(
            (const __attribute__((address_space(1))) void*)(sa + 128 * 2048),
            (__attribute__((address_space(3))) void*)&lds[buf * 12288 + 4096 + w * 512], 16, 0, 0);
        const ushort_t* sb = Bq + (size_t)(col0 + rs) * 2048 + t * 32 + lcs * 8;
        __builtin_amdgcn_global_load_lds(
            (const __attribute__((address_space(1))) void*)sb,
            (__attribute__((address_space(3))) void*)&lds[buf * 12288 + 8192 + w * 512], 16, 0, 0);
    };

    f32x4 acc[8][2] = {};

#define OPHASE(BUF, STAGE_STMT, WAIT_STMT)                                        \
    {                                                                             \
        bf16x8 av[8], bv[2];                                                      \
        _Pragma("unroll") for (int i_ = 0; i_ < 8; ++i_)                          \
            av[i_] = *(const bf16x8*)&lds[(BUF) * 12288 + aoff + i_ * 512];       \
        _Pragma("unroll") for (int i_ = 0; i_ < 2; ++i_)                          \
            bv[i_] = *(const bf16x8*)&lds[(BUF) * 12288 + boff + i_ * 512];       \
        STAGE_STMT;                                                               \
        FENCE; __builtin_amdgcn_s_barrier(); FENCE;                               \
        asm volatile("s_waitcnt lgkmcnt(0)" ::: "memory");                        \
        __builtin_amdgcn_sched_barrier(0);                                        \
        __builtin_amdgcn_s_setprio(1);                                            \
        _Pragma("unroll") for (int i_ = 0; i_ < 8; ++i_)                          \
            _Pragma("unroll") for (int j_ = 0; j_ < 2; ++j_)                      \
                acc[i_][j_] = __builtin_amdgcn_mfma_f32_16x16x32_bf16(            \
                    av[i_], bv[j_], acc[i_][j_], 0, 0, 0);                        \
        __builtin_amdgcn_s_setprio(0);                                            \
        WAIT_STMT;                                                                \
        FENCE; __builtin_amdgcn_s_barrier(); FENCE;                               \
    }

    stg(0, 0); stg(1, 1); stg(2, 2);   // 9 loads
    VM6;                                // confirm R0's 3
    FENCE; __builtin_amdgcn_s_barrier(); FENCE;

#pragma unroll 1
    for (int k = 0; k < 15; ++k) {
        const int t3 = 4 * k + 3;
        OPHASE(0, stg(3, t3), VM6);
        OPHASE(1, stg(0, t3 + 1), VM6);
        OPHASE(2, stg(1, t3 + 2), VM6);
        OPHASE(3, stg(2, t3 + 3), VM6);
    }
    // last iteration k=15: tiles 60..63; only tile 63 left to stage
    OPHASE(0, stg(3, 63), VM6);
    OPHASE(1, (void)0, VM3);
    OPHASE(2, (void)0, VM0);
    OPHASE(3, (void)0, (void)0);
#undef OPHASE

#pragma unroll
    for (int mf = 0; mf < 8; ++mf)
#pragma unroll
        for (int nf = 0; nf < 2; ++nf) {
            int col = col0 + wn * 32 + nf * 16 + l15;
#pragma unroll
            for (int r = 0; r < 4; ++r) {
                int row = row0 + wm * 128 + mf * 16 + (lane >> 4) * 4 + r;
                C[(size_t)row * 1024 + col] = f2bf(acc[mf][nf][r]);
            }
        }
}

// ---------------- m97-structure bf16 MFMA GEMM (x_proj / dt_proj) ------------
template <int EPI, bool OUTBF>
__global__ __launch_bounds__(256) void k_gemm2(
    const ushort_t* __restrict__ A, const ushort_t* __restrict__ Bw,
    void* __restrict__ C, const float* __restrict__ bias,
    int M, int N, int K, int lda, int ldb, int ldc, int tilesM) {
    __shared__ ushort_t As[128 * 64];
    __shared__ ushort_t Bs[128 * 64];
    int tid = threadIdx.x;
    int lane = tid & 63, wv = tid >> 6;
    int wr = wv >> 1, wc = wv & 1;
    int bid = blockIdx.x;
    int tilesN = gridDim.x / tilesM;
    int per = 8 * tilesN;
    int grp = bid / per, within = bid % per;
    int tm = grp * 8 + (within & 7);
    int tn = within >> 3;
    int row0 = tm * 128, col0 = tn * 128;
    int kchunk = K / gridDim.z;
    int kbeg = blockIdx.z * kchunk, kend = kbeg + kchunk;
    float* Cf = (float*)C + (size_t)blockIdx.z * (size_t)M * ldc;

    int sr = lane >> 3;
    int sj = lane & 7;
    f32x4 acc[4][4] = {};

    for (int k0 = kbeg; k0 < kend; k0 += 64) {
        __syncthreads();
#pragma unroll
        for (int i = 0; i < 4; ++i) {
            int slot = wv * 4 + i;
            int r = slot * 8 + sr;
            int jA = sj ^ (r & 7);
            __builtin_amdgcn_global_load_lds(
                (const __attribute__((address_space(1))) void*)&A[(size_t)(row0 + r) * lda + k0 + jA * 8],
                (__attribute__((address_space(3))) void*)&As[slot * 512], 16, 0, 0);
            __builtin_amdgcn_global_load_lds(
                (const __attribute__((address_space(1))) void*)&Bw[(size_t)(col0 + r) * ldb + k0 + jA * 8],
                (__attribute__((address_space(3))) void*)&Bs[slot * 512], 16, 0, 0);
        }
        __syncthreads();
#pragma unroll
        for (int kk = 0; kk < 2; ++kk) {
            int co = kk * 32 + (lane >> 4) * 8;
            int sx = (lane & 7) << 3;
            bf16x8 af[4], bfr[4];
#pragma unroll
            for (int m = 0; m < 4; ++m) {
                int rw = wr * 64 + m * 16 + (lane & 15);
                af[m] = *reinterpret_cast<const bf16x8*>(&As[rw * 64 + (co ^ sx)]);
            }
#pragma unroll
            for (int n = 0; n < 4; ++n) {
                int rw = wc * 64 + n * 16 + (lane & 15);
                bfr[n] = *reinterpret_cast<const bf16x8*>(&Bs[rw * 64 + (co ^ sx)]);
            }
#pragma unroll
            for (int m = 0; m < 4; ++m)
#pragma unroll
                for (int n = 0; n < 4; ++n)
                    acc[m][n] = __builtin_amdgcn_mfma_f32_16x16x32_bf16(af[m], bfr[n], acc[m][n], 0, 0, 0);
        }
    }

#pragma unroll
    for (int m = 0; m < 4; ++m) {
#pragma unroll
        for (int n = 0; n < 4; ++n) {
            int col = col0 + wc * 64 + n * 16 + (lane & 15);
            if (col >= N) continue;
#pragma unroll
            for (int r = 0; r < 4; ++r) {
                int row = row0 + wr * 64 + m * 16 + (lane >> 4) * 4 + r;
                float v = acc[m][n][r];
                if (EPI == 1) {
                    v += bias[col];
                    v = (v > 20.f) ? v : log1pf(__expf(v));
                }
                if (OUTBF)
                    ((ushort_t*)C)[(size_t)row * ldc + col] = f2bf(v);
                else
                    Cf[(size_t)row * ldc + col] = v;
            }
        }
    }
}

// ---------------- split-K partial reduce (4 partials f32 -> bf16) ------------
__global__ __launch_bounds__(256) void k_red4(const float* __restrict__ p,
                                              ushort_t* __restrict__ o,
                                              int n, int stride) {
    int i = (blockIdx.x * 256 + threadIdx.x) * 4;
    if (i >= n) return;
    f32x4 a = *reinterpret_cast<const f32x4*>(&p[i]);
    f32x4 b = *reinterpret_cast<const f32x4*>(&p[i + stride]);
    f32x4 c = *reinterpret_cast<const f32x4*>(&p[i + 2 * stride]);
    f32x4 d = *reinterpret_cast<const f32x4*>(&p[i + 3 * stride]);
    ushort4 r;
    r.x = f2bf(a[0] + b[0] + c[0] + d[0]);
    r.y = f2bf(a[1] + b[1] + c[1] + d[1]);
    r.z = f2bf(a[2] + b[2] + c[2] + d[2]);
    r.w = f2bf(a[3] + b[3] + c[3] + d[3]);
    *reinterpret_cast<ushort4*>(&o[i]) = r;
}

// ---------------- depthwise causal conv (width 4) + SiLU ----------------
__global__ __launch_bounds__(256) void k_conv(const ushort_t* __restrict__ xz,
                                              const float* __restrict__ w,
                                              const float* __restrict__ bias,
                                              ushort_t* __restrict__ out) {
    int d = blockIdx.x * 256 + threadIdx.x;
    int b = blockIdx.z;
    int t0 = blockIdx.y * 128;
    float w0 = w[d * 4 + 0], w1 = w[d * 4 + 1], w2 = w[d * 4 + 2], w3 = w[d * 4 + 3];
    float bi = bias[d];
    size_t base = ((size_t)b * L_) * (2 * DI) + d;
    size_t obase = ((size_t)b * L_) * DI + d;
    float x0 = (t0 >= 3) ? bf2f(xz[base + (size_t)(t0 - 3) * (2 * DI)]) : 0.f;
    float x1 = (t0 >= 2) ? bf2f(xz[base + (size_t)(t0 - 2) * (2 * DI)]) : 0.f;
    float x2 = (t0 >= 1) ? bf2f(xz[base + (size_t)(t0 - 1) * (2 * DI)]) : 0.f;
    for (int t = t0; t < t0 + 128; ++t) {
        float cur = bf2f(xz[base + (size_t)t * (2 * DI)]);
        float v = w0 * x0 + w1 * x1 + w2 * x2 + w3 * cur + bi;
        v = v / (1.f + __expf(-v));
        out[obase + (size_t)t * DI] = f2bf(v);
        x0 = x1; x1 = x2; x2 = cur;
    }
}

// ---------------- chunked selective scan ----------------
// Phase 1: per-chunk local scan (h=0) -> chunk-final h and sum(dt)
__global__ __launch_bounds__(256) void k_scan1(
    const ushort_t* __restrict__ dt, const ushort_t* __restrict__ xm,
    const ushort_t* __restrict__ dbc, const float* __restrict__ A_log,
    float* __restrict__ hfin, float* __restrict__ dtsum) {
    __shared__ float Bsh[LC][DSTATE];
    int tid = threadIdx.x;
    int d = blockIdx.x * 256 + tid;
    int c = blockIdx.y, b = blockIdx.z;
    f32x16 arow;
    float a1 = __expf(A_log[d * DSTATE]);
    bool ok = true;
#pragma unroll
    for (int s = 0; s < DSTATE; ++s) {
        float av = __expf(A_log[d * DSTATE + s]);
        arow[s] = -av * LOG2E;
        ok = ok && (fabsf(av - (float)(s + 1) * a1) <= 1e-4f * (float)(s + 1) * fabsf(a1) + 1e-6f);
    }
    float arow0 = -a1 * LOG2E;
    size_t rbase = (size_t)b * L_ + (size_t)c * LC;
    {
        int i = tid * 4;
        int t = i >> 4, s0 = i & 15;
        u16x4 v = *reinterpret_cast<const u16x4*>(&dbc[(rbase + t) * 96 + DTR + s0]);
#pragma unroll
        for (int j = 0; j < 4; ++j) Bsh[t][s0 + j] = bf2f(v[j]);
    }
    __syncthreads();
    f32x4 h0 = {}, h1 = {}, h2 = {}, h3 = {};
    float sd = 0.f;
    if (ok) {
        for (int t = 0; t < LC; ++t) {
            size_t ro = rbase + t;
            float dtv = bf2f(dt[ro * DI + d]);
            float xv = bf2f(xm[ro * DI + d]);
            float dx = dtv * xv;
            sd += dtv;
            float p = __builtin_amdgcn_exp2f(dtv * arow0);
            float p2 = p * p, p3 = p2 * p, p4 = p2 * p2;
            f32x4 ea = {p, p2, p3, p4};
            f32x4 eb = ea * p4, ec = eb * p4, ed = ec * p4;
            const f32x4* Bq = reinterpret_cast<const f32x4*>(&Bsh[t][0]);
            h0 = h0 * ea + Bq[0] * dx;
            h1 = h1 * eb + Bq[1] * dx;
            h2 = h2 * ec + Bq[2] * dx;
            h3 = h3 * ed + Bq[3] * dx;
        }
    } else {
        for (int t = 0; t < LC; ++t) {
            size_t ro = rbase + t;
            float dtv = bf2f(dt[ro * DI + d]);
            float xv = bf2f(xm[ro * DI + d]);
            float dx = dtv * xv;
            sd += dtv;
            const f32x4* Bq = reinterpret_cast<const f32x4*>(&Bsh[t][0]);
            f32x4 e0, e1, e2, e3;
#pragma unroll
            for (int j = 0; j < 4; ++j) {
                e0[j] = __builtin_amdgcn_exp2f(dtv * arow[j]);
                e1[j] = __builtin_amdgcn_exp2f(dtv * arow[4 + j]);
                e2[j] = __builtin_amdgcn_exp2f(dtv * arow[8 + j]);
                e3[j] = __builtin_amdgcn_exp2f(dtv * arow[12 + j]);
            }
            h0 = h0 * e0 + Bq[0] * dx;
            h1 = h1 * e1 + Bq[1] * dx;
            h2 = h2 * e2 + Bq[2] * dx;
            h3 = h3 * e3 + Bq[3] * dx;
        }
    }
    size_t hbase = (((size_t)b * NC + c) * DI + d) * DSTATE;
    *reinterpret_cast<f32x4*>(&hfin[hbase + 0]) = h0;
    *reinterpret_cast<f32x4*>(&hfin[hbase + 4]) = h1;
    *reinterpret_cast<f32x4*>(&hfin[hbase + 8]) = h2;
    *reinterpret_cast<f32x4*>(&hfin[hbase + 12]) = h3;
    dtsum[((size_t)b * NC + c) * DI + d] = sd;
}

// Phase 2: sequential carry over chunks; hfin becomes carry-IN per chunk.
__global__ __launch_bounds__(256) void k_scan2(
    float* __restrict__ hfin, const float* __restrict__ dtsum,
    const float* __restrict__ A_log) {
    int gid = blockIdx.x * 256 + threadIdx.x;  // s fastest, then d, then b
    int s = gid & (DSTATE - 1);
    int d = (gid >> 4) & (DI - 1);
    int b = gid >> 15;
    float Av = -__expf(A_log[d * DSTATE + s]) * LOG2E;
    float carry = 0.f;
    for (int c = 0; c < NC; ++c) {
        size_t idx = (((size_t)b * NC + c) * DI + d) * DSTATE + s;
        float loc = hfin[idx];
        hfin[idx] = carry;
        float sd = dtsum[((size_t)b * NC + c) * DI + d];
        carry = __builtin_amdgcn_exp2f(Av * sd) * carry + loc;
    }
}

// Phase 3: local scan with carry-in + D*x + z-gating -> yg (bf16)
__global__ __launch_bounds__(256) void k_scan3(
    const ushort_t* __restrict__ dt, const ushort_t* __restrict__ xm,
    const ushort_t* __restrict__ xz, const ushort_t* __restrict__ dbc,
    const float* __restrict__ A_log, const float* __restrict__ Dp,
    const float* __restrict__ hinit, ushort_t* __restrict__ yg) {
    __shared__ float Bsh[LC][DSTATE];
    __shared__ float Csh[LC][DSTATE];
    int tid = threadIdx.x;
    int d = blockIdx.x * 256 + tid;
    int c = blockIdx.y, b = blockIdx.z;
    f32x16 arow;
    float a1 = __expf(A_log[d * DSTATE]);
    bool ok = true;
#pragma unroll
    for (int s = 0; s < DSTATE; ++s) {
        float av = __expf(A_log[d * DSTATE + s]);
        arow[s] = -av * LOG2E;
        ok = ok && (fabsf(av - (float)(s + 1) * a1) <= 1e-4f * (float)(s + 1) * fabsf(a1) + 1e-6f);
    }
    float arow0 = -a1 * LOG2E;
    float Dd = Dp[d];
    size_t rbase = (size_t)b * L_ + (size_t)c * LC;
    {
        int e0 = tid * 8;
        int t = e0 >> 5, s0 = e0 & 31;
        u16x8 v = *reinterpret_cast<const u16x8*>(&dbc[(rbase + t) * 96 + DTR + s0]);
#pragma unroll
        for (int j = 0; j < 8; ++j) {
            int s = s0 + j;
            float f = bf2f(v[j]);
            if (s < DSTATE) Bsh[t][s] = f;
            else Csh[t][s - DSTATE] = f;
        }
    }
    __syncthreads();
    size_t hbase = (((size_t)b * NC + c) * DI + d) * DSTATE;
    f32x4 h0 = *reinterpret_cast<const f32x4*>(&hinit[hbase + 0]);
    f32x4 h1 = *reinterpret_cast<const f32x4*>(&hinit[hbase + 4]);
    f32x4 h2 = *reinterpret_cast<const f32x4*>(&hinit[hbase + 8]);
    f32x4 h3 = *reinterpret_cast<const f32x4*>(&hinit[hbase + 12]);
    if (ok) {
        for (int t = 0; t < LC; ++t) {
            size_t ro = rbase + t;
            float dtv = bf2f(dt[ro * DI + d]);
            float xv = bf2f(xm[ro * DI + d]);
            float zv = bf2f(xz[ro * (2 * DI) + DI + d]);
            float dx = dtv * xv;
            float p = __builtin_amdgcn_exp2f(dtv * arow0);
            float p2 = p * p, p3 = p2 * p, p4 = p2 * p2;
            f32x4 ea = {p, p2, p3, p4};
            f32x4 eb = ea * p4, ec = eb * p4, ed = ec * p4;
            const f32x4* Bq = reinterpret_cast<const f32x4*>(&Bsh[t][0]);
            const f32x4* Cq = reinterpret_cast<const f32x4*>(&Csh[t][0]);
            h0 = h0 * ea + Bq[0] * dx;
            h1 = h1 * eb + Bq[1] * dx;
            h2 = h2 * ec + Bq[2] * dx;
            h3 = h3 * ed + Bq[3] * dx;
            f32x4 y4 = h0 * Cq[0] + h1 * Cq[1] + h2 * Cq[2] + h3 * Cq[3];
            float y = (y4[0] + y4[1]) + (y4[2] + y4[3]) + Dd * xv;
            y *= zv / (1.f + __expf(-zv));
            yg[ro * DI + d] = f2bf(y);
        }
    } else {
        for (int t = 0; t < LC; ++t) {
            size_t ro = rbase + t;
            float dtv = bf2f(dt[ro * DI + d]);
            float xv = bf2f(xm[ro * DI + d]);
            float zv = bf2f(xz[ro * (2 * DI) + DI + d]);
            float dx = dtv * xv;
            const f32x4* Bq = reinterpret_cast<const f32x4*>(&Bsh[t][0]);
            const f32x4* Cq = reinterpret_cast<const f32x4*>(&Csh[t][0]);
            f32x4 e0, e1, e2, e3;
#pragma unroll
            for (int j = 0; j < 4; ++j) {
                e0[j] = __builtin_amdgcn_exp2f(dtv * arow[j]);
                e1[j] = __builtin_amdgcn_exp2f(dtv * arow[4 + j]);
                e2[j] = __builtin_amdgcn_exp2f(dtv * arow[8 + j]);
                e3[j] = __builtin_amdgcn_exp2f(dtv * arow[12 + j]);
            }
            h0 = h0 * e0 + Bq[0] * dx;
            h1 = h1 * e1 + Bq[1] * dx;
            h2 = h2 * e2 + Bq[2] * dx;
            h3 = h3 * e3 + Bq[3] * dx;
            f32x4 y4 = h0 * Cq[0] + h1 * Cq[1] + h2 * Cq[2] + h3 * Cq[3];
            float y = (y4[0] + y4[1]) + (y4[2] + y4[3]) + Dd * xv;
            y *= zv / (1.f + __expf(-zv));
            yg[ro * DI + d] = f2bf(y);
        }
    }
}

// ---------------- residual + LayerNorm (bf16 mamba-out) ----------------
__global__ __launch_bounds__(256) void k_ln(const ushort_t* __restrict__ mo,
                                            const float* __restrict__ x,
                                            const float* __restrict__ g,
                                            const float* __restrict__ be,
                                            float* __restrict__ out) {
    __shared__ float red[8];
    size_t r = blockIdx.x;
    int tid = threadIdx.x;
    ushort4 mv = *reinterpret_cast<const ushort4*>(&mo[r * DM + tid * 4]);
    float4 xv = *reinterpret_cast<const float4*>(&x[r * DM + tid * 4]);
    float h0 = bf2f(mv.x) + xv.x, h1 = bf2f(mv.y) + xv.y;
    float h2 = bf2f(mv.z) + xv.z, h3 = bf2f(mv.w) + xv.w;
    float s = h0 + h1 + h2 + h3;
    float q = h0 * h0 + h1 * h1 + h2 * h2 + h3 * h3;
#pragma unroll
    for (int o = 32; o > 0; o >>= 1) {
        s += __shfl_down(s, o);
        q += __shfl_down(q, o);
    }
    int lane = tid & 63, wid = tid >> 6;
    if (lane == 0) { red[wid] = s; red[4 + wid] = q; }
    __syncthreads();
    s = red[0] + red[1] + red[2] + red[3];
    q = red[4] + red[5] + red[6] + red[7];
    float mu = s * (1.f / DM);
    float var = q * (1.f / DM) - mu * mu;
    float rs = rsqrtf(var + 1e-5f);
    float4 gv = *reinterpret_cast<const float4*>(&g[tid * 4]);
    float4 bv = *reinterpret_cast<const float4*>(&be[tid * 4]);
    float4 o;
    o.x = (h0 - mu) * rs * gv.x + bv.x;
    o.y = (h1 - mu) * rs * gv.y + bv.y;
    o.z = (h2 - mu) * rs * gv.z + bv.z;
    o.w = (h3 - mu) * rs * gv.w + bv.w;
    *reinterpret_cast<float4*>(&out[r * DM + tid * 4]) = o;
}

extern "C" void kernel_launch(void* const* d_in, const int* in_sizes, int n_in,
                              void* d_out, int out_size, void* d_ws, size_t ws_size,
                              hipStream_t stream) {
    const float* x      = (const float*)d_in[0];   // (B,L,DM)
    const float* w_in   = (const float*)d_in[1];   // (2*DI, DM)
    const float* conv_w = (const float*)d_in[2];   // (DI,1,4)
    const float* conv_b = (const float*)d_in[3];   // (DI)
    const float* w_xp   = (const float*)d_in[4];   // (96, DI)
    const float* w_dt   = (const float*)d_in[5];   // (DI, 64)
    const float* dt_b   = (const float*)d_in[6];   // (DI)
    const float* A_log  = (const float*)d_in[7];   // (DI,16)
    const float* Dp     = (const float*)d_in[8];   // (DI)
    const float* w_out  = (const float*)d_in[9];   // (DM, DI)
    const float* ln_g   = (const float*)d_in[10];
    const float* ln_b   = (const float*)d_in[11];
    float* out = (float*)d_out;

    char* ws = (char*)d_ws;
    size_t off = 0;
    auto alloc = [&](size_t bytes) -> void* {
        void* p = ws + off;
        off += (bytes + 255) & ~(size_t)255;
        return p;
    };
    const int M = B_ * L_;  // 8192
    ushort_t* w_in_b  = (ushort_t*)alloc((size_t)2 * DI * DM * 2);
    ushort_t* w_xp_b  = (ushort_t*)alloc((size_t)96 * DI * 2);
    ushort_t* w_dt_b  = (ushort_t*)alloc((size_t)DI * DTR * 2);
    ushort_t* w_out_b = (ushort_t*)alloc((size_t)DM * DI * 2);
    ushort_t* x_b     = (ushort_t*)alloc((size_t)M * DM * 2);   // 16.8 MB
    ushort_t* xz      = (ushort_t*)alloc((size_t)M * 2 * DI * 2);
    ushort_t* xm      = (ushort_t*)alloc((size_t)M * DI * 2);
    ushort_t* dbc     = (ushort_t*)alloc((size_t)M * 96 * 2);
    ushort_t* dtb     = (ushort_t*)alloc((size_t)M * DI * 2);   // bf16 dt (33.5 MB)
    ushort_t* yg      = (ushort_t*)alloc((size_t)M * DI * 2);
    float*    dtsum   = (float*)alloc((size_t)B_ * NC * DI * 4);
    float*    dbc_p   = (float*)alloc((size_t)4 * M * 96 * 4);  // split-K partials
    ushort_t* mo      = dtb;           // alias: dt dead after scan3 (bf16 mo fits)
    float*    hfin    = (float*)x_b;   // alias: x_b dead after in_proj

    // fused f32->bf16 conversion of all inputs (1 launch)
    k_cvt5<<<dim3(CV_E4 / 256), 256, 0, stream>>>(
        w_in, w_in_b, w_xp, w_xp_b, w_dt, w_dt_b, w_out, w_out_b, x, x_b);

    // in_proj: xz[8192,4096] = x_b @ w_in_b^T  (256^2 8-phase)
    k_gemm8<<<dim3(512), 512, 0, stream>>>(x_b, w_in_b, xz);
    // conv + silu
    k_conv<<<dim3(DI / 256, L_ / 128, B_), 256, 0, stream>>>(xz, conv_w, conv_b, xm);
    // x_proj (split-K=4): dbc_p[z][M,96] = xm @ w_xp[96,2048]^T (K chunk 512)
    k_gemm2<0, false><<<dim3(64, 1, 4), 256, 0, stream>>>(
        xm, w_xp_b, dbc_p, nullptr, M, 96, DI, DI, DI, 96, 64);
    k_red4<<<dim3((M * 96 / 4 + 255) / 256), 256, 0, stream>>>(dbc_p, dbc, M * 96, M * 96);
    // dt_proj + softplus -> bf16
    k_gemm2<1, true><<<dim3(64 * 16, 1, 1), 256, 0, stream>>>(
        dbc, w_dt_b, dtb, dt_b, M, DI, DTR, 96, DTR, DI, 64);
    // chunked selective scan
    k_scan1<<<dim3(DI / 256, NC, B_), 256, 0, stream>>>(dtb, xm, dbc, A_log, hfin, dtsum);
    k_scan2<<<dim3(B_ * DI * DSTATE / 256), 256, 0, stream>>>(hfin, dtsum, A_log);
    k_scan3<<<dim3(DI / 256, NC, B_), 256, 0, stream>>>(dtb, xm, xz, dbc, A_log, Dp, hfin, yg);
    // out_proj: mo[8192,1024](bf16) = yg @ w_out^T  (256x128 8-phase, grid 256)
    k_gemm8o<<<dim3(256), 512, 0, stream>>>(yg, w_out_b, mo);
    // residual + layernorm
    k_ln<<<dim3(M), 256, 0, stream>>>(mo, x, ln_g, ln_b, out);
}

// Round 10
// 326.811 us; speedup vs baseline: 4.9180x; 1.0066x over previous
//
#include <hip/hip_runtime.h>
#include <hip/hip_bf16.h>

// Mamba block: B=4, L=2048, D_MODEL=1024, D_INNER=2048, D_STATE=16, DT_RANK=64
#define B_ 4
#define L_ 2048
#define DM 1024
#define DI 2048
#define DSTATE 16
#define DTR 64
#define LC 64            // scan chunk length
#define NC (L_ / LC)     // 32 chunks
#define LOG2E 1.44269504f

typedef unsigned short ushort_t;
typedef __bf16 bf16x8 __attribute__((ext_vector_type(8)));
typedef float f32x4 __attribute__((ext_vector_type(4)));
typedef float f32x16 __attribute__((ext_vector_type(16)));
typedef unsigned short u16x8 __attribute__((ext_vector_type(8)));
typedef unsigned short u16x4 __attribute__((ext_vector_type(4)));

__device__ __forceinline__ ushort_t f2bf(float f) {
    unsigned u = __builtin_bit_cast(unsigned, f);
    unsigned r = (u + 0x7FFFu + ((u >> 16) & 1u)) >> 16;
    return (ushort_t)r;
}
__device__ __forceinline__ float bf2f(ushort_t h) {
    unsigned u = ((unsigned)h) << 16;
    return __builtin_bit_cast(float, u);
}

// ---------------- fused f32 -> bf16 convert for all 5 buffers ----------------
#define CV_E0 1048576
#define CV_E1 (CV_E0 + 49152)
#define CV_E2 (CV_E1 + 32768)
#define CV_E3 (CV_E2 + 524288)
#define CV_E4 (CV_E3 + 2097152)     // total 3751936 quads = 14656 * 256
__global__ __launch_bounds__(256) void k_cvt5(
    const float* __restrict__ s0, ushort_t* __restrict__ d0,
    const float* __restrict__ s1, ushort_t* __restrict__ d1,
    const float* __restrict__ s2, ushort_t* __restrict__ d2,
    const float* __restrict__ s3, ushort_t* __restrict__ d3,
    const float* __restrict__ s4, ushort_t* __restrict__ d4) {
    int g = blockIdx.x * 256 + threadIdx.x;
    const float* s;
    ushort_t* dst;
    int i;
    if (g < CV_E0)      { s = s0; dst = d0; i = g * 4; }
    else if (g < CV_E1) { s = s1; dst = d1; i = (g - CV_E0) * 4; }
    else if (g < CV_E2) { s = s2; dst = d2; i = (g - CV_E1) * 4; }
    else if (g < CV_E3) { s = s3; dst = d3; i = (g - CV_E2) * 4; }
    else                { s = s4; dst = d4; i = (g - CV_E3) * 4; }
    float4 v = *reinterpret_cast<const float4*>(s + i);
    ushort4 o;
    o.x = f2bf(v.x); o.y = f2bf(v.y); o.z = f2bf(v.z); o.w = f2bf(v.w);
    *reinterpret_cast<ushort4*>(dst + i) = o;
}

// ============ 8-phase MFMA GEMM machinery ============
#define FENCE asm volatile("" ::: "memory")
#define VM8 asm volatile("s_waitcnt vmcnt(8)" ::: "memory")
#define VM6 asm volatile("s_waitcnt vmcnt(6)" ::: "memory")
#define VM4 asm volatile("s_waitcnt vmcnt(4)" ::: "memory")
#define VM3 asm volatile("s_waitcnt vmcnt(3)" ::: "memory")
#define VM0 asm volatile("s_waitcnt vmcnt(0)" ::: "memory")

// -------- in_proj: C[8192,4096](bf16) = A[8192,1024] * W[4096,1024]^T --------
// Merged-phase schedule: per phase read av[8]+bv[4] (12 ds_read_b128), stage
// one full tile (4 global_load_lds), 32 MFMA, ONE barrier-pair. 4-buffer ring,
// stage distance 3, uniform VM8 (4 loads/tile x 3 tiles in flight = 12 ->
// wait-to-8 confirms next-read tile landed). Drain VM8/VM4/VM0.
__global__ __launch_bounds__(512, 2) void k_gemm8(const ushort_t* __restrict__ Aq,
                                                  const ushort_t* __restrict__ Bq,
                                                  ushort_t* __restrict__ C) {
    __shared__ ushort_t lds[65536];  // 128 KB: 4 buffers x (A 8192 + B 8192 elems)
    const int tid = threadIdx.x;
    const int w = tid >> 6, lane = tid & 63;
    const int l15 = lane & 15;
    const int wm = w >> 2, wn = w & 3;
    const int bid = blockIdx.x;
    const int tm = (bid & 7) * 4 + ((bid >> 3) & 3);
    const int tn = bid >> 5;
    const int row0 = tm * 256, col0 = tn * 256;

    const int rs = w * 16 + (lane >> 2);
    const int lcs = (lane & 3) ^ ((lane >> 3) & 3);
    const int pcr = ((lane >> 4) ^ ((l15 >> 1) & 3)) * 8;
    const int aoff = wm * 4096 + l15 * 32 + pcr;
    const int boff = 8192 + (wn >> 1) * 4096 + (wn & 1) * 2048 + l15 * 32 + pcr;

    auto stg = [&](int buf, int t) {
        const ushort_t* sa = Aq + (size_t)(row0 + rs) * 1024 + t * 32 + lcs * 8;
        __builtin_amdgcn_global_load_lds(
            (const __attribute__((address_space(1))) void*)sa,
            (__attribute__((address_space(3))) void*)&lds[buf * 16384 + w * 512], 16, 0, 0);
        __builtin_amdgcn_global_load_lds(
            (const __attribute__((address_space(1))) void*)(sa + 128 * 1024),
            (__attribute__((address_space(3))) void*)&lds[buf * 16384 + 4096 + w * 512], 16, 0, 0);
        const ushort_t* sb = Bq + (size_t)(col0 + rs) * 1024 + t * 32 + lcs * 8;
        __builtin_amdgcn_global_load_lds(
            (const __attribute__((address_space(1))) void*)sb,
            (__attribute__((address_space(3))) void*)&lds[buf * 16384 + 8192 + w * 512], 16, 0, 0);
        __builtin_amdgcn_global_load_lds(
            (const __attribute__((address_space(1))) void*)(sb + 128 * 1024),
            (__attribute__((address_space(3))) void*)&lds[buf * 16384 + 12288 + w * 512], 16, 0, 0);
    };

    f32x4 acc[8][4] = {};

#define MPHASE(BUF, STAGE_STMT, WAIT_STMT)                                        \
    {                                                                             \
        bf16x8 av[8], bv[4];                                                      \
        _Pragma("unroll") for (int i_ = 0; i_ < 8; ++i_)                          \
            av[i_] = *(const bf16x8*)&lds[(BUF) * 16384 + aoff + i_ * 512];       \
        _Pragma("unroll") for (int i_ = 0; i_ < 4; ++i_)                          \
            bv[i_] = *(const bf16x8*)&lds[(BUF) * 16384 + boff + i_ * 512];       \
        STAGE_STMT;                                                               \
        FENCE; __builtin_amdgcn_s_barrier(); FENCE;                               \
        asm volatile("s_waitcnt lgkmcnt(0)" ::: "memory");                        \
        __builtin_amdgcn_sched_barrier(0);                                        \
        __builtin_amdgcn_s_setprio(1);                                            \
        _Pragma("unroll") for (int i_ = 0; i_ < 8; ++i_)                          \
            _Pragma("unroll") for (int j_ = 0; j_ < 4; ++j_)                      \
                acc[i_][j_] = __builtin_amdgcn_mfma_f32_16x16x32_bf16(            \
                    av[i_], bv[j_], acc[i_][j_], 0, 0, 0);                        \
        __builtin_amdgcn_s_setprio(0);                                            \
        WAIT_STMT;                                                                \
        FENCE; __builtin_amdgcn_s_barrier(); FENCE;                               \
    }

    stg(0, 0); stg(1, 1); stg(2, 2);   // 12 loads in flight
    VM8;                                // tile 0 landed
    FENCE; __builtin_amdgcn_s_barrier(); FENCE;

#pragma unroll 1
    for (int k = 0; k < 7; ++k) {
        const int t3 = 4 * k + 3;
        MPHASE(0, stg(3, t3), VM8);
        MPHASE(1, stg(0, t3 + 1), VM8);
        MPHASE(2, stg(1, t3 + 2), VM8);
        MPHASE(3, stg(2, t3 + 3), VM8);
    }
    // tail: tiles 28..31; only tile 31 left to stage
    MPHASE(0, stg(3, 31), VM8);
    MPHASE(1, (void)0, VM4);
    MPHASE(2, (void)0, VM0);
    MPHASE(3, (void)0, (void)0);
#undef MPHASE

#pragma unroll
    for (int mf = 0; mf < 8; ++mf)
#pragma unroll
        for (int nf = 0; nf < 4; ++nf) {
            int col = col0 + wn * 64 + nf * 16 + l15;
#pragma unroll
            for (int r = 0; r < 4; ++r) {
                int row = row0 + wm * 128 + mf * 16 + (lane >> 4) * 4 + r;
                C[(size_t)row * 4096 + col] = f2bf(acc[mf][nf][r]);
            }
        }
}

// -------- out_proj: mo[8192,1024](bf16) = yg[8192,2048] * w_out[1024,2048]^T --
__global__ __launch_bounds__(512, 2) void k_gemm8o(const ushort_t* __restrict__ Aq,
                                                   const ushort_t* __restrict__ Bq,
                                                   ushort_t* __restrict__ C) {
    __shared__ ushort_t lds[49152];  // 96 KB: 4 x (A 8192 + B 4096 elems)
    const int tid = threadIdx.x;
    const int w = tid >> 6, lane = tid & 63;
    const int l15 = lane & 15;
    const int wm = w >> 2, wn = w & 3;
    const int bid = blockIdx.x;
    const int tm = bid & 31, tn = bid >> 5;
    const int row0 = tm * 256, col0 = tn * 128;

    const int rs = w * 16 + (lane >> 2);
    const int lcs = (lane & 3) ^ ((lane >> 3) & 3);
    const int pcr = ((lane >> 4) ^ ((l15 >> 1) & 3)) * 8;
    const int aoff = wm * 4096 + l15 * 32 + pcr;
    const int boff = 8192 + wn * 1024 + l15 * 32 + pcr;

    auto stg = [&](int buf, int t) {
        const ushort_t* sa = Aq + (size_t)(row0 + rs) * 2048 + t * 32 + lcs * 8;
        __builtin_amdgcn_global_load_lds(
            (const __attribute__((address_space(1))) void*)sa,
            (__attribute__((address_space(3))) void*)&lds[buf * 12288 + w * 512], 16, 0, 0);
        __builtin_amdgcn_global_load_lds(
            (const __attribute__((address_space(1))) void*)(sa + 128 * 2048),
            (__attribute__((address_space(3))) void*)&lds[buf * 12288 + 4096 + w * 512], 16, 0, 0);
        const ushort_t* sb = Bq + (size_t)(col0 + rs) * 2048 + t * 32 + lcs * 8;
        __builtin_amdgcn_global_load_lds(
            (const __attribute__((address_space(1))) void*)sb,
            (__attribute__((address_space(3))) void*)&lds[buf * 12288 + 8192 + w * 512], 16, 0, 0);
    };

    f32x4 acc[8][2] = {};

#define OPHASE(BUF, STAGE_STMT, WAIT_STMT)                                        \
    {                                                                             \
        bf16x8 av[8], bv[2];                                                      \
        _Pragma("unroll") for (int i_ = 0; i_ < 8; ++i_)                          \
            av[i_] = *(const bf16x8*)&lds[(BUF) * 12288 + aoff + i_ * 512];       \
        _Pragma("unroll") for (int i_ = 0; i_ < 2; ++i_)                          \
            bv[i_] = *(const bf16x8*)&lds[(BUF) * 12288 + boff + i_ * 512];       \
        STAGE_STMT;                                                               \
        FENCE; __builtin_amdgcn_s_barrier(); FENCE;                               \
        asm volatile("s_waitcnt lgkmcnt(0)" ::: "memory");                        \
        __builtin_amdgcn_sched_barrier(0);                                        \
        __builtin_amdgcn_s_setprio(1);                                            \
        _Pragma("unroll") for (int i_ = 0; i_ < 8; ++i_)                          \
            _Pragma("unroll") for (int j_ = 0; j_ < 2; ++j_)                      \
                acc[i_][j_] = __builtin_amdgcn_mfma_f32_16x16x32_bf16(            \
                    av[i_], bv[j_], acc[i_][j_], 0, 0, 0);                        \
        __builtin_amdgcn_s_setprio(0);                                            \
        WAIT_STMT;                                                                \
        FENCE; __builtin_amdgcn_s_barrier(); FENCE;                               \
    }

    stg(0, 0); stg(1, 1); stg(2, 2);   // 9 loads
    VM6;                                // tile 0's 3 landed
    FENCE; __builtin_amdgcn_s_barrier(); FENCE;

#pragma unroll 1
    for (int k = 0; k < 15; ++k) {
        const int t3 = 4 * k + 3;
        OPHASE(0, stg(3, t3), VM6);
        OPHASE(1, stg(0, t3 + 1), VM6);
        OPHASE(2, stg(1, t3 + 2), VM6);
        OPHASE(3, stg(2, t3 + 3), VM6);
    }
    OPHASE(0, stg(3, 63), VM6);
    OPHASE(1, (void)0, VM3);
    OPHASE(2, (void)0, VM0);
    OPHASE(3, (void)0, (void)0);
#undef OPHASE

#pragma unroll
    for (int mf = 0; mf < 8; ++mf)
#pragma unroll
        for (int nf = 0; nf < 2; ++nf) {
            int col = col0 + wn * 32 + nf * 16 + l15;
#pragma unroll
            for (int r = 0; r < 4; ++r) {
                int row = row0 + wm * 128 + mf * 16 + (lane >> 4) * 4 + r;
                C[(size_t)row * 1024 + col] = f2bf(acc[mf][nf][r]);
            }
        }
}

// ---------------- m97-structure bf16 MFMA GEMM (x_proj / dt_proj) ------------
template <int EPI, bool OUTBF>
__global__ __launch_bounds__(256) void k_gemm2(
    const ushort_t* __restrict__ A, const ushort_t* __restrict__ Bw,
    void* __restrict__ C, const float* __restrict__ bias,
    int M, int N, int K, int lda, int ldb, int ldc, int tilesM) {
    __shared__ ushort_t As[128 * 64];
    __shared__ ushort_t Bs[128 * 64];
    int tid = threadIdx.x;
    int lane = tid & 63, wv = tid >> 6;
    int wr = wv >> 1, wc = wv & 1;
    int bid = blockIdx.x;
    int tilesN = gridDim.x / tilesM;
    int per = 8 * tilesN;
    int grp = bid / per, within = bid % per;
    int tm = grp * 8 + (within & 7);
    int tn = within >> 3;
    int row0 = tm * 128, col0 = tn * 128;
    int kchunk = K / gridDim.z;
    int kbeg = blockIdx.z * kchunk, kend = kbeg + kchunk;
    float* Cf = (float*)C + (size_t)blockIdx.z * (size_t)M * ldc;

    int sr = lane >> 3;
    int sj = lane & 7;
    f32x4 acc[4][4] = {};

    for (int k0 = kbeg; k0 < kend; k0 += 64) {
        __syncthreads();
#pragma unroll
        for (int i = 0; i < 4; ++i) {
            int slot = wv * 4 + i;
            int r = slot * 8 + sr;
            int jA = sj ^ (r & 7);
            __builtin_amdgcn_global_load_lds(
                (const __attribute__((address_space(1))) void*)&A[(size_t)(row0 + r) * lda + k0 + jA * 8],
                (__attribute__((address_space(3))) void*)&As[slot * 512], 16, 0, 0);
            __builtin_amdgcn_global_load_lds(
                (const __attribute__((address_space(1))) void*)&Bw[(size_t)(col0 + r) * ldb + k0 + jA * 8],
                (__attribute__((address_space(3))) void*)&Bs[slot * 512], 16, 0, 0);
        }
        __syncthreads();
#pragma unroll
        for (int kk = 0; kk < 2; ++kk) {
            int co = kk * 32 + (lane >> 4) * 8;
            int sx = (lane & 7) << 3;
            bf16x8 af[4], bfr[4];
#pragma unroll
            for (int m = 0; m < 4; ++m) {
                int rw = wr * 64 + m * 16 + (lane & 15);
                af[m] = *reinterpret_cast<const bf16x8*>(&As[rw * 64 + (co ^ sx)]);
            }
#pragma unroll
            for (int n = 0; n < 4; ++n) {
                int rw = wc * 64 + n * 16 + (lane & 15);
                bfr[n] = *reinterpret_cast<const bf16x8*>(&Bs[rw * 64 + (co ^ sx)]);
            }
#pragma unroll
            for (int m = 0; m < 4; ++m)
#pragma unroll
                for (int n = 0; n < 4; ++n)
                    acc[m][n] = __builtin_amdgcn_mfma_f32_16x16x32_bf16(af[m], bfr[n], acc[m][n], 0, 0, 0);
        }
    }

#pragma unroll
    for (int m = 0; m < 4; ++m) {
#pragma unroll
        for (int n = 0; n < 4; ++n) {
            int col = col0 + wc * 64 + n * 16 + (lane & 15);
            if (col >= N) continue;
#pragma unroll
            for (int r = 0; r < 4; ++r) {
                int row = row0 + wr * 64 + m * 16 + (lane >> 4) * 4 + r;
                float v = acc[m][n][r];
                if (EPI == 1) {
                    v += bias[col];
                    v = (v > 20.f) ? v : log1pf(__expf(v));
                }
                if (OUTBF)
                    ((ushort_t*)C)[(size_t)row * ldc + col] = f2bf(v);
                else
                    Cf[(size_t)row * ldc + col] = v;
            }
        }
    }
}

// ---------------- split-K partial reduce (4 partials f32 -> bf16) ------------
__global__ __launch_bounds__(256) void k_red4(const float* __restrict__ p,
                                              ushort_t* __restrict__ o,
                                              int n, int stride) {
    int i = (blockIdx.x * 256 + threadIdx.x) * 4;
    if (i >= n) return;
    f32x4 a = *reinterpret_cast<const f32x4*>(&p[i]);
    f32x4 b = *reinterpret_cast<const f32x4*>(&p[i + stride]);
    f32x4 c = *reinterpret_cast<const f32x4*>(&p[i + 2 * stride]);
    f32x4 d = *reinterpret_cast<const f32x4*>(&p[i + 3 * stride]);
    ushort4 r;
    r.x = f2bf(a[0] + b[0] + c[0] + d[0]);
    r.y = f2bf(a[1] + b[1] + c[1] + d[1]);
    r.z = f2bf(a[2] + b[2] + c[2] + d[2]);
    r.w = f2bf(a[3] + b[3] + c[3] + d[3]);
    *reinterpret_cast<ushort4*>(&o[i]) = r;
}

// ---------------- depthwise causal conv (width 4) + SiLU ----------------
__global__ __launch_bounds__(256) void k_conv(const ushort_t* __restrict__ xz,
                                              const float* __restrict__ w,
                                              const float* __restrict__ bias,
                                              ushort_t* __restrict__ out) {
    int d = blockIdx.x * 256 + threadIdx.x;
    int b = blockIdx.z;
    int t0 = blockIdx.y * 128;
    float w0 = w[d * 4 + 0], w1 = w[d * 4 + 1], w2 = w[d * 4 + 2], w3 = w[d * 4 + 3];
    float bi = bias[d];
    size_t base = ((size_t)b * L_) * (2 * DI) + d;
    size_t obase = ((size_t)b * L_) * DI + d;
    float x0 = (t0 >= 3) ? bf2f(xz[base + (size_t)(t0 - 3) * (2 * DI)]) : 0.f;
    float x1 = (t0 >= 2) ? bf2f(xz[base + (size_t)(t0 - 2) * (2 * DI)]) : 0.f;
    float x2 = (t0 >= 1) ? bf2f(xz[base + (size_t)(t0 - 1) * (2 * DI)]) : 0.f;
    for (int t = t0; t < t0 + 128; ++t) {
        float cur = bf2f(xz[base + (size_t)t * (2 * DI)]);
        float v = w0 * x0 + w1 * x1 + w2 * x2 + w3 * cur + bi;
        v = v / (1.f + __expf(-v));
        out[obase + (size_t)t * DI] = f2bf(v);
        x0 = x1; x1 = x2; x2 = cur;
    }
}

// ---------------- chunked selective scan ----------------
// Phase 1: per-chunk local scan (h=0) -> chunk-final h and sum(dt)
__global__ __launch_bounds__(256) void k_scan1(
    const ushort_t* __restrict__ dt, const ushort_t* __restrict__ xm,
    const ushort_t* __restrict__ dbc, const float* __restrict__ A_log,
    float* __restrict__ hfin, float* __restrict__ dtsum) {
    __shared__ float Bsh[LC][DSTATE];
    int tid = threadIdx.x;
    int d = blockIdx.x * 256 + tid;
    int c = blockIdx.y, b = blockIdx.z;
    f32x16 arow;
    float a1 = __expf(A_log[d * DSTATE]);
    bool ok = true;
#pragma unroll
    for (int s = 0; s < DSTATE; ++s) {
        float av = __expf(A_log[d * DSTATE + s]);
        arow[s] = -av * LOG2E;
        ok = ok && (fabsf(av - (float)(s + 1) * a1) <= 1e-4f * (float)(s + 1) * fabsf(a1) + 1e-6f);
    }
    float arow0 = -a1 * LOG2E;
    size_t rbase = (size_t)b * L_ + (size_t)c * LC;
    {
        int i = tid * 4;
        int t = i >> 4, s0 = i & 15;
        u16x4 v = *reinterpret_cast<const u16x4*>(&dbc[(rbase + t) * 96 + DTR + s0]);
#pragma unroll
        for (int j = 0; j < 4; ++j) Bsh[t][s0 + j] = bf2f(v[j]);
    }
    __syncthreads();
    f32x4 h0 = {}, h1 = {}, h2 = {}, h3 = {};
    float sd = 0.f;
    if (ok) {
        for (int t = 0; t < LC; ++t) {
            size_t ro = rbase + t;
            float dtv = bf2f(dt[ro * DI + d]);
            float xv = bf2f(xm[ro * DI + d]);
            float dx = dtv * xv;
            sd += dtv;
            float p = __builtin_amdgcn_exp2f(dtv * arow0);
            float p2 = p * p, p3 = p2 * p, p4 = p2 * p2;
            f32x4 ea = {p, p2, p3, p4};
            f32x4 eb = ea * p4, ec = eb * p4, ed = ec * p4;
            const f32x4* Bq = reinterpret_cast<const f32x4*>(&Bsh[t][0]);
            h0 = h0 * ea + Bq[0] * dx;
            h1 = h1 * eb + Bq[1] * dx;
            h2 = h2 * ec + Bq[2] * dx;
            h3 = h3 * ed + Bq[3] * dx;
        }
    } else {
        for (int t = 0; t < LC; ++t) {
            size_t ro = rbase + t;
            float dtv = bf2f(dt[ro * DI + d]);
            float xv = bf2f(xm[ro * DI + d]);
            float dx = dtv * xv;
            sd += dtv;
            const f32x4* Bq = reinterpret_cast<const f32x4*>(&Bsh[t][0]);
            f32x4 e0, e1, e2, e3;
#pragma unroll
            for (int j = 0; j < 4; ++j) {
                e0[j] = __builtin_amdgcn_exp2f(dtv * arow[j]);
                e1[j] = __builtin_amdgcn_exp2f(dtv * arow[4 + j]);
                e2[j] = __builtin_amdgcn_exp2f(dtv * arow[8 + j]);
                e3[j] = __builtin_amdgcn_exp2f(dtv * arow[12 + j]);
            }
            h0 = h0 * e0 + Bq[0] * dx;
            h1 = h1 * e1 + Bq[1] * dx;
            h2 = h2 * e2 + Bq[2] * dx;
            h3 = h3 * e3 + Bq[3] * dx;
        }
    }
    size_t hbase = (((size_t)b * NC + c) * DI + d) * DSTATE;
    *reinterpret_cast<f32x4*>(&hfin[hbase + 0]) = h0;
    *reinterpret_cast<f32x4*>(&hfin[hbase + 4]) = h1;
    *reinterpret_cast<f32x4*>(&hfin[hbase + 8]) = h2;
    *reinterpret_cast<f32x4*>(&hfin[hbase + 12]) = h3;
    dtsum[((size_t)b * NC + c) * DI + d] = sd;
}

// Phase 2: sequential carry over chunks; hfin becomes carry-IN per chunk.
__global__ __launch_bounds__(256) void k_scan2(
    float* __restrict__ hfin, const float* __restrict__ dtsum,
    const float* __restrict__ A_log) {
    int gid = blockIdx.x * 256 + threadIdx.x;  // s fastest, then d, then b
    int s = gid & (DSTATE - 1);
    int d = (gid >> 4) & (DI - 1);
    int b = gid >> 15;
    float Av = -__expf(A_log[d * DSTATE + s]) * LOG2E;
    float carry = 0.f;
    for (int c = 0; c < NC; ++c) {
        size_t idx = (((size_t)b * NC + c) * DI + d) * DSTATE + s;
        float loc = hfin[idx];
        hfin[idx] = carry;
        float sd = dtsum[((size_t)b * NC + c) * DI + d];
        carry = __builtin_amdgcn_exp2f(Av * sd) * carry + loc;
    }
}

// Phase 3: local scan with carry-in + D*x + z-gating -> yg (bf16)
__global__ __launch_bounds__(256) void k_scan3(
    const ushort_t* __restrict__ dt, const ushort_t* __restrict__ xm,
    const ushort_t* __restrict__ xz, const ushort_t* __restrict__ dbc,
    const float* __restrict__ A_log, const float* __restrict__ Dp,
    const float* __restrict__ hinit, ushort_t* __restrict__ yg) {
    __shared__ float Bsh[LC][DSTATE];
    __shared__ float Csh[LC][DSTATE];
    int tid = threadIdx.x;
    int d = blockIdx.x * 256 + tid;
    int c = blockIdx.y, b = blockIdx.z;
    f32x16 arow;
    float a1 = __expf(A_log[d * DSTATE]);
    bool ok = true;
#pragma unroll
    for (int s = 0; s < DSTATE; ++s) {
        float av = __expf(A_log[d * DSTATE + s]);
        arow[s] = -av * LOG2E;
        ok = ok && (fabsf(av - (float)(s + 1) * a1) <= 1e-4f * (float)(s + 1) * fabsf(a1) + 1e-6f);
    }
    float arow0 = -a1 * LOG2E;
    float Dd = Dp[d];
    size_t rbase = (size_t)b * L_ + (size_t)c * LC;
    {
        int e0 = tid * 8;
        int t = e0 >> 5, s0 = e0 & 31;
        u16x8 v = *reinterpret_cast<const u16x8*>(&dbc[(rbase + t) * 96 + DTR + s0]);
#pragma unroll
        for (int j = 0; j < 8; ++j) {
            int s = s0 + j;
            float f = bf2f(v[j]);
            if (s < DSTATE) Bsh[t][s] = f;
            else Csh[t][s - DSTATE] = f;
        }
    }
    __syncthreads();
    size_t hbase = (((size_t)b * NC + c) * DI + d) * DSTATE;
    f32x4 h0 = *reinterpret_cast<const f32x4*>(&hinit[hbase + 0]);
    f32x4 h1 = *reinterpret_cast<const f32x4*>(&hinit[hbase + 4]);
    f32x4 h2 = *reinterpret_cast<const f32x4*>(&hinit[hbase + 8]);
    f32x4 h3 = *reinterpret_cast<const f32x4*>(&hinit[hbase + 12]);
    if (ok) {
        for (int t = 0; t < LC; ++t) {
            size_t ro = rbase + t;
            float dtv = bf2f(dt[ro * DI + d]);
            float xv = bf2f(xm[ro * DI + d]);
            float zv = bf2f(xz[ro * (2 * DI) + DI + d]);
            float dx = dtv * xv;
            float p = __builtin_amdgcn_exp2f(dtv * arow0);
            float p2 = p * p, p3 = p2 * p, p4 = p2 * p2;
            f32x4 ea = {p, p2, p3, p4};
            f32x4 eb = ea * p4, ec = eb * p4, ed = ec * p4;
            const f32x4* Bq = reinterpret_cast<const f32x4*>(&Bsh[t][0]);
            const f32x4* Cq = reinterpret_cast<const f32x4*>(&Csh[t][0]);
            h0 = h0 * ea + Bq[0] * dx;
            h1 = h1 * eb + Bq[1] * dx;
            h2 = h2 * ec + Bq[2] * dx;
            h3 = h3 * ed + Bq[3] * dx;
            f32x4 y4 = h0 * Cq[0] + h1 * Cq[1] + h2 * Cq[2] + h3 * Cq[3];
            float y = (y4[0] + y4[1]) + (y4[2] + y4[3]) + Dd * xv;
            y *= zv / (1.f + __expf(-zv));
            yg[ro * DI + d] = f2bf(y);
        }
    } else {
        for (int t = 0; t < LC; ++t) {
            size_t ro = rbase + t;
            float dtv = bf2f(dt[ro * DI + d]);
            float xv = bf2f(xm[ro * DI + d]);
            float zv = bf2f(xz[ro * (2 * DI) + DI + d]);
            float dx = dtv * xv;
            const f32x4* Bq = reinterpret_cast<const f32x4*>(&Bsh[t][0]);
            const f32x4* Cq = reinterpret_cast<const f32x4*>(&Csh[t][0]);
            f32x4 e0, e1, e2, e3;
#pragma unroll
            for (int j = 0; j < 4; ++j) {
                e0[j] = __builtin_amdgcn_exp2f(dtv * arow[j]);
                e1[j] = __builtin_amdgcn_exp2f(dtv * arow[4 + j]);
                e2[j] = __builtin_amdgcn_exp2f(dtv * arow[8 + j]);
                e3[j] = __builtin_amdgcn_exp2f(dtv * arow[12 + j]);
            }
            h0 = h0 * e0 + Bq[0] * dx;
            h1 = h1 * e1 + Bq[1] * dx;
            h2 = h2 * e2 + Bq[2] * dx;
            h3 = h3 * e3 + Bq[3] * dx;
            f32x4 y4 = h0 * Cq[0] + h1 * Cq[1] + h2 * Cq[2] + h3 * Cq[3];
            float y = (y4[0] + y4[1]) + (y4[2] + y4[3]) + Dd * xv;
            y *= zv / (1.f + __expf(-zv));
            yg[ro * DI + d] = f2bf(y);
        }
    }
}

// ---------------- residual + LayerNorm (bf16 mamba-out) ----------------
__global__ __launch_bounds__(256) void k_ln(const ushort_t* __restrict__ mo,
                                            const float* __restrict__ x,
                                            const float* __restrict__ g,
                                            const float* __restrict__ be,
                                            float* __restrict__ out) {
    __shared__ float red[8];
    size_t r = blockIdx.x;
    int tid = threadIdx.x;
    ushort4 mv = *reinterpret_cast<const ushort4*>(&mo[r * DM + tid * 4]);
    float4 xv = *reinterpret_cast<const float4*>(&x[r * DM + tid * 4]);
    float h0 = bf2f(mv.x) + xv.x, h1 = bf2f(mv.y) + xv.y;
    float h2 = bf2f(mv.z) + xv.z, h3 = bf2f(mv.w) + xv.w;
    float s = h0 + h1 + h2 + h3;
    float q = h0 * h0 + h1 * h1 + h2 * h2 + h3 * h3;
#pragma unroll
    for (int o = 32; o > 0; o >>= 1) {
        s += __shfl_down(s, o);
        q += __shfl_down(q, o);
    }
    int lane = tid & 63, wid = tid >> 6;
    if (lane == 0) { red[wid] = s; red[4 + wid] = q; }
    __syncthreads();
    s = red[0] + red[1] + red[2] + red[3];
    q = red[4] + red[5] + red[6] + red[7];
    float mu = s * (1.f / DM);
    float var = q * (1.f / DM) - mu * mu;
    float rs = rsqrtf(var + 1e-5f);
    float4 gv = *reinterpret_cast<const float4*>(&g[tid * 4]);
    float4 bv = *reinterpret_cast<const float4*>(&be[tid * 4]);
    float4 o;
    o.x = (h0 - mu) * rs * gv.x + bv.x;
    o.y = (h1 - mu) * rs * gv.y + bv.y;
    o.z = (h2 - mu) * rs * gv.z + bv.z;
    o.w = (h3 - mu) * rs * gv.w + bv.w;
    *reinterpret_cast<float4*>(&out[r * DM + tid * 4]) = o;
}

extern "C" void kernel_launch(void* const* d_in, const int* in_sizes, int n_in,
                              void* d_out, int out_size, void* d_ws, size_t ws_size,
                              hipStream_t stream) {
    const float* x      = (const float*)d_in[0];   // (B,L,DM)
    const float* w_in   = (const float*)d_in[1];   // (2*DI, DM)
    const float* conv_w = (const float*)d_in[2];   // (DI,1,4)
    const float* conv_b = (const float*)d_in[3];   // (DI)
    const float* w_xp   = (const float*)d_in[4];   // (96, DI)
    const float* w_dt   = (const float*)d_in[5];   // (DI, 64)
    const float* dt_b   = (const float*)d_in[6];   // (DI)
    const float* A_log  = (const float*)d_in[7];   // (DI,16)
    const float* Dp     = (const float*)d_in[8];   // (DI)
    const float* w_out  = (const float*)d_in[9];   // (DM, DI)
    const float* ln_g   = (const float*)d_in[10];
    const float* ln_b   = (const float*)d_in[11];
    float* out = (float*)d_out;

    char* ws = (char*)d_ws;
    size_t off = 0;
    auto alloc = [&](size_t bytes) -> void* {
        void* p = ws + off;
        off += (bytes + 255) & ~(size_t)255;
        return p;
    };
    const int M = B_ * L_;  // 8192
    ushort_t* w_in_b  = (ushort_t*)alloc((size_t)2 * DI * DM * 2);
    ushort_t* w_xp_b  = (ushort_t*)alloc((size_t)96 * DI * 2);
    ushort_t* w_dt_b  = (ushort_t*)alloc((size_t)DI * DTR * 2);
    ushort_t* w_out_b = (ushort_t*)alloc((size_t)DM * DI * 2);
    ushort_t* x_b     = (ushort_t*)alloc((size_t)M * DM * 2);   // 16.8 MB
    ushort_t* xz      = (ushort_t*)alloc((size_t)M * 2 * DI * 2);
    ushort_t* xm      = (ushort_t*)alloc((size_t)M * DI * 2);
    ushort_t* dbc     = (ushort_t*)alloc((size_t)M * 96 * 2);
    ushort_t* dtb     = (ushort_t*)alloc((size_t)M * DI * 2);   // bf16 dt (33.5 MB)
    ushort_t* yg      = (ushort_t*)alloc((size_t)M * DI * 2);
    float*    dtsum   = (float*)alloc((size_t)B_ * NC * DI * 4);
    float*    dbc_p   = (float*)alloc((size_t)4 * M * 96 * 4);  // split-K partials
    ushort_t* mo      = dtb;           // alias: dt dead after scan3 (bf16 mo fits)
    float*    hfin    = (float*)x_b;   // alias: x_b dead after in_proj

    // fused f32->bf16 conversion of all inputs (1 launch)
    k_cvt5<<<dim3(CV_E4 / 256), 256, 0, stream>>>(
        w_in, w_in_b, w_xp, w_xp_b, w_dt, w_dt_b, w_out, w_out_b, x, x_b);

    // in_proj: xz[8192,4096] = x_b @ w_in_b^T  (256^2 merged-phase)
    k_gemm8<<<dim3(512), 512, 0, stream>>>(x_b, w_in_b, xz);
    // conv + silu
    k_conv<<<dim3(DI / 256, L_ / 128, B_), 256, 0, stream>>>(xz, conv_w, conv_b, xm);
    // x_proj (split-K=4): dbc_p[z][M,96] = xm @ w_xp[96,2048]^T (K chunk 512)
    k_gemm2<0, false><<<dim3(64, 1, 4), 256, 0, stream>>>(
        xm, w_xp_b, dbc_p, nullptr, M, 96, DI, DI, DI, 96, 64);
    k_red4<<<dim3((M * 96 / 4 + 255) / 256), 256, 0, stream>>>(dbc_p, dbc, M * 96, M * 96);
    // dt_proj + softplus -> bf16
    k_gemm2<1, true><<<dim3(64 * 16, 1, 1), 256, 0, stream>>>(
        dbc, w_dt_b, dtb, dt_b, M, DI, DTR, 96, DTR, DI, 64);
    // chunked selective scan
    k_scan1<<<dim3(DI / 256, NC, B_), 256, 0, stream>>>(dtb, xm, dbc, A_log, hfin, dtsum);
    k_scan2<<<dim3(B_ * DI * DSTATE / 256), 256, 0, stream>>>(hfin, dtsum, A_log);
    k_scan3<<<dim3(DI / 256, NC, B_), 256, 0, stream>>>(dtb, xm, xz, dbc, A_log, Dp, hfin, yg);
    // out_proj: mo[8192,1024](bf16) = yg @ w_out^T  (256x128 merged-phase)
    k_gemm8o<<<dim3(256), 512, 0, stream>>>(yg, w_out_b, mo);
    // residual + layernorm
    k_ln<<<dim3(M), 256, 0, stream>>>(mo, x, ln_g, ln_b, out);
}